// Round 7
// baseline (943.033 us; speedup 1.0000x reference)
//
#include <hip/hip_runtime.h>
#include <math.h>

#define NNODES 32768
#define NLIG   1024
#define KAT    32
#define KNN    8
#define NEDGES (NNODES*KNN)
#define HID    128
#define TF     16
#define NG     20
#define OUTF   64

#define NPB    8            // nodes per edge-block
#define EPB    64           // edges per edge-block
#define K1     320          // padded GEMM1 K (292 -> 320)
#define MIDSTR 132          // node_k sMid row stride (floats)

typedef unsigned short u16;
typedef __attribute__((__ext_vector_type__(8))) short bfx8;
typedef __attribute__((__ext_vector_type__(4))) float f32x4;

union U8 { u16 a[8]; bfx8 v; };

__device__ __forceinline__ float siluf(float v) {
    return __fdividef(v, 1.0f + __expf(-v));
}
__device__ __forceinline__ float sigf(float v) {
    return __fdividef(1.0f, 1.0f + __expf(-v));
}
__device__ __forceinline__ u16 bf16_rn(float f) {
    union { float f; unsigned u; } v; v.f = f;
    unsigned r = v.u + 0x7FFFu + ((v.u >> 16) & 1u);
    return (u16)(r >> 16);
}
__device__ __forceinline__ float bf16_tof(u16 u) {
    union { unsigned u; float f; } v; v.u = ((unsigned)u) << 16;
    return v.f;
}
__device__ __forceinline__ f32x4 mfma3(bfx8 ah, bfx8 al, bfx8 wh, bfx8 wl, f32x4 c) {
    c = __builtin_amdgcn_mfma_f32_16x16x32_bf16(ah, wh, c, 0, 0, 0);
    c = __builtin_amdgcn_mfma_f32_16x16x32_bf16(ah, wl, c, 0, 0, 0);
    c = __builtin_amdgcn_mfma_f32_16x16x32_bf16(al, wh, c, 0, 0, 0);
    return c;
}
__device__ __forceinline__ f32x4 mfma2(bfx8 ah, bfx8 wh, bfx8 wl, f32x4 c) {
    c = __builtin_amdgcn_mfma_f32_16x16x32_bf16(ah, wh, c, 0, 0, 0);
    c = __builtin_amdgcn_mfma_f32_16x16x32_bf16(ah, wl, c, 0, 0, 0);
    return c;
}
__device__ __forceinline__ void wragg(u16* __restrict__ H, u16* __restrict__ L,
                                      size_t i, float v) {
    u16 hb = bf16_rn(v);
    H[i] = hb; L[i] = bf16_rn(v - bf16_tof(hb));
}

// ---------------------------------------------------------------- prep
#define PREP_TEMB 16000
#define PREP_W1   (4*128*K1)       // 163840
#define PREP_W2   (4*128*128)      // 65536
#define PREP_WN1  (4*128*256)      // 131072
#define PREP_WN2  (4*128*128)      // 65536
#define PREP_TOT  (PREP_TEMB+PREP_W1+PREP_W2+PREP_WN1+PREP_WN2)

__global__ __launch_bounds__(256) void prep_k(
    const float* __restrict__ temb, const float* __restrict__ We1,
    const float* __restrict__ We2,  const float* __restrict__ Wn1,
    const float* __restrict__ Wn2,
    u16* __restrict__ tembH, u16* __restrict__ tembL,
    u16* __restrict__ W1TH, u16* __restrict__ W1TL,
    u16* __restrict__ W2TH, u16* __restrict__ W2TL,
    u16* __restrict__ WN1TH, u16* __restrict__ WN1TL,
    u16* __restrict__ WN2TH, u16* __restrict__ WN2TL)
{
    int i = blockIdx.x*256 + threadIdx.x;
    if (i >= PREP_TOT) return;
    float v; u16 *dh, *dl; int di;
    if (i < PREP_TEMB) {
        v = temb[i]; dh = tembH; dl = tembL; di = i;
    } else if (i < PREP_TEMB + PREP_W1) {
        int j = i - PREP_TEMB; di = j; dh = W1TH; dl = W1TL;
        int l = j / (128*K1); int r = j - l*(128*K1);
        int col = r / K1, k = r - col*K1;
        v = (k < 292) ? We1[(size_t)l*292*128 + (size_t)k*128 + col] : 0.0f;
    } else if (i < PREP_TEMB + PREP_W1 + PREP_W2) {
        int j = i - PREP_TEMB - PREP_W1; di = j; dh = W2TH; dl = W2TL;
        int l = j >> 14; int r = j & 16383;
        int col = r >> 7, k = r & 127;
        v = We2[(size_t)l*16384 + (size_t)k*128 + col];
    } else if (i < PREP_TEMB + PREP_W1 + PREP_W2 + PREP_WN1) {
        int j = i - PREP_TEMB - PREP_W1 - PREP_W2; di = j; dh = WN1TH; dl = WN1TL;
        int l = j >> 15; int r = j & 32767;
        int col = r >> 8, k = r & 255;
        v = Wn1[(size_t)l*32768 + (size_t)k*128 + col];
    } else {
        int j = i - PREP_TEMB - PREP_W1 - PREP_W2 - PREP_WN1; di = j; dh = WN2TH; dl = WN2TL;
        int l = j >> 14; int r = j & 16383;
        int col = r >> 7, k = r & 127;
        v = Wn2[(size_t)l*16384 + (size_t)k*128 + col];
    }
    u16 hb = bf16_rn(v);
    dh[di] = hb;
    dl[di] = bf16_rn(v - bf16_tof(hb));
}

// ---------------------------------------------------------------- embed (8 nodes/block)
__global__ __launch_bounds__(256) void embed_k(
    const float* __restrict__ h, const int* __restrict__ t,
    const float* __restrict__ temb, const float* __restrict__ Win,
    const float* __restrict__ bin, float* __restrict__ hh,
    u16* __restrict__ hhH, u16* __restrict__ hhL)
{
    __shared__ float sIn[8][32];
    const int tid = threadIdx.x;
    {
        const int n = tid >> 5, i = tid & 31;
        const int node = blockIdx.x*8 + n;
        sIn[n][i] = (i < TF) ? h[node*TF + i] : temb[t[node]*TF + (i-TF)];
    }
    __syncthreads();
    const int sub = tid >> 7, col = tid & 127;
    float acc[4];
    const float b = bin[col];
    acc[0]=acc[1]=acc[2]=acc[3]=b;
    #pragma unroll 8
    for (int i = 0; i < 32; ++i) {
        const float wv = Win[i*HID + col];
        acc[0] = fmaf(sIn[sub][i],   wv, acc[0]);
        acc[1] = fmaf(sIn[2+sub][i], wv, acc[1]);
        acc[2] = fmaf(sIn[4+sub][i], wv, acc[2]);
        acc[3] = fmaf(sIn[6+sub][i], wv, acc[3]);
    }
    #pragma unroll
    for (int nn = 0; nn < 4; ++nn) {
        const size_t idx = (size_t)(blockIdx.x*8 + nn*2 + sub)*HID + col;
        hh[idx] = acc[nn];
        u16 hb = bf16_rn(acc[nn]);
        hhH[idx] = hb; hhL[idx] = bf16_rn(acc[nn] - bf16_tof(hb));
    }
}

// ---------------------------------------------------------------- edge
// M=64, P-GEMM hoisting, in-register LN, two-pass GEMM2. LDS 30.5 KB.
__global__ __launch_bounds__(256, 5) void edge_k(
    const u16* __restrict__ hhH, const u16* __restrict__ hhL,
    const float* __restrict__ x,
    const int* __restrict__ ecol, const int* __restrict__ tbond,
    const u16* __restrict__ tembH, const u16* __restrict__ tembL,
    const u16* __restrict__ W1TH, const u16* __restrict__ W1TL,
    const u16* __restrict__ W2TH, const u16* __restrict__ W2TL,
    const float* __restrict__ be1, const float* __restrict__ g1,
    const float* __restrict__ bt1, const float* __restrict__ be2,
    const float* __restrict__ Watt, const float* __restrict__ batt,
    u16* __restrict__ aggH, u16* __restrict__ aggL)
{
    // LDS layout (31232 B):
    //  [0,8192)      tblH (32 atoms x 128 u16)  | later: sB2H (32 rows x 128 u16)
    //  [8192,16384)  tblL                        | later: sB2L
    //  [16384,24576) tail single-bf16 (64 x 64 u16)
    //  [24576,28672) P_lds (8 x 128 f32)
    //  [28672,30720) sStats (64 rows x 4 waves x float2) | later: sAP (256 f32)
    //  [30720,31232) sMuInv (64 x float2)               | later: sAttv (64 f32)
    __shared__ __align__(16) char smem[31232];
    u16*   tblH  = (u16*)(smem);
    u16*   tblL  = (u16*)(smem + 8192);
    u16*   tailB = (u16*)(smem + 16384);
    float* P_lds = (float*)(smem + 24576);
    float* sStats= (float*)(smem + 28672);
    float* sMuInv= (float*)(smem + 30720);
    u16*   sB2H  = (u16*)(smem);
    u16*   sB2L  = (u16*)(smem + 8192);
    float* sAP   = (float*)(smem + 28672);
    float* sAttv = (float*)(smem + 30720);

    const int tid = threadIdx.x;
    const int node0 = blockIdx.x * NPB;
    const int ligBase = node0 & ~31;
    const int aBase   = node0 & 31;      // 0,8,16,24
    const int w = tid >> 6, lane = tid & 63, lr = lane & 15, lh = lane >> 4;
    const int colB0 = w*32 + lr, colB1 = colB0 + 16;

    // ---- per-lane col indices (local atom ids) -------------------------
    int aCol[4];
    #pragma unroll
    for (int rt = 0; rt < 4; ++rt)
        aCol[rt] = ecol[node0*KNN + rt*16 + lr] & 31;

    // ---- stage ligand hh table (32 atoms x 16 chunks, hi/lo) -----------
    for (int idx = tid; idx < 1024; idx += 256) {
        const int hl = idx >> 9, rem = idx & 511;
        const int a = rem >> 4, c4 = rem & 15;
        const bfx8 v = *(const bfx8*)((hl ? hhL : hhH) + (size_t)(ligBase + a)*HID + c4*8);
        u16* dst = hl ? tblL : tblH;
        *(bfx8*)&dst[a*128 + ((c4 ^ (a & 15)) << 3)] = v;
    }

    // ---- tail (single bf16) [64 rows][8 chunks]: temb(2)|smear(3)|0(3) -
    for (int pe = tid; pe < 512; pe += 256) {
        const int row = pe & 63, part = pe >> 6;
        U8 vh;
        if (part < 2) {
            const int r = node0 + (row >> 3);
            const int c = ecol[node0*KNN + row];
            int sbi = r*(KAT-1) + c - (r/KAT)*KAT - (r < c ? 1 : 0);
            const int tb = tbond[sbi];
            #pragma unroll
            for (int j = 0; j < 8; ++j)
                vh.a[j] = tembH[tb*TF + part*8 + j];
        } else if (part < 5) {
            const int r = node0 + (row >> 3);
            const int c = ecol[node0*KNN + row];
            float dx = x[3*r]-x[3*c], dy = x[3*r+1]-x[3*c+1], dz = x[3*r+2]-x[3*c+2];
            float dist = fminf(sqrtf(dx*dx+dy*dy+dz*dz), 4.0f);
            const float Cc = 0.12220674183617694f;   // log2(5)/19
            #pragma unroll
            for (int j = 0; j < 8; ++j) {
                int g = (part-2)*8 + j;
                float v = 0.0f;
                if (g < NG) {
                    float og = exp2f(Cc*(float)g) - 1.0f;
                    int gm = (g > 0) ? g : 1;
                    float d = exp2f(Cc*(float)gm) - exp2f(Cc*(float)(gm-1));
                    float dd = dist - og;
                    v = __expf(-0.5f/(d*d)*dd*dd);
                }
                vh.a[j] = bf16_rn(v);
            }
        } else {
            #pragma unroll
            for (int j = 0; j < 8; ++j) vh.a[j] = 0;
        }
        *(bfx8*)&tailB[row*64 + ((part ^ (row & 7)) << 3)] = vh.v;
    }
    __syncthreads();                                    // bar1

    // ---- GEMM1 (unified 10-step loop, same W slices as before) ---------
    //  s 0..3 : P-GEMM (per-node hoisted hh[row] part, one A fragment)
    //  s 4..7 : per-edge col-hh part (3-product)
    //  s 8..9 : per-edge tail (single-bf16 A, 2-product)
    const u16* bH0 = W1TH + (size_t)colB0*K1 + lh*8;
    const u16* bH1 = W1TH + (size_t)colB1*K1 + lh*8;
    const u16* bL0 = W1TL + (size_t)colB0*K1 + lh*8;
    const u16* bL1 = W1TL + (size_t)colB1*K1 + lh*8;

    f32x4 pw0 = {0,0,0,0}, pw1 = {0,0,0,0};
    f32x4 acc[4][2];
    #pragma unroll
    for (int rt = 0; rt < 4; ++rt) { acc[rt][0] = (f32x4){0,0,0,0}; acc[rt][1] = (f32x4){0,0,0,0}; }
    {
        bfx8 wh0 = *(const bfx8*)bH0, wh1 = *(const bfx8*)bH1;
        bfx8 wl0 = *(const bfx8*)bL0, wl1 = *(const bfx8*)bL1;
        #pragma unroll
        for (int s = 0; s < 10; ++s) {
            bfx8 nh0 = wh0, nh1 = wh1, nl0 = wl0, nl1 = wl1;
            if (s < 9) {
                nh0 = *(const bfx8*)(bH0 + 32*(s+1)); nh1 = *(const bfx8*)(bH1 + 32*(s+1));
                nl0 = *(const bfx8*)(bL0 + 32*(s+1)); nl1 = *(const bfx8*)(bL1 + 32*(s+1));
            }
            if (s < 4) {
                const int aR = aBase + (lr & 7);         // rows 8..15 = dupes, unused
                const int c4 = s*4 + lh;
                const int ad = aR*128 + ((c4 ^ (aR & 15)) << 3);
                const bfx8 ah = *(const bfx8*)&tblH[ad];
                const bfx8 al = *(const bfx8*)&tblL[ad];
                pw0 = mfma3(ah, al, wh0, wl0, pw0);
                pw1 = mfma3(ah, al, wh1, wl1, pw1);
            } else if (s < 8) {
                #pragma unroll
                for (int rt = 0; rt < 4; ++rt) {
                    const int aC = aCol[rt];
                    const int c4 = (s-4)*4 + lh;
                    const int ad = aC*128 + ((c4 ^ (aC & 15)) << 3);
                    const bfx8 ah = *(const bfx8*)&tblH[ad];
                    const bfx8 al = *(const bfx8*)&tblL[ad];
                    acc[rt][0] = mfma3(ah, al, wh0, wl0, acc[rt][0]);
                    acc[rt][1] = mfma3(ah, al, wh1, wl1, acc[rt][1]);
                }
            } else {
                #pragma unroll
                for (int rt = 0; rt < 4; ++rt) {
                    const int r = rt*16 + lr;
                    const int c = (s-8)*4 + lh;
                    const int ad = r*64 + ((c ^ (r & 7)) << 3);
                    const bfx8 ah = *(const bfx8*)&tailB[ad];
                    acc[rt][0] = mfma2(ah, wh0, wl0, acc[rt][0]);
                    acc[rt][1] = mfma2(ah, wh1, wl1, acc[rt][1]);
                }
            }
            wh0 = nh0; wh1 = nh1; wl0 = nl0; wl1 = nl1;
        }
    }
    // write P (rows 0..7 = nodes; 8..15 dupes skipped)
    if (lh < 2) {
        #pragma unroll
        for (int j = 0; j < 4; ++j) {
            P_lds[(4*lh + j)*128 + colB0] = pw0[j];
            P_lds[(4*lh + j)*128 + colB1] = pw1[j];
        }
    }
    __syncthreads();                                    // bar2 (tbl/tail reads + P writes done)

    // ---- inject P + bias; in-register LN partials ----------------------
    {
        const float b10 = be1[colB0], b11 = be1[colB1];
        const int n = (lh >> 1);
        #pragma unroll
        for (int rt = 0; rt < 4; ++rt) {
            const float p0 = P_lds[(rt*2 + n)*128 + colB0] + b10;
            const float p1 = P_lds[(rt*2 + n)*128 + colB1] + b11;
            #pragma unroll
            for (int j = 0; j < 4; ++j) { acc[rt][0][j] += p0; acc[rt][1][j] += p1; }
        }
    }
    {
        #pragma unroll
        for (int rt = 0; rt < 4; ++rt) {
            float sv[4], qv[4];
            #pragma unroll
            for (int j = 0; j < 4; ++j) {
                const float a0 = acc[rt][0][j], a1 = acc[rt][1][j];
                sv[j] = a0 + a1; qv[j] = a0*a0 + a1*a1;
            }
            #pragma unroll
            for (int msk = 1; msk < 16; msk <<= 1) {
                #pragma unroll
                for (int j = 0; j < 4; ++j) {
                    sv[j] += __shfl_xor(sv[j], msk);
                    qv[j] += __shfl_xor(qv[j], msk);
                }
            }
            if (lr == 0) {
                #pragma unroll
                for (int j = 0; j < 4; ++j) {
                    const int row = rt*16 + 4*lh + j;
                    sStats[(row*4 + w)*2 + 0] = sv[j];
                    sStats[(row*4 + w)*2 + 1] = qv[j];
                }
            }
        }
    }
    __syncthreads();                                    // bar3

    if (tid < EPB) {
        const float4 a = *(const float4*)&sStats[tid*8];
        const float4 b = *(const float4*)&sStats[tid*8 + 4];
        const float st = a.x + a.z + b.x + b.z;
        const float qt = a.y + a.w + b.y + b.w;
        const float mu  = st * (1.0f/HID);
        const float var = qt * (1.0f/HID) - mu*mu;
        sMuInv[tid*2 + 0] = mu;
        sMuInv[tid*2 + 1] = rsqrtf(var + 1e-5f);
    }
    __syncthreads();                                    // bar4

    // ---- normalize + SiLU in place -------------------------------------
    {
        const float G0 = g1[colB0], G1s = g1[colB1];
        const float B0 = bt1[colB0], B1s = bt1[colB1];
        #pragma unroll
        for (int rt = 0; rt < 4; ++rt) {
            const int r0 = rt*16 + 4*lh;
            const float4 mi0 = *(const float4*)&sMuInv[r0*2];      // mu0,inv0,mu1,inv1
            const float4 mi1 = *(const float4*)&sMuInv[r0*2 + 4];  // mu2,inv2,mu3,inv3
            acc[rt][0][0] = siluf(fmaf((acc[rt][0][0]-mi0.x)*mi0.y, G0, B0));
            acc[rt][1][0] = siluf(fmaf((acc[rt][1][0]-mi0.x)*mi0.y, G1s, B1s));
            acc[rt][0][1] = siluf(fmaf((acc[rt][0][1]-mi0.z)*mi0.w, G0, B0));
            acc[rt][1][1] = siluf(fmaf((acc[rt][1][1]-mi0.z)*mi0.w, G1s, B1s));
            acc[rt][0][2] = siluf(fmaf((acc[rt][0][2]-mi1.x)*mi1.y, G0, B0));
            acc[rt][1][2] = siluf(fmaf((acc[rt][1][2]-mi1.x)*mi1.y, G1s, B1s));
            acc[rt][0][3] = siluf(fmaf((acc[rt][0][3]-mi1.z)*mi1.w, G0, B0));
            acc[rt][1][3] = siluf(fmaf((acc[rt][1][3]-mi1.z)*mi1.w, G1s, B1s));
        }
    }

    // ---- GEMM2 in two 32-row passes (sB2 = 16 KB, aliases tbl) ---------
    f32x4 d[4][2];
    #pragma unroll
    for (int rt = 0; rt < 4; ++rt) { d[rt][0] = (f32x4){0,0,0,0}; d[rt][1] = (f32x4){0,0,0,0}; }

    const u16* c2H0 = W2TH + (size_t)colB0*HID + lh*8;
    const u16* c2H1 = W2TH + (size_t)colB1*HID + lh*8;
    const u16* c2L0 = W2TL + (size_t)colB0*HID + lh*8;
    const u16* c2L1 = W2TL + (size_t)colB1*HID + lh*8;

    #pragma unroll
    for (int p = 0; p < 2; ++p) {
        // write rows [p*32, p*32+32) of post-LN acts as bf16 hi/lo
        #pragma unroll
        for (int rr = 0; rr < 2; ++rr) {
            const int rt = 2*p + rr;
            #pragma unroll
            for (int hcol = 0; hcol < 2; ++hcol) {
                const int col = hcol ? colB1 : colB0;
                const int gch = col >> 3, cw = col & 7;
                #pragma unroll
                for (int j = 0; j < 4; ++j) {
                    const int rowL = rr*16 + 4*lh + j;
                    const int ad = rowL*128 + (((gch) ^ (rowL & 15)) << 3) + cw;
                    const float v = acc[rt][hcol][j];
                    const u16 hb = bf16_rn(v);
                    sB2H[ad] = hb;
                    sB2L[ad] = bf16_rn(v - bf16_tof(hb));
                }
            }
        }
        __syncthreads();                                // bar5 / bar7
        {
            bfx8 wh0 = *(const bfx8*)c2H0, wh1 = *(const bfx8*)c2H1;
            bfx8 wl0 = *(const bfx8*)c2L0, wl1 = *(const bfx8*)c2L1;
            #pragma unroll
            for (int s = 0; s < 4; ++s) {
                bfx8 nh0 = wh0, nh1 = wh1, nl0 = wl0, nl1 = wl1;
                if (s < 3) {
                    nh0 = *(const bfx8*)(c2H0 + 32*(s+1)); nh1 = *(const bfx8*)(c2H1 + 32*(s+1));
                    nl0 = *(const bfx8*)(c2L0 + 32*(s+1)); nl1 = *(const bfx8*)(c2L1 + 32*(s+1));
                }
                #pragma unroll
                for (int rr = 0; rr < 2; ++rr) {
                    const int rowL = rr*16 + lr;
                    const int c4 = s*4 + lh;
                    const int ad = rowL*128 + ((c4 ^ lr) << 3);
                    const bfx8 ah = *(const bfx8*)&sB2H[ad];
                    const bfx8 al = *(const bfx8*)&sB2L[ad];
                    d[2*p+rr][0] = mfma3(ah, al, wh0, wl0, d[2*p+rr][0]);
                    d[2*p+rr][1] = mfma3(ah, al, wh1, wl1, d[2*p+rr][1]);
                }
                wh0 = nh0; wh1 = nh1; wl0 = nl0; wl1 = nl1;
            }
        }
        if (p == 0) __syncthreads();                    // bar6 (reads done before pass-2 writes)
    }

    // ---- SiLU + attention gate -----------------------------------------
    float m[4][2][4];
    {
        const float b20 = be2[colB0], b21 = be2[colB1];
        #pragma unroll
        for (int rt = 0; rt < 4; ++rt) {
            #pragma unroll
            for (int j = 0; j < 4; ++j) {
                m[rt][0][j] = siluf(d[rt][0][j] + b20);
                m[rt][1][j] = siluf(d[rt][1][j] + b21);
            }
        }
    }
    {
        const float wa0 = Watt[colB0], wa1 = Watt[colB1];
        float pa[4][4];
        #pragma unroll
        for (int rt = 0; rt < 4; ++rt)
            #pragma unroll
            for (int j = 0; j < 4; ++j)
                pa[rt][j] = m[rt][0][j]*wa0 + m[rt][1][j]*wa1;
        #pragma unroll
        for (int msk = 1; msk < 16; msk <<= 1) {
            #pragma unroll
            for (int rt = 0; rt < 4; ++rt)
                #pragma unroll
                for (int j = 0; j < 4; ++j)
                    pa[rt][j] += __shfl_xor(pa[rt][j], msk);
        }
        if (lr == 0) {
            #pragma unroll
            for (int rt = 0; rt < 4; ++rt)
                #pragma unroll
                for (int j = 0; j < 4; ++j)
                    sAP[w*64 + rt*16 + 4*lh + j] = pa[rt][j];
        }
    }
    __syncthreads();                                    // bar8
    if (tid < EPB)
        sAttv[tid] = sigf(sAP[tid] + sAP[64+tid] + sAP[128+tid] + sAP[192+tid] + batt[0]);
    __syncthreads();                                    // bar9

    // ---- gated aggregate -> aggH/aggL ----------------------------------
    #pragma unroll
    for (int rt = 0; rt < 4; ++rt) {
        float s0 = 0.0f, s1 = 0.0f;
        #pragma unroll
        for (int j = 0; j < 4; ++j) {
            const float av = sAttv[rt*16 + 4*lh + j];
            s0 += m[rt][0][j]*av;
            s1 += m[rt][1][j]*av;
        }
        s0 += __shfl_xor(s0, 16);
        s1 += __shfl_xor(s1, 16);
        if ((lh & 1) == 0) {
            const int node = node0 + 2*rt + (lh >> 1);
            wragg(aggH, aggL, (size_t)node*HID + colB0, s0*0.2f);
            wragg(aggH, aggL, (size_t)node*HID + colB1, s1*0.2f);
        }
    }
}

// ---------------------------------------------------------------- node (MFMA, 32 nodes/block)
__global__ __launch_bounds__(256, 6) void node_k(
    float* __restrict__ hh, u16* __restrict__ hhH, u16* __restrict__ hhL,
    const u16* __restrict__ aggH, const u16* __restrict__ aggL,
    const u16* __restrict__ B1H, const u16* __restrict__ B1L,
    const u16* __restrict__ B2H, const u16* __restrict__ B2L,
    const float* __restrict__ bn1, const float* __restrict__ g2,
    const float* __restrict__ bt2, const float* __restrict__ bn2)
{
    __shared__ __align__(16) char smem[16896];
    float* sMid = (float*)smem;
    u16* sYH = (u16*)smem;
    u16* sYL = (u16*)(smem + 8192);

    const int tid = threadIdx.x;
    const int node0 = blockIdx.x * 32;
    const int w = tid >> 6, lane = tid & 63, lr = lane & 15, lh = lane >> 4;
    const int colB0 = w*32 + lr, colB1 = colB0 + 16;

    const u16* a1h0 = hhH  + (size_t)(node0+lr)*HID + lh*8;
    const u16* a1l0 = hhL  + (size_t)(node0+lr)*HID + lh*8;
    const u16* a2h0 = aggH + (size_t)(node0+lr)*HID + lh*8;
    const u16* a2l0 = aggL + (size_t)(node0+lr)*HID + lh*8;
    const u16* c1H0 = B1H + (size_t)colB0*256 + lh*8;
    const u16* c1H1 = B1H + (size_t)colB1*256 + lh*8;
    const u16* c1L0 = B1L + (size_t)colB0*256 + lh*8;
    const u16* c1L1 = B1L + (size_t)colB1*256 + lh*8;

    f32x4 acc00={0,0,0,0}, acc01={0,0,0,0}, acc10={0,0,0,0}, acc11={0,0,0,0};
    {
        bfx8 wh0 = *(const bfx8*)c1H0, wh1 = *(const bfx8*)c1H1;
        bfx8 wl0 = *(const bfx8*)c1L0, wl1 = *(const bfx8*)c1L1;
        #pragma unroll
        for (int s = 0; s < 8; ++s) {
            bfx8 nh0 = wh0, nh1 = wh1, nl0 = wl0, nl1 = wl1;
            if (s < 7) {
                nh0 = *(const bfx8*)(c1H0 + 32*(s+1)); nh1 = *(const bfx8*)(c1H1 + 32*(s+1));
                nl0 = *(const bfx8*)(c1L0 + 32*(s+1)); nl1 = *(const bfx8*)(c1L1 + 32*(s+1));
            }
            bfx8 ah0, ah1, al0, al1;
            if (s < 4) {
                ah0 = *(const bfx8*)(a1h0 + 32*s);            ah1 = *(const bfx8*)(a1h0 + 16*HID + 32*s);
                al0 = *(const bfx8*)(a1l0 + 32*s);            al1 = *(const bfx8*)(a1l0 + 16*HID + 32*s);
            } else {
                ah0 = *(const bfx8*)(a2h0 + 32*(s-4));        ah1 = *(const bfx8*)(a2h0 + 16*HID + 32*(s-4));
                al0 = *(const bfx8*)(a2l0 + 32*(s-4));        al1 = *(const bfx8*)(a2l0 + 16*HID + 32*(s-4));
            }
            acc00 = mfma3(ah0, al0, wh0, wl0, acc00);
            acc01 = mfma3(ah0, al0, wh1, wl1, acc01);
            acc10 = mfma3(ah1, al1, wh0, wl0, acc10);
            acc11 = mfma3(ah1, al1, wh1, wl1, acc11);
            wh0 = nh0; wh1 = nh1; wl0 = nl0; wl1 = nl1;
        }
    }
    {
        const float b10 = bn1[colB0], b11 = bn1[colB1];
        #pragma unroll
        for (int j = 0; j < 4; ++j) {
            const int r0 = 4*lh + j;
            sMid[r0*MIDSTR + colB0]      = acc00[j] + b10;
            sMid[r0*MIDSTR + colB1]      = acc01[j] + b11;
            sMid[(16+r0)*MIDSTR + colB0] = acc10[j] + b10;
            sMid[(16+r0)*MIDSTR + colB1] = acc11[j] + b11;
        }
    }
    __syncthreads();

    float y[16];
    const int eLN = tid >> 3, c0 = (tid & 7)*16;
    {
        const float* mrow = &sMid[eLN*MIDSTR + c0];
        float4 v0 = *(const float4*)&mrow[0];
        float4 v1 = *(const float4*)&mrow[4];
        float4 v2 = *(const float4*)&mrow[8];
        float4 v3 = *(const float4*)&mrow[12];
        float s = v0.x+v0.y+v0.z+v0.w + v1.x+v1.y+v1.z+v1.w
                + v2.x+v2.y+v2.z+v2.w + v3.x+v3.y+v3.z+v3.w;
        float q = v0.x*v0.x+v0.y*v0.y+v0.z*v0.z+v0.w*v0.w
                + v1.x*v1.x+v1.y*v1.y+v1.z*v1.z+v1.w*v1.w
                + v2.x*v2.x+v2.y*v2.y+v2.z*v2.z+v2.w*v2.w
                + v3.x*v3.x+v3.y*v3.y+v3.z*v3.z+v3.w*v3.w;
        #pragma unroll
        for (int m = 4; m >= 1; m >>= 1) { s += __shfl_xor(s, m); q += __shfl_xor(q, m); }
        float mu  = s * (1.0f/HID);
        float var = q * (1.0f/HID) - mu*mu;
        float inv = rsqrtf(var + 1e-5f);
        const float4 G0 = *(const float4*)&g2[c0+0],  G1v = *(const float4*)&g2[c0+4];
        const float4 G2 = *(const float4*)&g2[c0+8],  G3 = *(const float4*)&g2[c0+12];
        const float4 B0 = *(const float4*)&bt2[c0+0], B1 = *(const float4*)&bt2[c0+4];
        const float4 B2 = *(const float4*)&bt2[c0+8], B3 = *(const float4*)&bt2[c0+12];
        y[0]=siluf(fmaf((v0.x-mu)*inv,G0.x,B0.x));  y[1]=siluf(fmaf((v0.y-mu)*inv,G0.y,B0.y));
        y[2]=siluf(fmaf((v0.z-mu)*inv,G0.z,B0.z));  y[3]=siluf(fmaf((v0.w-mu)*inv,G0.w,B0.w));
        y[4]=siluf(fmaf((v1.x-mu)*inv,G1v.x,B1.x)); y[5]=siluf(fmaf((v1.y-mu)*inv,G1v.y,B1.y));
        y[6]=siluf(fmaf((v1.z-mu)*inv,G1v.z,B1.z)); y[7]=siluf(fmaf((v1.w-mu)*inv,G1v.w,B1.w));
        y[8]=siluf(fmaf((v2.x-mu)*inv,G2.x,B2.x));  y[9]=siluf(fmaf((v2.y-mu)*inv,G2.y,B2.y));
        y[10]=siluf(fmaf((v2.z-mu)*inv,G2.z,B2.z)); y[11]=siluf(fmaf((v2.w-mu)*inv,G2.w,B2.w));
        y[12]=siluf(fmaf((v3.x-mu)*inv,G3.x,B3.x)); y[13]=siluf(fmaf((v3.y-mu)*inv,G3.y,B3.y));
        y[14]=siluf(fmaf((v3.z-mu)*inv,G3.z,B3.z)); y[15]=siluf(fmaf((v3.w-mu)*inv,G3.w,B3.w));
    }
    __syncthreads();
    {
        U8 ha, hb2, la, lb2;
        #pragma unroll
        for (int j = 0; j < 8; ++j) {
            u16 t0 = bf16_rn(y[j]);   ha.a[j]  = t0; la.a[j]  = bf16_rn(y[j]   - bf16_tof(t0));
            u16 t1 = bf16_rn(y[8+j]); hb2.a[j] = t1; lb2.a[j] = bf16_rn(y[8+j] - bf16_tof(t1));
        }
        const int cA = (2*(tid & 7))     ^ (eLN & 15);
        const int cB = (2*(tid & 7) + 1) ^ (eLN & 15);
        *(bfx8*)&sYH[eLN*128 + (cA << 3)] = ha.v;
        *(bfx8*)&sYH[eLN*128 + (cB << 3)] = hb2.v;
        *(bfx8*)&sYL[eLN*128 + (cA << 3)] = la.v;
        *(bfx8*)&sYL[eLN*128 + (cB << 3)] = lb2.v;
    }
    __syncthreads();

    f32x4 d00={0,0,0,0}, d01={0,0,0,0}, d10={0,0,0,0}, d11={0,0,0,0};
    {
        const u16* c2H0 = B2H + (size_t)colB0*HID + lh*8;
        const u16* c2H1 = B2H + (size_t)colB1*HID + lh*8;
        const u16* c2L0 = B2L + (size_t)colB0*HID + lh*8;
        const u16* c2L1 = B2L + (size_t)colB1*HID + lh*8;
        bfx8 wh0 = *(const bfx8*)c2H0, wh1 = *(const bfx8*)c2H1;
        bfx8 wl0 = *(const bfx8*)c2L0, wl1 = *(const bfx8*)c2L1;
        #pragma unroll
        for (int s = 0; s < 4; ++s) {
            bfx8 nh0 = wh0, nh1 = wh1, nl0 = wl0, nl1 = wl1;
            if (s < 3) {
                nh0 = *(const bfx8*)(c2H0 + 32*(s+1)); nh1 = *(const bfx8*)(c2H1 + 32*(s+1));
                nl0 = *(const bfx8*)(c2L0 + 32*(s+1)); nl1 = *(const bfx8*)(c2L1 + 32*(s+1));
            }
            const int c4 = s*4 + lh;
            const int i0 = lr*128 + ((c4 ^ lr) << 3);
            const int i1 = (16+lr)*128 + ((c4 ^ lr) << 3);
            bfx8 ah0 = *(const bfx8*)&sYH[i0], ah1 = *(const bfx8*)&sYH[i1];
            bfx8 al0 = *(const bfx8*)&sYL[i0], al1 = *(const bfx8*)&sYL[i1];
            d00 = mfma3(ah0, al0, wh0, wl0, d00);
            d01 = mfma3(ah0, al0, wh1, wl1, d01);
            d10 = mfma3(ah1, al1, wh0, wl0, d10);
            d11 = mfma3(ah1, al1, wh1, wl1, d11);
            wh0 = nh0; wh1 = nh1; wl0 = nl0; wl1 = nl1;
        }
    }

    {
        const float b20 = bn2[colB0], b21 = bn2[colB1];
        #pragma unroll
        for (int j = 0; j < 4; ++j) {
            const int r0 = 4*lh + j, r1 = 16 + 4*lh + j;
            const size_t i00 = (size_t)(node0+r0)*HID + colB0;
            const size_t i01 = (size_t)(node0+r0)*HID + colB1;
            const size_t i10 = (size_t)(node0+r1)*HID + colB0;
            const size_t i11 = (size_t)(node0+r1)*HID + colB1;
            float v00 = hh[i00] + d00[j] + b20;
            float v01 = hh[i01] + d01[j] + b21;
            float v10 = hh[i10] + d10[j] + b20;
            float v11 = hh[i11] + d11[j] + b21;
            hh[i00] = v00; hh[i01] = v01; hh[i10] = v10; hh[i11] = v11;
            u16 h00 = bf16_rn(v00); hhH[i00] = h00; hhL[i00] = bf16_rn(v00 - bf16_tof(h00));
            u16 h01 = bf16_rn(v01); hhH[i01] = h01; hhL[i01] = bf16_rn(v01 - bf16_tof(h01));
            u16 h10 = bf16_rn(v10); hhH[i10] = h10; hhL[i10] = bf16_rn(v10 - bf16_tof(h10));
            u16 h11 = bf16_rn(v11); hhH[i11] = h11; hhL[i11] = bf16_rn(v11 - bf16_tof(h11));
        }
    }
}

// ---------------------------------------------------------------- output head
__global__ __launch_bounds__(HID) void out_k(
    const float* __restrict__ hh, const float* __restrict__ Woe,
    const float* __restrict__ boe, const float* __restrict__ Wf,
    const float* __restrict__ bf, float* __restrict__ out)
{
    __shared__ float sH[HID];
    const int lig = blockIdx.x, tid = threadIdx.x;
    float s = 0.0f;
    const float* base = hh + (size_t)lig*KAT*HID + tid;
    #pragma unroll 8
    for (int a = 0; a < KAT; ++a) s += base[a*HID];
    sH[tid] = s * (1.0f/KAT);
    __syncthreads();

    float contrib = 0.0f;
    if (tid < OUTF) {
        float p = boe[tid];
        #pragma unroll 4
        for (int i = 0; i < HID; ++i)
            p = fmaf(sH[i], Woe[i*OUTF + tid], p);
        contrib = p * Wf[tid];
    }
    #pragma unroll
    for (int m = 1; m < 64; m <<= 1) contrib += __shfl_xor(contrib, m);
    if (tid == 0) out[lig] = contrib + bf[0];
}

// ---------------------------------------------------------------- launch
extern "C" void kernel_launch(void* const* d_in, const int* in_sizes, int n_in,
                              void* d_out, int out_size, void* d_ws, size_t ws_size,
                              hipStream_t stream)
{
    (void)in_sizes; (void)n_in; (void)out_size; (void)ws_size;
    const float* x    = (const float*)d_in[0];
    const float* h    = (const float*)d_in[1];
    const int*   t    = (const int*)d_in[2];
    const int*   edges= (const int*)d_in[3];
    const int*   tb   = (const int*)d_in[4];
    const float* temb = (const float*)d_in[8];
    const float* Win  = (const float*)d_in[9];
    const float* bin  = (const float*)d_in[10];
    const float* We1  = (const float*)d_in[11];
    const float* be1  = (const float*)d_in[12];
    const float* g1   = (const float*)d_in[13];
    const float* bt1  = (const float*)d_in[14];
    const float* We2  = (const float*)d_in[15];
    const float* be2  = (const float*)d_in[16];
    const float* Watt = (const float*)d_in[17];
    const float* batt = (const float*)d_in[18];
    const float* Wn1  = (const float*)d_in[19];
    const float* bn1  = (const float*)d_in[20];
    const float* g2   = (const float*)d_in[21];
    const float* bt2  = (const float*)d_in[22];
    const float* Wn2  = (const float*)d_in[23];
    const float* bn2  = (const float*)d_in[24];
    const float* Woe  = (const float*)d_in[25];
    const float* boe  = (const float*)d_in[26];
    const float* Wf   = (const float*)d_in[27];
    const float* bf   = (const float*)d_in[28];
    float* out = (float*)d_out;

    char* wsb = (char*)d_ws;
    float* hh  = (float*)(wsb);                        // 16 MB
    u16* hhH   = (u16*)(wsb + ((size_t)16<<20));       // 8 MB
    u16* hhL   = (u16*)(wsb + ((size_t)24<<20));       // 8 MB
    u16* aggH  = (u16*)(wsb + ((size_t)32<<20));       // 8 MB
    u16* aggL  = (u16*)(wsb + ((size_t)40<<20));       // 8 MB
    u16* tembH = (u16*)(wsb + ((size_t)48<<20));
    u16* tembL = tembH + PREP_TEMB;
    u16* W1TH  = tembL + PREP_TEMB;
    u16* W1TL  = W1TH + PREP_W1;
    u16* W2TH  = W1TL + PREP_W1;
    u16* W2TL  = W2TH + PREP_W2;
    u16* WN1TH = W2TL + PREP_W2;
    u16* WN1TL = WN1TH + PREP_WN1;
    u16* WN2TH = WN1TL + PREP_WN1;
    u16* WN2TL = WN2TH + PREP_WN2;

    prep_k<<<(PREP_TOT + 255)/256, 256, 0, stream>>>(
        temb, We1, We2, Wn1, Wn2,
        tembH, tembL, W1TH, W1TL, W2TH, W2TL, WN1TH, WN1TL, WN2TH, WN2TL);

    embed_k<<<NNODES/8, 256, 0, stream>>>(h, t, temb, Win, bin, hh, hhH, hhL);

    for (int l = 0; l < 4; ++l) {
        edge_k<<<NNODES/NPB, 256, 0, stream>>>(
            hhH, hhL, x, edges + NEDGES, tb, tembH, tembL,
            W1TH + (size_t)l*128*K1, W1TL + (size_t)l*128*K1,
            W2TH + (size_t)l*128*128, W2TL + (size_t)l*128*128,
            be1 + l*HID, g1 + l*HID, bt1 + l*HID, be2 + l*HID,
            Watt + l*HID, batt + l, aggH, aggL);
        node_k<<<NNODES/32, 256, 0, stream>>>(
            hh, hhH, hhL, aggH, aggL,
            WN1TH + (size_t)l*128*256, WN1TL + (size_t)l*128*256,
            WN2TH + (size_t)l*128*128, WN2TL + (size_t)l*128*128,
            bn1 + l*HID, g2 + l*HID, bt2 + l*HID, bn2 + l*HID);
    }
    out_k<<<NLIG, HID, 0, stream>>>(hh, Woe, boe, Wf, bf, out);
}

// Round 8
// 851.275 us; speedup vs baseline: 1.1078x; 1.1078x over previous
//
#include <hip/hip_runtime.h>
#include <math.h>

#define NNODES 32768
#define NLIG   1024
#define KAT    32
#define KNN    8
#define NEDGES (NNODES*KNN)
#define HID    128
#define TF     16
#define NG     20
#define OUTF   64

#define NPB    8            // nodes per edge-block
#define EPB    64           // edges per edge-block
#define K1     320          // padded GEMM1 K (292 -> 320)
#define MIDSTR 132          // node_k sMid row stride (floats)

typedef unsigned short u16;
typedef __attribute__((__ext_vector_type__(8))) short bfx8;
typedef __attribute__((__ext_vector_type__(4))) float f32x4;

union U8 { u16 a[8]; bfx8 v; };

__device__ __forceinline__ float siluf(float v) {
    return __fdividef(v, 1.0f + __expf(-v));
}
__device__ __forceinline__ float sigf(float v) {
    return __fdividef(1.0f, 1.0f + __expf(-v));
}
__device__ __forceinline__ u16 bf16_rn(float f) {
    union { float f; unsigned u; } v; v.f = f;
    unsigned r = v.u + 0x7FFFu + ((v.u >> 16) & 1u);
    return (u16)(r >> 16);
}
__device__ __forceinline__ float bf16_tof(u16 u) {
    union { unsigned u; float f; } v; v.u = ((unsigned)u) << 16;
    return v.f;
}
__device__ __forceinline__ f32x4 mfma3(bfx8 ah, bfx8 al, bfx8 wh, bfx8 wl, f32x4 c) {
    c = __builtin_amdgcn_mfma_f32_16x16x32_bf16(ah, wh, c, 0, 0, 0);
    c = __builtin_amdgcn_mfma_f32_16x16x32_bf16(ah, wl, c, 0, 0, 0);
    c = __builtin_amdgcn_mfma_f32_16x16x32_bf16(al, wh, c, 0, 0, 0);
    return c;
}
__device__ __forceinline__ f32x4 mfma2(bfx8 ah, bfx8 wh, bfx8 wl, f32x4 c) {
    c = __builtin_amdgcn_mfma_f32_16x16x32_bf16(ah, wh, c, 0, 0, 0);
    c = __builtin_amdgcn_mfma_f32_16x16x32_bf16(ah, wl, c, 0, 0, 0);
    return c;
}
__device__ __forceinline__ void wragg(u16* __restrict__ H, u16* __restrict__ L,
                                      size_t i, float v) {
    u16 hb = bf16_rn(v);
    H[i] = hb; L[i] = bf16_rn(v - bf16_tof(hb));
}

// ---------------------------------------------------------------- prep
#define PREP_TEMB 16000
#define PREP_W1   (4*128*K1)       // 163840
#define PREP_W2   (4*128*128)      // 65536
#define PREP_WN1  (4*128*256)      // 131072
#define PREP_WN2  (4*128*128)      // 65536
#define PREP_TOT  (PREP_TEMB+PREP_W1+PREP_W2+PREP_WN1+PREP_WN2)

__global__ __launch_bounds__(256) void prep_k(
    const float* __restrict__ temb, const float* __restrict__ We1,
    const float* __restrict__ We2,  const float* __restrict__ Wn1,
    const float* __restrict__ Wn2,
    u16* __restrict__ tembH, u16* __restrict__ tembL,
    u16* __restrict__ W1TH, u16* __restrict__ W1TL,
    u16* __restrict__ W2TH, u16* __restrict__ W2TL,
    u16* __restrict__ WN1TH, u16* __restrict__ WN1TL,
    u16* __restrict__ WN2TH, u16* __restrict__ WN2TL)
{
    int i = blockIdx.x*256 + threadIdx.x;
    if (i >= PREP_TOT) return;
    float v; u16 *dh, *dl; int di;
    if (i < PREP_TEMB) {
        v = temb[i]; dh = tembH; dl = tembL; di = i;
    } else if (i < PREP_TEMB + PREP_W1) {
        int j = i - PREP_TEMB; di = j; dh = W1TH; dl = W1TL;
        int l = j / (128*K1); int r = j - l*(128*K1);
        int col = r / K1, k = r - col*K1;
        v = (k < 292) ? We1[(size_t)l*292*128 + (size_t)k*128 + col] : 0.0f;
    } else if (i < PREP_TEMB + PREP_W1 + PREP_W2) {
        int j = i - PREP_TEMB - PREP_W1; di = j; dh = W2TH; dl = W2TL;
        int l = j >> 14; int r = j & 16383;
        int col = r >> 7, k = r & 127;
        v = We2[(size_t)l*16384 + (size_t)k*128 + col];
    } else if (i < PREP_TEMB + PREP_W1 + PREP_W2 + PREP_WN1) {
        int j = i - PREP_TEMB - PREP_W1 - PREP_W2; di = j; dh = WN1TH; dl = WN1TL;
        int l = j >> 15; int r = j & 32767;
        int col = r >> 8, k = r & 255;
        v = Wn1[(size_t)l*32768 + (size_t)k*128 + col];
    } else {
        int j = i - PREP_TEMB - PREP_W1 - PREP_W2 - PREP_WN1; di = j; dh = WN2TH; dl = WN2TL;
        int l = j >> 14; int r = j & 16383;
        int col = r >> 7, k = r & 127;
        v = Wn2[(size_t)l*16384 + (size_t)k*128 + col];
    }
    u16 hb = bf16_rn(v);
    dh[di] = hb;
    dl[di] = bf16_rn(v - bf16_tof(hb));
}

// ---------------------------------------------------------------- embed (8 nodes/block)
__global__ __launch_bounds__(256) void embed_k(
    const float* __restrict__ h, const int* __restrict__ t,
    const float* __restrict__ temb, const float* __restrict__ Win,
    const float* __restrict__ bin, float* __restrict__ hh,
    u16* __restrict__ hhH, u16* __restrict__ hhL)
{
    __shared__ float sIn[8][32];
    const int tid = threadIdx.x;
    {
        const int n = tid >> 5, i = tid & 31;
        const int node = blockIdx.x*8 + n;
        sIn[n][i] = (i < TF) ? h[node*TF + i] : temb[t[node]*TF + (i-TF)];
    }
    __syncthreads();
    const int sub = tid >> 7, col = tid & 127;
    float acc[4];
    const float b = bin[col];
    acc[0]=acc[1]=acc[2]=acc[3]=b;
    #pragma unroll 8
    for (int i = 0; i < 32; ++i) {
        const float wv = Win[i*HID + col];
        acc[0] = fmaf(sIn[sub][i],   wv, acc[0]);
        acc[1] = fmaf(sIn[2+sub][i], wv, acc[1]);
        acc[2] = fmaf(sIn[4+sub][i], wv, acc[2]);
        acc[3] = fmaf(sIn[6+sub][i], wv, acc[3]);
    }
    #pragma unroll
    for (int nn = 0; nn < 4; ++nn) {
        const size_t idx = (size_t)(blockIdx.x*8 + nn*2 + sub)*HID + col;
        hh[idx] = acc[nn];
        u16 hb = bf16_rn(acc[nn]);
        hhH[idx] = hb; hhL[idx] = bf16_rn(acc[nn] - bf16_tof(hb));
    }
}

// ---------------------------------------------------------------- edge
// M=64, P-GEMM hoisting, in-register LN, two-pass GEMM2. LDS 30.5 KB.
// __launch_bounds__(256,4): VGPR cap 128 — (256,5) spilled (round-7 regression:
// VGPR squeezed to 48, WRITE_SIZE 16->114 MB of scratch traffic).
__global__ __launch_bounds__(256, 4) void edge_k(
    const u16* __restrict__ hhH, const u16* __restrict__ hhL,
    const float* __restrict__ x,
    const int* __restrict__ ecol, const int* __restrict__ tbond,
    const u16* __restrict__ tembH, const u16* __restrict__ tembL,
    const u16* __restrict__ W1TH, const u16* __restrict__ W1TL,
    const u16* __restrict__ W2TH, const u16* __restrict__ W2TL,
    const float* __restrict__ be1, const float* __restrict__ g1,
    const float* __restrict__ bt1, const float* __restrict__ be2,
    const float* __restrict__ Watt, const float* __restrict__ batt,
    u16* __restrict__ aggH, u16* __restrict__ aggL)
{
    // LDS layout (31232 B):
    //  [0,8192)      tblH (32 atoms x 128 u16)  | later: sB2H (32 rows x 128 u16)
    //  [8192,16384)  tblL                        | later: sB2L
    //  [16384,24576) tail single-bf16 (64 x 64 u16)
    //  [24576,28672) P_lds (8 x 128 f32)
    //  [28672,30720) sStats (64 rows x 4 waves x float2) | later: sAP (256 f32)
    //  [30720,31232) sMuInv (64 x float2)               | later: sAttv (64 f32)
    __shared__ __align__(16) char smem[31232];
    u16*   tblH  = (u16*)(smem);
    u16*   tblL  = (u16*)(smem + 8192);
    u16*   tailB = (u16*)(smem + 16384);
    float* P_lds = (float*)(smem + 24576);
    float* sStats= (float*)(smem + 28672);
    float* sMuInv= (float*)(smem + 30720);
    u16*   sB2H  = (u16*)(smem);
    u16*   sB2L  = (u16*)(smem + 8192);
    float* sAP   = (float*)(smem + 28672);
    float* sAttv = (float*)(smem + 30720);

    const int tid = threadIdx.x;
    const int node0 = blockIdx.x * NPB;
    const int ligBase = node0 & ~31;
    const int aBase   = node0 & 31;      // 0,8,16,24
    const int w = tid >> 6, lane = tid & 63, lr = lane & 15, lh = lane >> 4;
    const int colB0 = w*32 + lr, colB1 = colB0 + 16;

    // ---- per-lane col indices (local atom ids) -------------------------
    int aCol[4];
    #pragma unroll
    for (int rt = 0; rt < 4; ++rt)
        aCol[rt] = ecol[node0*KNN + rt*16 + lr] & 31;

    // ---- stage ligand hh table (32 atoms x 16 chunks, hi/lo) -----------
    for (int idx = tid; idx < 1024; idx += 256) {
        const int hl = idx >> 9, rem = idx & 511;
        const int a = rem >> 4, c4 = rem & 15;
        const bfx8 v = *(const bfx8*)((hl ? hhL : hhH) + (size_t)(ligBase + a)*HID + c4*8);
        u16* dst = hl ? tblL : tblH;
        *(bfx8*)&dst[a*128 + ((c4 ^ (a & 15)) << 3)] = v;
    }

    // ---- tail (single bf16) [64 rows][8 chunks]: temb(2)|smear(3)|0(3) -
    for (int pe = tid; pe < 512; pe += 256) {
        const int row = pe & 63, part = pe >> 6;
        U8 vh;
        if (part < 2) {
            const int r = node0 + (row >> 3);
            const int c = ecol[node0*KNN + row];
            int sbi = r*(KAT-1) + c - (r/KAT)*KAT - (r < c ? 1 : 0);
            const int tb = tbond[sbi];
            #pragma unroll
            for (int j = 0; j < 8; ++j)
                vh.a[j] = tembH[tb*TF + part*8 + j];
        } else if (part < 5) {
            const int r = node0 + (row >> 3);
            const int c = ecol[node0*KNN + row];
            float dx = x[3*r]-x[3*c], dy = x[3*r+1]-x[3*c+1], dz = x[3*r+2]-x[3*c+2];
            float dist = fminf(sqrtf(dx*dx+dy*dy+dz*dz), 4.0f);
            const float Cc = 0.12220674183617694f;   // log2(5)/19
            #pragma unroll
            for (int j = 0; j < 8; ++j) {
                int g = (part-2)*8 + j;
                float v = 0.0f;
                if (g < NG) {
                    float og = exp2f(Cc*(float)g) - 1.0f;
                    int gm = (g > 0) ? g : 1;
                    float d = exp2f(Cc*(float)gm) - exp2f(Cc*(float)(gm-1));
                    float dd = dist - og;
                    v = __expf(-0.5f/(d*d)*dd*dd);
                }
                vh.a[j] = bf16_rn(v);
            }
        } else {
            #pragma unroll
            for (int j = 0; j < 8; ++j) vh.a[j] = 0;
        }
        *(bfx8*)&tailB[row*64 + ((part ^ (row & 7)) << 3)] = vh.v;
    }
    __syncthreads();                                    // bar1

    // ---- GEMM1 (unified 10-step loop) ----------------------------------
    //  s 0..3 : P-GEMM (per-node hoisted hh[row] part)
    //  s 4..7 : per-edge col-hh part (3-product)
    //  s 8..9 : per-edge tail (single-bf16 A, 2-product)
    const u16* bH0 = W1TH + (size_t)colB0*K1 + lh*8;
    const u16* bH1 = W1TH + (size_t)colB1*K1 + lh*8;
    const u16* bL0 = W1TL + (size_t)colB0*K1 + lh*8;
    const u16* bL1 = W1TL + (size_t)colB1*K1 + lh*8;

    f32x4 pw0 = {0,0,0,0}, pw1 = {0,0,0,0};
    f32x4 acc[4][2];
    #pragma unroll
    for (int rt = 0; rt < 4; ++rt) { acc[rt][0] = (f32x4){0,0,0,0}; acc[rt][1] = (f32x4){0,0,0,0}; }
    {
        bfx8 wh0 = *(const bfx8*)bH0, wh1 = *(const bfx8*)bH1;
        bfx8 wl0 = *(const bfx8*)bL0, wl1 = *(const bfx8*)bL1;
        #pragma unroll
        for (int s = 0; s < 10; ++s) {
            bfx8 nh0 = wh0, nh1 = wh1, nl0 = wl0, nl1 = wl1;
            if (s < 9) {
                nh0 = *(const bfx8*)(bH0 + 32*(s+1)); nh1 = *(const bfx8*)(bH1 + 32*(s+1));
                nl0 = *(const bfx8*)(bL0 + 32*(s+1)); nl1 = *(const bfx8*)(bL1 + 32*(s+1));
            }
            if (s < 4) {
                const int aR = aBase + (lr & 7);         // rows 8..15 = dupes, unused
                const int c4 = s*4 + lh;
                const int ad = aR*128 + ((c4 ^ (aR & 15)) << 3);
                const bfx8 ah = *(const bfx8*)&tblH[ad];
                const bfx8 al = *(const bfx8*)&tblL[ad];
                pw0 = mfma3(ah, al, wh0, wl0, pw0);
                pw1 = mfma3(ah, al, wh1, wl1, pw1);
            } else if (s < 8) {
                #pragma unroll
                for (int rt = 0; rt < 4; ++rt) {
                    const int aC = aCol[rt];
                    const int c4 = (s-4)*4 + lh;
                    const int ad = aC*128 + ((c4 ^ (aC & 15)) << 3);
                    const bfx8 ah = *(const bfx8*)&tblH[ad];
                    const bfx8 al = *(const bfx8*)&tblL[ad];
                    acc[rt][0] = mfma3(ah, al, wh0, wl0, acc[rt][0]);
                    acc[rt][1] = mfma3(ah, al, wh1, wl1, acc[rt][1]);
                }
            } else {
                #pragma unroll
                for (int rt = 0; rt < 4; ++rt) {
                    const int r = rt*16 + lr;
                    const int c = (s-8)*4 + lh;
                    const int ad = r*64 + ((c ^ (r & 7)) << 3);
                    const bfx8 ah = *(const bfx8*)&tailB[ad];
                    acc[rt][0] = mfma2(ah, wh0, wl0, acc[rt][0]);
                    acc[rt][1] = mfma2(ah, wh1, wl1, acc[rt][1]);
                }
            }
            wh0 = nh0; wh1 = nh1; wl0 = nl0; wl1 = nl1;
        }
    }
    // write P (rows 0..7 = nodes; 8..15 dupes skipped)
    if (lh < 2) {
        #pragma unroll
        for (int j = 0; j < 4; ++j) {
            P_lds[(4*lh + j)*128 + colB0] = pw0[j];
            P_lds[(4*lh + j)*128 + colB1] = pw1[j];
        }
    }
    __syncthreads();                                    // bar2 (tbl/tail reads + P writes done)

    // ---- inject P + bias; in-register LN partials ----------------------
    {
        const float b10 = be1[colB0], b11 = be1[colB1];
        const int n = (lh >> 1);
        #pragma unroll
        for (int rt = 0; rt < 4; ++rt) {
            const float p0 = P_lds[(rt*2 + n)*128 + colB0] + b10;
            const float p1 = P_lds[(rt*2 + n)*128 + colB1] + b11;
            #pragma unroll
            for (int j = 0; j < 4; ++j) { acc[rt][0][j] += p0; acc[rt][1][j] += p1; }
        }
    }
    {
        #pragma unroll
        for (int rt = 0; rt < 4; ++rt) {
            float sv[4], qv[4];
            #pragma unroll
            for (int j = 0; j < 4; ++j) {
                const float a0 = acc[rt][0][j], a1 = acc[rt][1][j];
                sv[j] = a0 + a1; qv[j] = a0*a0 + a1*a1;
            }
            #pragma unroll
            for (int msk = 1; msk < 16; msk <<= 1) {
                #pragma unroll
                for (int j = 0; j < 4; ++j) {
                    sv[j] += __shfl_xor(sv[j], msk);
                    qv[j] += __shfl_xor(qv[j], msk);
                }
            }
            if (lr == 0) {
                #pragma unroll
                for (int j = 0; j < 4; ++j) {
                    const int row = rt*16 + 4*lh + j;
                    sStats[(row*4 + w)*2 + 0] = sv[j];
                    sStats[(row*4 + w)*2 + 1] = qv[j];
                }
            }
        }
    }
    __syncthreads();                                    // bar3

    if (tid < EPB) {
        const float4 a = *(const float4*)&sStats[tid*8];
        const float4 b = *(const float4*)&sStats[tid*8 + 4];
        const float st = a.x + a.z + b.x + b.z;
        const float qt = a.y + a.w + b.y + b.w;
        const float mu  = st * (1.0f/HID);
        const float var = qt * (1.0f/HID) - mu*mu;
        sMuInv[tid*2 + 0] = mu;
        sMuInv[tid*2 + 1] = rsqrtf(var + 1e-5f);
    }
    __syncthreads();                                    // bar4

    // ---- normalize + SiLU in place -------------------------------------
    {
        const float G0 = g1[colB0], G1s = g1[colB1];
        const float B0 = bt1[colB0], B1s = bt1[colB1];
        #pragma unroll
        for (int rt = 0; rt < 4; ++rt) {
            const int r0 = rt*16 + 4*lh;
            const float4 mi0 = *(const float4*)&sMuInv[r0*2];      // mu0,inv0,mu1,inv1
            const float4 mi1 = *(const float4*)&sMuInv[r0*2 + 4];  // mu2,inv2,mu3,inv3
            acc[rt][0][0] = siluf(fmaf((acc[rt][0][0]-mi0.x)*mi0.y, G0, B0));
            acc[rt][1][0] = siluf(fmaf((acc[rt][1][0]-mi0.x)*mi0.y, G1s, B1s));
            acc[rt][0][1] = siluf(fmaf((acc[rt][0][1]-mi0.z)*mi0.w, G0, B0));
            acc[rt][1][1] = siluf(fmaf((acc[rt][1][1]-mi0.z)*mi0.w, G1s, B1s));
            acc[rt][0][2] = siluf(fmaf((acc[rt][0][2]-mi1.x)*mi1.y, G0, B0));
            acc[rt][1][2] = siluf(fmaf((acc[rt][1][2]-mi1.x)*mi1.y, G1s, B1s));
            acc[rt][0][3] = siluf(fmaf((acc[rt][0][3]-mi1.z)*mi1.w, G0, B0));
            acc[rt][1][3] = siluf(fmaf((acc[rt][1][3]-mi1.z)*mi1.w, G1s, B1s));
        }
    }

    // ---- GEMM2 in two 32-row passes (sB2 = 16 KB, aliases tbl) ---------
    f32x4 d[4][2];
    #pragma unroll
    for (int rt = 0; rt < 4; ++rt) { d[rt][0] = (f32x4){0,0,0,0}; d[rt][1] = (f32x4){0,0,0,0}; }

    const u16* c2H0 = W2TH + (size_t)colB0*HID + lh*8;
    const u16* c2H1 = W2TH + (size_t)colB1*HID + lh*8;
    const u16* c2L0 = W2TL + (size_t)colB0*HID + lh*8;
    const u16* c2L1 = W2TL + (size_t)colB1*HID + lh*8;

    #pragma unroll
    for (int p = 0; p < 2; ++p) {
        // write rows [p*32, p*32+32) of post-LN acts as bf16 hi/lo
        #pragma unroll
        for (int rr = 0; rr < 2; ++rr) {
            const int rt = 2*p + rr;
            #pragma unroll
            for (int hcol = 0; hcol < 2; ++hcol) {
                const int col = hcol ? colB1 : colB0;
                const int gch = col >> 3, cw = col & 7;
                #pragma unroll
                for (int j = 0; j < 4; ++j) {
                    const int rowL = rr*16 + 4*lh + j;
                    const int ad = rowL*128 + (((gch) ^ (rowL & 15)) << 3) + cw;
                    const float v = acc[rt][hcol][j];
                    const u16 hb = bf16_rn(v);
                    sB2H[ad] = hb;
                    sB2L[ad] = bf16_rn(v - bf16_tof(hb));
                }
            }
        }
        __syncthreads();                                // bar5 / bar7
        {
            bfx8 wh0 = *(const bfx8*)c2H0, wh1 = *(const bfx8*)c2H1;
            bfx8 wl0 = *(const bfx8*)c2L0, wl1 = *(const bfx8*)c2L1;
            #pragma unroll
            for (int s = 0; s < 4; ++s) {
                bfx8 nh0 = wh0, nh1 = wh1, nl0 = wl0, nl1 = wl1;
                if (s < 3) {
                    nh0 = *(const bfx8*)(c2H0 + 32*(s+1)); nh1 = *(const bfx8*)(c2H1 + 32*(s+1));
                    nl0 = *(const bfx8*)(c2L0 + 32*(s+1)); nl1 = *(const bfx8*)(c2L1 + 32*(s+1));
                }
                #pragma unroll
                for (int rr = 0; rr < 2; ++rr) {
                    const int rowL = rr*16 + lr;
                    const int c4 = s*4 + lh;
                    const int ad = rowL*128 + ((c4 ^ lr) << 3);
                    const bfx8 ah = *(const bfx8*)&sB2H[ad];
                    const bfx8 al = *(const bfx8*)&sB2L[ad];
                    d[2*p+rr][0] = mfma3(ah, al, wh0, wl0, d[2*p+rr][0]);
                    d[2*p+rr][1] = mfma3(ah, al, wh1, wl1, d[2*p+rr][1]);
                }
                wh0 = nh0; wh1 = nh1; wl0 = nl0; wl1 = nl1;
            }
        }
        if (p == 0) __syncthreads();                    // bar6 (reads done before pass-2 writes)
    }

    // ---- SiLU in place (d becomes m) + attention gate ------------------
    {
        const float b20 = be2[colB0], b21 = be2[colB1];
        #pragma unroll
        for (int rt = 0; rt < 4; ++rt) {
            #pragma unroll
            for (int j = 0; j < 4; ++j) {
                d[rt][0][j] = siluf(d[rt][0][j] + b20);
                d[rt][1][j] = siluf(d[rt][1][j] + b21);
            }
        }
    }
    {
        const float wa0 = Watt[colB0], wa1 = Watt[colB1];
        float pa[4][4];
        #pragma unroll
        for (int rt = 0; rt < 4; ++rt)
            #pragma unroll
            for (int j = 0; j < 4; ++j)
                pa[rt][j] = d[rt][0][j]*wa0 + d[rt][1][j]*wa1;
        #pragma unroll
        for (int msk = 1; msk < 16; msk <<= 1) {
            #pragma unroll
            for (int rt = 0; rt < 4; ++rt)
                #pragma unroll
                for (int j = 0; j < 4; ++j)
                    pa[rt][j] += __shfl_xor(pa[rt][j], msk);
        }
        if (lr == 0) {
            #pragma unroll
            for (int rt = 0; rt < 4; ++rt)
                #pragma unroll
                for (int j = 0; j < 4; ++j)
                    sAP[w*64 + rt*16 + 4*lh + j] = pa[rt][j];
        }
    }
    __syncthreads();                                    // bar8
    if (tid < EPB)
        sAttv[tid] = sigf(sAP[tid] + sAP[64+tid] + sAP[128+tid] + sAP[192+tid] + batt[0]);
    __syncthreads();                                    // bar9

    // ---- gated aggregate -> aggH/aggL ----------------------------------
    #pragma unroll
    for (int rt = 0; rt < 4; ++rt) {
        float s0 = 0.0f, s1 = 0.0f;
        #pragma unroll
        for (int j = 0; j < 4; ++j) {
            const float av = sAttv[rt*16 + 4*lh + j];
            s0 += d[rt][0][j]*av;
            s1 += d[rt][1][j]*av;
        }
        s0 += __shfl_xor(s0, 16);
        s1 += __shfl_xor(s1, 16);
        if ((lh & 1) == 0) {
            const int node = node0 + 2*rt + (lh >> 1);
            wragg(aggH, aggL, (size_t)node*HID + colB0, s0*0.2f);
            wragg(aggH, aggL, (size_t)node*HID + colB1, s1*0.2f);
        }
    }
}

// ---------------------------------------------------------------- node (MFMA, 32 nodes/block)
__global__ __launch_bounds__(256, 6) void node_k(
    float* __restrict__ hh, u16* __restrict__ hhH, u16* __restrict__ hhL,
    const u16* __restrict__ aggH, const u16* __restrict__ aggL,
    const u16* __restrict__ B1H, const u16* __restrict__ B1L,
    const u16* __restrict__ B2H, const u16* __restrict__ B2L,
    const float* __restrict__ bn1, const float* __restrict__ g2,
    const float* __restrict__ bt2, const float* __restrict__ bn2)
{
    __shared__ __align__(16) char smem[16896];
    float* sMid = (float*)smem;
    u16* sYH = (u16*)smem;
    u16* sYL = (u16*)(smem + 8192);

    const int tid = threadIdx.x;
    const int node0 = blockIdx.x * 32;
    const int w = tid >> 6, lane = tid & 63, lr = lane & 15, lh = lane >> 4;
    const int colB0 = w*32 + lr, colB1 = colB0 + 16;

    const u16* a1h0 = hhH  + (size_t)(node0+lr)*HID + lh*8;
    const u16* a1l0 = hhL  + (size_t)(node0+lr)*HID + lh*8;
    const u16* a2h0 = aggH + (size_t)(node0+lr)*HID + lh*8;
    const u16* a2l0 = aggL + (size_t)(node0+lr)*HID + lh*8;
    const u16* c1H0 = B1H + (size_t)colB0*256 + lh*8;
    const u16* c1H1 = B1H + (size_t)colB1*256 + lh*8;
    const u16* c1L0 = B1L + (size_t)colB0*256 + lh*8;
    const u16* c1L1 = B1L + (size_t)colB1*256 + lh*8;

    f32x4 acc00={0,0,0,0}, acc01={0,0,0,0}, acc10={0,0,0,0}, acc11={0,0,0,0};
    {
        bfx8 wh0 = *(const bfx8*)c1H0, wh1 = *(const bfx8*)c1H1;
        bfx8 wl0 = *(const bfx8*)c1L0, wl1 = *(const bfx8*)c1L1;
        #pragma unroll
        for (int s = 0; s < 8; ++s) {
            bfx8 nh0 = wh0, nh1 = wh1, nl0 = wl0, nl1 = wl1;
            if (s < 7) {
                nh0 = *(const bfx8*)(c1H0 + 32*(s+1)); nh1 = *(const bfx8*)(c1H1 + 32*(s+1));
                nl0 = *(const bfx8*)(c1L0 + 32*(s+1)); nl1 = *(const bfx8*)(c1L1 + 32*(s+1));
            }
            bfx8 ah0, ah1, al0, al1;
            if (s < 4) {
                ah0 = *(const bfx8*)(a1h0 + 32*s);            ah1 = *(const bfx8*)(a1h0 + 16*HID + 32*s);
                al0 = *(const bfx8*)(a1l0 + 32*s);            al1 = *(const bfx8*)(a1l0 + 16*HID + 32*s);
            } else {
                ah0 = *(const bfx8*)(a2h0 + 32*(s-4));        ah1 = *(const bfx8*)(a2h0 + 16*HID + 32*(s-4));
                al0 = *(const bfx8*)(a2l0 + 32*(s-4));        al1 = *(const bfx8*)(a2l0 + 16*HID + 32*(s-4));
            }
            acc00 = mfma3(ah0, al0, wh0, wl0, acc00);
            acc01 = mfma3(ah0, al0, wh1, wl1, acc01);
            acc10 = mfma3(ah1, al1, wh0, wl0, acc10);
            acc11 = mfma3(ah1, al1, wh1, wl1, acc11);
            wh0 = nh0; wh1 = nh1; wl0 = nl0; wl1 = nl1;
        }
    }
    {
        const float b10 = bn1[colB0], b11 = bn1[colB1];
        #pragma unroll
        for (int j = 0; j < 4; ++j) {
            const int r0 = 4*lh + j;
            sMid[r0*MIDSTR + colB0]      = acc00[j] + b10;
            sMid[r0*MIDSTR + colB1]      = acc01[j] + b11;
            sMid[(16+r0)*MIDSTR + colB0] = acc10[j] + b10;
            sMid[(16+r0)*MIDSTR + colB1] = acc11[j] + b11;
        }
    }
    __syncthreads();

    float y[16];
    const int eLN = tid >> 3, c0 = (tid & 7)*16;
    {
        const float* mrow = &sMid[eLN*MIDSTR + c0];
        float4 v0 = *(const float4*)&mrow[0];
        float4 v1 = *(const float4*)&mrow[4];
        float4 v2 = *(const float4*)&mrow[8];
        float4 v3 = *(const float4*)&mrow[12];
        float s = v0.x+v0.y+v0.z+v0.w + v1.x+v1.y+v1.z+v1.w
                + v2.x+v2.y+v2.z+v2.w + v3.x+v3.y+v3.z+v3.w;
        float q = v0.x*v0.x+v0.y*v0.y+v0.z*v0.z+v0.w*v0.w
                + v1.x*v1.x+v1.y*v1.y+v1.z*v1.z+v1.w*v1.w
                + v2.x*v2.x+v2.y*v2.y+v2.z*v2.z+v2.w*v2.w
                + v3.x*v3.x+v3.y*v3.y+v3.z*v3.z+v3.w*v3.w;
        #pragma unroll
        for (int m = 4; m >= 1; m >>= 1) { s += __shfl_xor(s, m); q += __shfl_xor(q, m); }
        float mu  = s * (1.0f/HID);
        float var = q * (1.0f/HID) - mu*mu;
        float inv = rsqrtf(var + 1e-5f);
        const float4 G0 = *(const float4*)&g2[c0+0],  G1v = *(const float4*)&g2[c0+4];
        const float4 G2 = *(const float4*)&g2[c0+8],  G3 = *(const float4*)&g2[c0+12];
        const float4 B0 = *(const float4*)&bt2[c0+0], B1 = *(const float4*)&bt2[c0+4];
        const float4 B2 = *(const float4*)&bt2[c0+8], B3 = *(const float4*)&bt2[c0+12];
        y[0]=siluf(fmaf((v0.x-mu)*inv,G0.x,B0.x));  y[1]=siluf(fmaf((v0.y-mu)*inv,G0.y,B0.y));
        y[2]=siluf(fmaf((v0.z-mu)*inv,G0.z,B0.z));  y[3]=siluf(fmaf((v0.w-mu)*inv,G0.w,B0.w));
        y[4]=siluf(fmaf((v1.x-mu)*inv,G1v.x,B1.x)); y[5]=siluf(fmaf((v1.y-mu)*inv,G1v.y,B1.y));
        y[6]=siluf(fmaf((v1.z-mu)*inv,G1v.z,B1.z)); y[7]=siluf(fmaf((v1.w-mu)*inv,G1v.w,B1.w));
        y[8]=siluf(fmaf((v2.x-mu)*inv,G2.x,B2.x));  y[9]=siluf(fmaf((v2.y-mu)*inv,G2.y,B2.y));
        y[10]=siluf(fmaf((v2.z-mu)*inv,G2.z,B2.z)); y[11]=siluf(fmaf((v2.w-mu)*inv,G2.w,B2.w));
        y[12]=siluf(fmaf((v3.x-mu)*inv,G3.x,B3.x)); y[13]=siluf(fmaf((v3.y-mu)*inv,G3.y,B3.y));
        y[14]=siluf(fmaf((v3.z-mu)*inv,G3.z,B3.z)); y[15]=siluf(fmaf((v3.w-mu)*inv,G3.w,B3.w));
    }
    __syncthreads();
    {
        U8 ha, hb2, la, lb2;
        #pragma unroll
        for (int j = 0; j < 8; ++j) {
            u16 t0 = bf16_rn(y[j]);   ha.a[j]  = t0; la.a[j]  = bf16_rn(y[j]   - bf16_tof(t0));
            u16 t1 = bf16_rn(y[8+j]); hb2.a[j] = t1; lb2.a[j] = bf16_rn(y[8+j] - bf16_tof(t1));
        }
        const int cA = (2*(tid & 7))     ^ (eLN & 15);
        const int cB = (2*(tid & 7) + 1) ^ (eLN & 15);
        *(bfx8*)&sYH[eLN*128 + (cA << 3)] = ha.v;
        *(bfx8*)&sYH[eLN*128 + (cB << 3)] = hb2.v;
        *(bfx8*)&sYL[eLN*128 + (cA << 3)] = la.v;
        *(bfx8*)&sYL[eLN*128 + (cB << 3)] = lb2.v;
    }
    __syncthreads();

    f32x4 d00={0,0,0,0}, d01={0,0,0,0}, d10={0,0,0,0}, d11={0,0,0,0};
    {
        const u16* c2H0 = B2H + (size_t)colB0*HID + lh*8;
        const u16* c2H1 = B2H + (size_t)colB1*HID + lh*8;
        const u16* c2L0 = B2L + (size_t)colB0*HID + lh*8;
        const u16* c2L1 = B2L + (size_t)colB1*HID + lh*8;
        bfx8 wh0 = *(const bfx8*)c2H0, wh1 = *(const bfx8*)c2H1;
        bfx8 wl0 = *(const bfx8*)c2L0, wl1 = *(const bfx8*)c2L1;
        #pragma unroll
        for (int s = 0; s < 4; ++s) {
            bfx8 nh0 = wh0, nh1 = wh1, nl0 = wl0, nl1 = wl1;
            if (s < 3) {
                nh0 = *(const bfx8*)(c2H0 + 32*(s+1)); nh1 = *(const bfx8*)(c2H1 + 32*(s+1));
                nl0 = *(const bfx8*)(c2L0 + 32*(s+1)); nl1 = *(const bfx8*)(c2L1 + 32*(s+1));
            }
            const int c4 = s*4 + lh;
            const int i0 = lr*128 + ((c4 ^ lr) << 3);
            const int i1 = (16+lr)*128 + ((c4 ^ lr) << 3);
            bfx8 ah0 = *(const bfx8*)&sYH[i0], ah1 = *(const bfx8*)&sYH[i1];
            bfx8 al0 = *(const bfx8*)&sYL[i0], al1 = *(const bfx8*)&sYL[i1];
            d00 = mfma3(ah0, al0, wh0, wl0, d00);
            d01 = mfma3(ah0, al0, wh1, wl1, d01);
            d10 = mfma3(ah1, al1, wh0, wl0, d10);
            d11 = mfma3(ah1, al1, wh1, wl1, d11);
            wh0 = nh0; wh1 = nh1; wl0 = nl0; wl1 = nl1;
        }
    }

    {
        const float b20 = bn2[colB0], b21 = bn2[colB1];
        #pragma unroll
        for (int j = 0; j < 4; ++j) {
            const int r0 = 4*lh + j, r1 = 16 + 4*lh + j;
            const size_t i00 = (size_t)(node0+r0)*HID + colB0;
            const size_t i01 = (size_t)(node0+r0)*HID + colB1;
            const size_t i10 = (size_t)(node0+r1)*HID + colB0;
            const size_t i11 = (size_t)(node0+r1)*HID + colB1;
            float v00 = hh[i00] + d00[j] + b20;
            float v01 = hh[i01] + d01[j] + b21;
            float v10 = hh[i10] + d10[j] + b20;
            float v11 = hh[i11] + d11[j] + b21;
            hh[i00] = v00; hh[i01] = v01; hh[i10] = v10; hh[i11] = v11;
            u16 h00 = bf16_rn(v00); hhH[i00] = h00; hhL[i00] = bf16_rn(v00 - bf16_tof(h00));
            u16 h01 = bf16_rn(v01); hhH[i01] = h01; hhL[i01] = bf16_rn(v01 - bf16_tof(h01));
            u16 h10 = bf16_rn(v10); hhH[i10] = h10; hhL[i10] = bf16_rn(v10 - bf16_tof(h10));
            u16 h11 = bf16_rn(v11); hhH[i11] = h11; hhL[i11] = bf16_rn(v11 - bf16_tof(h11));
        }
    }
}

// ---------------------------------------------------------------- output head
__global__ __launch_bounds__(HID) void out_k(
    const float* __restrict__ hh, const float* __restrict__ Woe,
    const float* __restrict__ boe, const float* __restrict__ Wf,
    const float* __restrict__ bf, float* __restrict__ out)
{
    __shared__ float sH[HID];
    const int lig = blockIdx.x, tid = threadIdx.x;
    float s = 0.0f;
    const float* base = hh + (size_t)lig*KAT*HID + tid;
    #pragma unroll 8
    for (int a = 0; a < KAT; ++a) s += base[a*HID];
    sH[tid] = s * (1.0f/KAT);
    __syncthreads();

    float contrib = 0.0f;
    if (tid < OUTF) {
        float p = boe[tid];
        #pragma unroll 4
        for (int i = 0; i < HID; ++i)
            p = fmaf(sH[i], Woe[i*OUTF + tid], p);
        contrib = p * Wf[tid];
    }
    #pragma unroll
    for (int m = 1; m < 64; m <<= 1) contrib += __shfl_xor(contrib, m);
    if (tid == 0) out[lig] = contrib + bf[0];
}

// ---------------------------------------------------------------- launch
extern "C" void kernel_launch(void* const* d_in, const int* in_sizes, int n_in,
                              void* d_out, int out_size, void* d_ws, size_t ws_size,
                              hipStream_t stream)
{
    (void)in_sizes; (void)n_in; (void)out_size; (void)ws_size;
    const float* x    = (const float*)d_in[0];
    const float* h    = (const float*)d_in[1];
    const int*   t    = (const int*)d_in[2];
    const int*   edges= (const int*)d_in[3];
    const int*   tb   = (const int*)d_in[4];
    const float* temb = (const float*)d_in[8];
    const float* Win  = (const float*)d_in[9];
    const float* bin  = (const float*)d_in[10];
    const float* We1  = (const float*)d_in[11];
    const float* be1  = (const float*)d_in[12];
    const float* g1   = (const float*)d_in[13];
    const float* bt1  = (const float*)d_in[14];
    const float* We2  = (const float*)d_in[15];
    const float* be2  = (const float*)d_in[16];
    const float* Watt = (const float*)d_in[17];
    const float* batt = (const float*)d_in[18];
    const float* Wn1  = (const float*)d_in[19];
    const float* bn1  = (const float*)d_in[20];
    const float* g2   = (const float*)d_in[21];
    const float* bt2  = (const float*)d_in[22];
    const float* Wn2  = (const float*)d_in[23];
    const float* bn2  = (const float*)d_in[24];
    const float* Woe  = (const float*)d_in[25];
    const float* boe  = (const float*)d_in[26];
    const float* Wf   = (const float*)d_in[27];
    const float* bf   = (const float*)d_in[28];
    float* out = (float*)d_out;

    char* wsb = (char*)d_ws;
    float* hh  = (float*)(wsb);                        // 16 MB
    u16* hhH   = (u16*)(wsb + ((size_t)16<<20));       // 8 MB
    u16* hhL   = (u16*)(wsb + ((size_t)24<<20));       // 8 MB
    u16* aggH  = (u16*)(wsb + ((size_t)32<<20));       // 8 MB
    u16* aggL  = (u16*)(wsb + ((size_t)40<<20));       // 8 MB
    u16* tembH = (u16*)(wsb + ((size_t)48<<20));
    u16* tembL = tembH + PREP_TEMB;
    u16* W1TH  = tembL + PREP_TEMB;
    u16* W1TL  = W1TH + PREP_W1;
    u16* W2TH  = W1TL + PREP_W1;
    u16* W2TL  = W2TH + PREP_W2;
    u16* WN1TH = W2TL + PREP_W2;
    u16* WN1TL = WN1TH + PREP_WN1;
    u16* WN2TH = WN1TL + PREP_WN1;
    u16* WN2TL = WN2TH + PREP_WN2;

    prep_k<<<(PREP_TOT + 255)/256, 256, 0, stream>>>(
        temb, We1, We2, Wn1, Wn2,
        tembH, tembL, W1TH, W1TL, W2TH, W2TL, WN1TH, WN1TL, WN2TH, WN2TL);

    embed_k<<<NNODES/8, 256, 0, stream>>>(h, t, temb, Win, bin, hh, hhH, hhL);

    for (int l = 0; l < 4; ++l) {
        edge_k<<<NNODES/NPB, 256, 0, stream>>>(
            hhH, hhL, x, edges + NEDGES, tb, tembH, tembL,
            W1TH + (size_t)l*128*K1, W1TL + (size_t)l*128*K1,
            W2TH + (size_t)l*128*128, W2TL + (size_t)l*128*128,
            be1 + l*HID, g1 + l*HID, bt1 + l*HID, be2 + l*HID,
            Watt + l*HID, batt + l, aggH, aggL);
        node_k<<<NNODES/32, 256, 0, stream>>>(
            hh, hhH, hhL, aggH, aggL,
            WN1TH + (size_t)l*128*256, WN1TL + (size_t)l*128*256,
            WN2TH + (size_t)l*128*128, WN2TL + (size_t)l*128*128,
            bn1 + l*HID, g2 + l*HID, bt2 + l*HID, bn2 + l*HID);
    }
    out_k<<<NLIG, HID, 0, stream>>>(hh, Woe, boe, Wf, bf, out);
}

// Round 9
// 739.962 us; speedup vs baseline: 1.2744x; 1.1504x over previous
//
#include <hip/hip_runtime.h>
#include <math.h>

#define NNODES 32768
#define NLIG   1024
#define KAT    32
#define KNN    8
#define NEDGES (NNODES*KNN)
#define HID    128
#define TF     16
#define NG     20
#define OUTF   64

#define NPB    8            // nodes per edge-block
#define EPB    64           // edges per edge-block
#define K1     320          // padded GEMM1 K (292 -> 320)
#define MIDSTR 132          // node_k sMid row stride (floats)

typedef unsigned short u16;
typedef __attribute__((__ext_vector_type__(8))) short bfx8;
typedef __attribute__((__ext_vector_type__(4))) float f32x4;

union U8 { u16 a[8]; bfx8 v; };

__device__ __forceinline__ float siluf(float v) {
    return __fdividef(v, 1.0f + __expf(-v));
}
__device__ __forceinline__ float sigf(float v) {
    return __fdividef(1.0f, 1.0f + __expf(-v));
}
__device__ __forceinline__ u16 bf16_rn(float f) {
    union { float f; unsigned u; } v; v.f = f;
    unsigned r = v.u + 0x7FFFu + ((v.u >> 16) & 1u);
    return (u16)(r >> 16);
}
__device__ __forceinline__ float bf16_tof(u16 u) {
    union { unsigned u; float f; } v; v.u = ((unsigned)u) << 16;
    return v.f;
}
__device__ __forceinline__ f32x4 mfma3(bfx8 ah, bfx8 al, bfx8 wh, bfx8 wl, f32x4 c) {
    c = __builtin_amdgcn_mfma_f32_16x16x32_bf16(ah, wh, c, 0, 0, 0);
    c = __builtin_amdgcn_mfma_f32_16x16x32_bf16(ah, wl, c, 0, 0, 0);
    c = __builtin_amdgcn_mfma_f32_16x16x32_bf16(al, wh, c, 0, 0, 0);
    return c;
}
__device__ __forceinline__ f32x4 mfma2(bfx8 ah, bfx8 wh, bfx8 wl, f32x4 c) {
    c = __builtin_amdgcn_mfma_f32_16x16x32_bf16(ah, wh, c, 0, 0, 0);
    c = __builtin_amdgcn_mfma_f32_16x16x32_bf16(ah, wl, c, 0, 0, 0);
    return c;
}
__device__ __forceinline__ void wragg(u16* __restrict__ H, u16* __restrict__ L,
                                      size_t i, float v) {
    u16 hb = bf16_rn(v);
    H[i] = hb; L[i] = bf16_rn(v - bf16_tof(hb));
}

// ---------------------------------------------------------------- prep
#define PREP_TEMB 16000
#define PREP_W1   (4*128*K1)       // 163840
#define PREP_W2   (4*128*128)      // 65536
#define PREP_WN1  (4*128*256)      // 131072
#define PREP_WN2  (4*128*128)      // 65536
#define PREP_TOT  (PREP_TEMB+PREP_W1+PREP_W2+PREP_WN1+PREP_WN2)

__global__ __launch_bounds__(256) void prep_k(
    const float* __restrict__ temb, const float* __restrict__ We1,
    const float* __restrict__ We2,  const float* __restrict__ Wn1,
    const float* __restrict__ Wn2,
    u16* __restrict__ tembH, u16* __restrict__ tembL,
    u16* __restrict__ W1TH, u16* __restrict__ W1TL,
    u16* __restrict__ W2TH, u16* __restrict__ W2TL,
    u16* __restrict__ WN1TH, u16* __restrict__ WN1TL,
    u16* __restrict__ WN2TH, u16* __restrict__ WN2TL)
{
    int i = blockIdx.x*256 + threadIdx.x;
    if (i >= PREP_TOT) return;
    float v; u16 *dh, *dl; int di;
    if (i < PREP_TEMB) {
        v = temb[i]; dh = tembH; dl = tembL; di = i;
    } else if (i < PREP_TEMB + PREP_W1) {
        int j = i - PREP_TEMB; di = j; dh = W1TH; dl = W1TL;
        int l = j / (128*K1); int r = j - l*(128*K1);
        int col = r / K1, k = r - col*K1;
        v = (k < 292) ? We1[(size_t)l*292*128 + (size_t)k*128 + col] : 0.0f;
    } else if (i < PREP_TEMB + PREP_W1 + PREP_W2) {
        int j = i - PREP_TEMB - PREP_W1; di = j; dh = W2TH; dl = W2TL;
        int l = j >> 14; int r = j & 16383;
        int col = r >> 7, k = r & 127;
        v = We2[(size_t)l*16384 + (size_t)k*128 + col];
    } else if (i < PREP_TEMB + PREP_W1 + PREP_W2 + PREP_WN1) {
        int j = i - PREP_TEMB - PREP_W1 - PREP_W2; di = j; dh = WN1TH; dl = WN1TL;
        int l = j >> 15; int r = j & 32767;
        int col = r >> 8, k = r & 255;
        v = Wn1[(size_t)l*32768 + (size_t)k*128 + col];
    } else {
        int j = i - PREP_TEMB - PREP_W1 - PREP_W2 - PREP_WN1; di = j; dh = WN2TH; dl = WN2TL;
        int l = j >> 14; int r = j & 16383;
        int col = r >> 7, k = r & 127;
        v = Wn2[(size_t)l*16384 + (size_t)k*128 + col];
    }
    u16 hb = bf16_rn(v);
    dh[di] = hb;
    dl[di] = bf16_rn(v - bf16_tof(hb));
}

// ---------------------------------------------------------------- embed (8 nodes/block)
__global__ __launch_bounds__(256) void embed_k(
    const float* __restrict__ h, const int* __restrict__ t,
    const float* __restrict__ temb, const float* __restrict__ Win,
    const float* __restrict__ bin, float* __restrict__ hh,
    u16* __restrict__ hhH, u16* __restrict__ hhL)
{
    __shared__ float sIn[8][32];
    const int tid = threadIdx.x;
    {
        const int n = tid >> 5, i = tid & 31;
        const int node = blockIdx.x*8 + n;
        sIn[n][i] = (i < TF) ? h[node*TF + i] : temb[t[node]*TF + (i-TF)];
    }
    __syncthreads();
    const int sub = tid >> 7, col = tid & 127;
    float acc[4];
    const float b = bin[col];
    acc[0]=acc[1]=acc[2]=acc[3]=b;
    #pragma unroll 8
    for (int i = 0; i < 32; ++i) {
        const float wv = Win[i*HID + col];
        acc[0] = fmaf(sIn[sub][i],   wv, acc[0]);
        acc[1] = fmaf(sIn[2+sub][i], wv, acc[1]);
        acc[2] = fmaf(sIn[4+sub][i], wv, acc[2]);
        acc[3] = fmaf(sIn[6+sub][i], wv, acc[3]);
    }
    #pragma unroll
    for (int nn = 0; nn < 4; ++nn) {
        const size_t idx = (size_t)(blockIdx.x*8 + nn*2 + sub)*HID + col;
        hh[idx] = acc[nn];
        u16 hb = bf16_rn(acc[nn]);
        hhH[idx] = hb; hhL[idx] = bf16_rn(acc[nn] - bf16_tof(hb));
    }
}

// ---------------------------------------------------------------- edge
// M=64, per-edge A (no hoist), in-reg LN, single-bf16 post-LN acts,
// single-pass 2-product GEMM2. LDS 26.5 KB, 6 barriers.
__global__ __launch_bounds__(256, 4) void edge_k(
    const u16* __restrict__ hhH, const u16* __restrict__ hhL,
    const float* __restrict__ x,
    const int* __restrict__ ecol, const int* __restrict__ tbond,
    const u16* __restrict__ tembH, const u16* __restrict__ tembL,
    const u16* __restrict__ W1TH, const u16* __restrict__ W1TL,
    const u16* __restrict__ W2TH, const u16* __restrict__ W2TL,
    const float* __restrict__ be1, const float* __restrict__ g1,
    const float* __restrict__ bt1, const float* __restrict__ be2,
    const float* __restrict__ Watt, const float* __restrict__ batt,
    u16* __restrict__ aggH, u16* __restrict__ aggL)
{
    // LDS (27136 B):
    //  [0,16384)     tblH(8K)+tblL(8K)   | after LN: sB2 single (64x128 u16 = 16K)
    //  [16384,24576) tailB (64 x 64 u16)
    //  [24576,26624) sStats (64 x 4 x f32x2) | after GEMM2: sAP (256 f32)
    //  [26624,27136) sMuInv (64 x f32x2)     | after: sAttv (64 f32)
    __shared__ __align__(16) char smem[27136];
    u16*   tblH  = (u16*)(smem);
    u16*   tblL  = (u16*)(smem + 8192);
    u16*   tailB = (u16*)(smem + 16384);
    float* sStats= (float*)(smem + 24576);
    float* sMuInv= (float*)(smem + 26624);
    u16*   sB2   = (u16*)(smem);
    float* sAP   = (float*)(smem + 24576);
    float* sAttv = (float*)(smem + 26624);

    const int tid = threadIdx.x;
    const int node0 = blockIdx.x * NPB;
    const int ligBase = node0 & ~31;
    const int aBase   = node0 & 31;      // 0,8,16,24
    const int w = tid >> 6, lane = tid & 63, lr = lane & 15, lh = lane >> 4;
    const int colB0 = w*32 + lr, colB1 = colB0 + 16;

    // ---- per-lane col indices (local atom ids) -------------------------
    int aCol[4];
    #pragma unroll
    for (int rt = 0; rt < 4; ++rt)
        aCol[rt] = ecol[node0*KNN + rt*16 + lr] & 31;

    // ---- GEMM1 weight pointers + first fragments (issued before staging,
    //      so they overlap with table staging loads) ----------------------
    const u16* bH0 = W1TH + (size_t)colB0*K1 + lh*8;
    const u16* bH1 = W1TH + (size_t)colB1*K1 + lh*8;
    const u16* bL0 = W1TL + (size_t)colB0*K1 + lh*8;
    const u16* bL1 = W1TL + (size_t)colB1*K1 + lh*8;
    bfx8 wh0 = *(const bfx8*)bH0, wh1 = *(const bfx8*)bH1;
    bfx8 wl0 = *(const bfx8*)bL0, wl1 = *(const bfx8*)bL1;

    // ---- stage ligand hh table (32 atoms x 16 chunks, hi/lo) -----------
    for (int idx = tid; idx < 1024; idx += 256) {
        const int hl = idx >> 9, rem = idx & 511;
        const int a = rem >> 4, c4 = rem & 15;
        const bfx8 v = *(const bfx8*)((hl ? hhL : hhH) + (size_t)(ligBase + a)*HID + c4*8);
        u16* dst = hl ? tblL : tblH;
        *(bfx8*)&dst[a*128 + ((c4 ^ (a & 15)) << 3)] = v;
    }

    // ---- tail (single bf16) [64 rows][8 chunks]: temb(2)|smear(3)|0(3) -
    for (int pe = tid; pe < 512; pe += 256) {
        const int row = pe & 63, part = pe >> 6;
        U8 vh;
        if (part < 2) {
            const int r = node0 + (row >> 3);
            const int c = ecol[node0*KNN + row];
            int sbi = r*(KAT-1) + c - (r/KAT)*KAT - (r < c ? 1 : 0);
            const int tb = tbond[sbi];
            #pragma unroll
            for (int j = 0; j < 8; ++j)
                vh.a[j] = tembH[tb*TF + part*8 + j];
        } else if (part < 5) {
            const int r = node0 + (row >> 3);
            const int c = ecol[node0*KNN + row];
            float dx = x[3*r]-x[3*c], dy = x[3*r+1]-x[3*c+1], dz = x[3*r+2]-x[3*c+2];
            float dist = fminf(sqrtf(dx*dx+dy*dy+dz*dz), 4.0f);
            const float Cc = 0.12220674183617694f;   // log2(5)/19
            #pragma unroll
            for (int j = 0; j < 8; ++j) {
                int g = (part-2)*8 + j;
                float v = 0.0f;
                if (g < NG) {
                    float og = exp2f(Cc*(float)g) - 1.0f;
                    int gm = (g > 0) ? g : 1;
                    float d = exp2f(Cc*(float)gm) - exp2f(Cc*(float)(gm-1));
                    float dd = dist - og;
                    v = __expf(-0.5f/(d*d)*dd*dd);
                }
                vh.a[j] = bf16_rn(v);
            }
        } else {
            #pragma unroll
            for (int j = 0; j < 8; ++j) vh.a[j] = 0;
        }
        *(bfx8*)&tailB[row*64 + ((part ^ (row & 7)) << 3)] = vh.v;
    }
    __syncthreads();                                    // bar1

    // ---- GEMM1: [64 x 320] @ [320 x 128], 1-deep W prefetch ------------
    //  s 0..3 : row-hh (3-product)   s 4..7 : col-hh (3-product)
    //  s 8..9 : tail (single-bf16 A, 2-product)
    f32x4 acc[4][2];
    #pragma unroll
    for (int rt = 0; rt < 4; ++rt) { acc[rt][0] = (f32x4){0,0,0,0}; acc[rt][1] = (f32x4){0,0,0,0}; }
    {
        #pragma unroll
        for (int s = 0; s < 10; ++s) {
            bfx8 nh0 = wh0, nh1 = wh1, nl0 = wl0, nl1 = wl1;
            if (s < 9) {
                nh0 = *(const bfx8*)(bH0 + 32*(s+1)); nh1 = *(const bfx8*)(bH1 + 32*(s+1));
                nl0 = *(const bfx8*)(bL0 + 32*(s+1)); nl1 = *(const bfx8*)(bL1 + 32*(s+1));
            }
            if (s < 4) {
                #pragma unroll
                for (int rt = 0; rt < 4; ++rt) {
                    const int aR = aBase + 2*rt + (lr >> 3);
                    const int c4 = s*4 + lh;
                    const int ad = aR*128 + ((c4 ^ (aR & 15)) << 3);
                    const bfx8 ah = *(const bfx8*)&tblH[ad];
                    const bfx8 al = *(const bfx8*)&tblL[ad];
                    acc[rt][0] = mfma3(ah, al, wh0, wl0, acc[rt][0]);
                    acc[rt][1] = mfma3(ah, al, wh1, wl1, acc[rt][1]);
                }
            } else if (s < 8) {
                #pragma unroll
                for (int rt = 0; rt < 4; ++rt) {
                    const int aC = aCol[rt];
                    const int c4 = (s-4)*4 + lh;
                    const int ad = aC*128 + ((c4 ^ (aC & 15)) << 3);
                    const bfx8 ah = *(const bfx8*)&tblH[ad];
                    const bfx8 al = *(const bfx8*)&tblL[ad];
                    acc[rt][0] = mfma3(ah, al, wh0, wl0, acc[rt][0]);
                    acc[rt][1] = mfma3(ah, al, wh1, wl1, acc[rt][1]);
                }
            } else {
                #pragma unroll
                for (int rt = 0; rt < 4; ++rt) {
                    const int r = rt*16 + lr;
                    const int c = (s-8)*4 + lh;
                    const int ad = r*64 + ((c ^ (r & 7)) << 3);
                    const bfx8 ah = *(const bfx8*)&tailB[ad];
                    acc[rt][0] = mfma2(ah, wh0, wl0, acc[rt][0]);
                    acc[rt][1] = mfma2(ah, wh1, wl1, acc[rt][1]);
                }
            }
            wh0 = nh0; wh1 = nh1; wl0 = nl0; wl1 = nl1;
        }
    }

    // ---- bias + in-register LN partials --------------------------------
    {
        const float b10 = be1[colB0], b11 = be1[colB1];
        #pragma unroll
        for (int rt = 0; rt < 4; ++rt)
            #pragma unroll
            for (int j = 0; j < 4; ++j) { acc[rt][0][j] += b10; acc[rt][1][j] += b11; }
    }
    {
        #pragma unroll
        for (int rt = 0; rt < 4; ++rt) {
            float sv[4], qv[4];
            #pragma unroll
            for (int j = 0; j < 4; ++j) {
                const float a0 = acc[rt][0][j], a1 = acc[rt][1][j];
                sv[j] = a0 + a1; qv[j] = a0*a0 + a1*a1;
            }
            #pragma unroll
            for (int msk = 1; msk < 16; msk <<= 1) {
                #pragma unroll
                for (int j = 0; j < 4; ++j) {
                    sv[j] += __shfl_xor(sv[j], msk);
                    qv[j] += __shfl_xor(qv[j], msk);
                }
            }
            if (lr == 0) {
                #pragma unroll
                for (int j = 0; j < 4; ++j) {
                    const int row = rt*16 + 4*lh + j;
                    sStats[(row*4 + w)*2 + 0] = sv[j];
                    sStats[(row*4 + w)*2 + 1] = qv[j];
                }
            }
        }
    }
    __syncthreads();                                    // bar2

    if (tid < EPB) {
        const float4 a = *(const float4*)&sStats[tid*8];
        const float4 b = *(const float4*)&sStats[tid*8 + 4];
        const float st = a.x + a.z + b.x + b.z;
        const float qt = a.y + a.w + b.y + b.w;
        const float mu  = st * (1.0f/HID);
        const float var = qt * (1.0f/HID) - mu*mu;
        sMuInv[tid*2 + 0] = mu;
        sMuInv[tid*2 + 1] = rsqrtf(var + 1e-5f);
    }
    __syncthreads();                                    // bar3

    // ---- GEMM2 weight pointers + first fragments (overlap with LN) -----
    const u16* c2H0 = W2TH + (size_t)colB0*HID + lh*8;
    const u16* c2H1 = W2TH + (size_t)colB1*HID + lh*8;
    const u16* c2L0 = W2TL + (size_t)colB0*HID + lh*8;
    const u16* c2L1 = W2TL + (size_t)colB1*HID + lh*8;
    bfx8 g2h0 = *(const bfx8*)c2H0, g2h1 = *(const bfx8*)c2H1;
    bfx8 g2l0 = *(const bfx8*)c2L0, g2l1 = *(const bfx8*)c2L1;

    // ---- normalize + SiLU in regs, write single-bf16 acts to sB2 -------
    {
        const float G0 = g1[colB0], G1s = g1[colB1];
        const float B0 = bt1[colB0], B1s = bt1[colB1];
        #pragma unroll
        for (int rt = 0; rt < 4; ++rt) {
            const int r0 = rt*16 + 4*lh;
            const float4 mi0 = *(const float4*)&sMuInv[r0*2];      // mu0,inv0,mu1,inv1
            const float4 mi1 = *(const float4*)&sMuInv[r0*2 + 4];  // mu2,inv2,mu3,inv3
            acc[rt][0][0] = siluf(fmaf((acc[rt][0][0]-mi0.x)*mi0.y, G0, B0));
            acc[rt][1][0] = siluf(fmaf((acc[rt][1][0]-mi0.x)*mi0.y, G1s, B1s));
            acc[rt][0][1] = siluf(fmaf((acc[rt][0][1]-mi0.z)*mi0.w, G0, B0));
            acc[rt][1][1] = siluf(fmaf((acc[rt][1][1]-mi0.z)*mi0.w, G1s, B1s));
            acc[rt][0][2] = siluf(fmaf((acc[rt][0][2]-mi1.x)*mi1.y, G0, B0));
            acc[rt][1][2] = siluf(fmaf((acc[rt][1][2]-mi1.x)*mi1.y, G1s, B1s));
            acc[rt][0][3] = siluf(fmaf((acc[rt][0][3]-mi1.z)*mi1.w, G0, B0));
            acc[rt][1][3] = siluf(fmaf((acc[rt][1][3]-mi1.z)*mi1.w, G1s, B1s));
        }
    }
    {
        #pragma unroll
        for (int rt = 0; rt < 4; ++rt) {
            #pragma unroll
            for (int hcol = 0; hcol < 2; ++hcol) {
                const int col = hcol ? colB1 : colB0;
                const int gch = col >> 3, cw = col & 7;
                #pragma unroll
                for (int j = 0; j < 4; ++j) {
                    const int row = rt*16 + 4*lh + j;
                    sB2[row*128 + ((gch ^ (row & 15)) << 3) + cw] =
                        bf16_rn(acc[rt][hcol][j]);
                }
            }
        }
    }
    __syncthreads();                                    // bar4

    // ---- GEMM2: [64 x 128] @ [128 x 128], single-bf16 A, 2-product -----
    f32x4 d[4][2];
    #pragma unroll
    for (int rt = 0; rt < 4; ++rt) { d[rt][0] = (f32x4){0,0,0,0}; d[rt][1] = (f32x4){0,0,0,0}; }
    {
        #pragma unroll
        for (int s = 0; s < 4; ++s) {
            bfx8 nh0 = g2h0, nh1 = g2h1, nl0 = g2l0, nl1 = g2l1;
            if (s < 3) {
                nh0 = *(const bfx8*)(c2H0 + 32*(s+1)); nh1 = *(const bfx8*)(c2H1 + 32*(s+1));
                nl0 = *(const bfx8*)(c2L0 + 32*(s+1)); nl1 = *(const bfx8*)(c2L1 + 32*(s+1));
            }
            #pragma unroll
            for (int rt = 0; rt < 4; ++rt) {
                const int rowL = rt*16 + lr;
                const int c4 = s*4 + lh;
                const bfx8 ah = *(const bfx8*)&sB2[rowL*128 + ((c4 ^ (rowL & 15)) << 3)];
                d[rt][0] = mfma2(ah, g2h0, g2l0, d[rt][0]);
                d[rt][1] = mfma2(ah, g2h1, g2l1, d[rt][1]);
            }
            g2h0 = nh0; g2h1 = nh1; g2l0 = nl0; g2l1 = nl1;
        }
    }

    // ---- SiLU in place (d becomes m) + attention gate ------------------
    {
        const float b20 = be2[colB0], b21 = be2[colB1];
        #pragma unroll
        for (int rt = 0; rt < 4; ++rt) {
            #pragma unroll
            for (int j = 0; j < 4; ++j) {
                d[rt][0][j] = siluf(d[rt][0][j] + b20);
                d[rt][1][j] = siluf(d[rt][1][j] + b21);
            }
        }
    }
    {
        const float wa0 = Watt[colB0], wa1 = Watt[colB1];
        float pa[4][4];
        #pragma unroll
        for (int rt = 0; rt < 4; ++rt)
            #pragma unroll
            for (int j = 0; j < 4; ++j)
                pa[rt][j] = d[rt][0][j]*wa0 + d[rt][1][j]*wa1;
        #pragma unroll
        for (int msk = 1; msk < 16; msk <<= 1) {
            #pragma unroll
            for (int rt = 0; rt < 4; ++rt)
                #pragma unroll
                for (int j = 0; j < 4; ++j)
                    pa[rt][j] += __shfl_xor(pa[rt][j], msk);
        }
        if (lr == 0) {
            #pragma unroll
            for (int rt = 0; rt < 4; ++rt)
                #pragma unroll
                for (int j = 0; j < 4; ++j)
                    sAP[w*64 + rt*16 + 4*lh + j] = pa[rt][j];
        }
    }
    __syncthreads();                                    // bar5
    if (tid < EPB)
        sAttv[tid] = sigf(sAP[tid] + sAP[64+tid] + sAP[128+tid] + sAP[192+tid] + batt[0]);
    __syncthreads();                                    // bar6

    // ---- gated aggregate -> aggH/aggL ----------------------------------
    #pragma unroll
    for (int rt = 0; rt < 4; ++rt) {
        float s0 = 0.0f, s1 = 0.0f;
        #pragma unroll
        for (int j = 0; j < 4; ++j) {
            const float av = sAttv[rt*16 + 4*lh + j];
            s0 += d[rt][0][j]*av;
            s1 += d[rt][1][j]*av;
        }
        s0 += __shfl_xor(s0, 16);
        s1 += __shfl_xor(s1, 16);
        if ((lh & 1) == 0) {
            const int node = node0 + 2*rt + (lh >> 1);
            wragg(aggH, aggL, (size_t)node*HID + colB0, s0*0.2f);
            wragg(aggH, aggL, (size_t)node*HID + colB1, s1*0.2f);
        }
    }
}

// ---------------------------------------------------------------- node (MFMA, 32 nodes/block)
__global__ __launch_bounds__(256, 6) void node_k(
    float* __restrict__ hh, u16* __restrict__ hhH, u16* __restrict__ hhL,
    const u16* __restrict__ aggH, const u16* __restrict__ aggL,
    const u16* __restrict__ B1H, const u16* __restrict__ B1L,
    const u16* __restrict__ B2H, const u16* __restrict__ B2L,
    const float* __restrict__ bn1, const float* __restrict__ g2,
    const float* __restrict__ bt2, const float* __restrict__ bn2)
{
    __shared__ __align__(16) char smem[16896];
    float* sMid = (float*)smem;
    u16* sY = (u16*)smem;                // single-bf16 post-LN acts (8 KB)

    const int tid = threadIdx.x;
    const int node0 = blockIdx.x * 32;
    const int w = tid >> 6, lane = tid & 63, lr = lane & 15, lh = lane >> 4;
    const int colB0 = w*32 + lr, colB1 = colB0 + 16;

    const u16* a1h0 = hhH  + (size_t)(node0+lr)*HID + lh*8;
    const u16* a1l0 = hhL  + (size_t)(node0+lr)*HID + lh*8;
    const u16* a2h0 = aggH + (size_t)(node0+lr)*HID + lh*8;
    const u16* a2l0 = aggL + (size_t)(node0+lr)*HID + lh*8;
    const u16* c1H0 = B1H + (size_t)colB0*256 + lh*8;
    const u16* c1H1 = B1H + (size_t)colB1*256 + lh*8;
    const u16* c1L0 = B1L + (size_t)colB0*256 + lh*8;
    const u16* c1L1 = B1L + (size_t)colB1*256 + lh*8;

    f32x4 acc00={0,0,0,0}, acc01={0,0,0,0}, acc10={0,0,0,0}, acc11={0,0,0,0};
    {
        bfx8 wh0 = *(const bfx8*)c1H0, wh1 = *(const bfx8*)c1H1;
        bfx8 wl0 = *(const bfx8*)c1L0, wl1 = *(const bfx8*)c1L1;
        #pragma unroll
        for (int s = 0; s < 8; ++s) {
            bfx8 nh0 = wh0, nh1 = wh1, nl0 = wl0, nl1 = wl1;
            if (s < 7) {
                nh0 = *(const bfx8*)(c1H0 + 32*(s+1)); nh1 = *(const bfx8*)(c1H1 + 32*(s+1));
                nl0 = *(const bfx8*)(c1L0 + 32*(s+1)); nl1 = *(const bfx8*)(c1L1 + 32*(s+1));
            }
            bfx8 ah0, ah1, al0, al1;
            if (s < 4) {
                ah0 = *(const bfx8*)(a1h0 + 32*s);            ah1 = *(const bfx8*)(a1h0 + 16*HID + 32*s);
                al0 = *(const bfx8*)(a1l0 + 32*s);            al1 = *(const bfx8*)(a1l0 + 16*HID + 32*s);
            } else {
                ah0 = *(const bfx8*)(a2h0 + 32*(s-4));        ah1 = *(const bfx8*)(a2h0 + 16*HID + 32*(s-4));
                al0 = *(const bfx8*)(a2l0 + 32*(s-4));        al1 = *(const bfx8*)(a2l0 + 16*HID + 32*(s-4));
            }
            acc00 = mfma3(ah0, al0, wh0, wl0, acc00);
            acc01 = mfma3(ah0, al0, wh1, wl1, acc01);
            acc10 = mfma3(ah1, al1, wh0, wl0, acc10);
            acc11 = mfma3(ah1, al1, wh1, wl1, acc11);
            wh0 = nh0; wh1 = nh1; wl0 = nl0; wl1 = nl1;
        }
    }
    {
        const float b10 = bn1[colB0], b11 = bn1[colB1];
        #pragma unroll
        for (int j = 0; j < 4; ++j) {
            const int r0 = 4*lh + j;
            sMid[r0*MIDSTR + colB0]      = acc00[j] + b10;
            sMid[r0*MIDSTR + colB1]      = acc01[j] + b11;
            sMid[(16+r0)*MIDSTR + colB0] = acc10[j] + b10;
            sMid[(16+r0)*MIDSTR + colB1] = acc11[j] + b11;
        }
    }
    __syncthreads();

    float y[16];
    const int eLN = tid >> 3, c0 = (tid & 7)*16;
    {
        const float* mrow = &sMid[eLN*MIDSTR + c0];
        float4 v0 = *(const float4*)&mrow[0];
        float4 v1 = *(const float4*)&mrow[4];
        float4 v2 = *(const float4*)&mrow[8];
        float4 v3 = *(const float4*)&mrow[12];
        float s = v0.x+v0.y+v0.z+v0.w + v1.x+v1.y+v1.z+v1.w
                + v2.x+v2.y+v2.z+v2.w + v3.x+v3.y+v3.z+v3.w;
        float q = v0.x*v0.x+v0.y*v0.y+v0.z*v0.z+v0.w*v0.w
                + v1.x*v1.x+v1.y*v1.y+v1.z*v1.z+v1.w*v1.w
                + v2.x*v2.x+v2.y*v2.y+v2.z*v2.z+v2.w*v2.w
                + v3.x*v3.x+v3.y*v3.y+v3.z*v3.z+v3.w*v3.w;
        #pragma unroll
        for (int m = 4; m >= 1; m >>= 1) { s += __shfl_xor(s, m); q += __shfl_xor(q, m); }
        float mu  = s * (1.0f/HID);
        float var = q * (1.0f/HID) - mu*mu;
        float inv = rsqrtf(var + 1e-5f);
        const float4 G0 = *(const float4*)&g2[c0+0],  G1v = *(const float4*)&g2[c0+4];
        const float4 G2 = *(const float4*)&g2[c0+8],  G3 = *(const float4*)&g2[c0+12];
        const float4 B0 = *(const float4*)&bt2[c0+0], B1 = *(const float4*)&bt2[c0+4];
        const float4 B2 = *(const float4*)&bt2[c0+8], B3 = *(const float4*)&bt2[c0+12];
        y[0]=siluf(fmaf((v0.x-mu)*inv,G0.x,B0.x));  y[1]=siluf(fmaf((v0.y-mu)*inv,G0.y,B0.y));
        y[2]=siluf(fmaf((v0.z-mu)*inv,G0.z,B0.z));  y[3]=siluf(fmaf((v0.w-mu)*inv,G0.w,B0.w));
        y[4]=siluf(fmaf((v1.x-mu)*inv,G1v.x,B1.x)); y[5]=siluf(fmaf((v1.y-mu)*inv,G1v.y,B1.y));
        y[6]=siluf(fmaf((v1.z-mu)*inv,G1v.z,B1.z)); y[7]=siluf(fmaf((v1.w-mu)*inv,G1v.w,B1.w));
        y[8]=siluf(fmaf((v2.x-mu)*inv,G2.x,B2.x));  y[9]=siluf(fmaf((v2.y-mu)*inv,G2.y,B2.y));
        y[10]=siluf(fmaf((v2.z-mu)*inv,G2.z,B2.z)); y[11]=siluf(fmaf((v2.w-mu)*inv,G2.w,B2.w));
        y[12]=siluf(fmaf((v3.x-mu)*inv,G3.x,B3.x)); y[13]=siluf(fmaf((v3.y-mu)*inv,G3.y,B3.y));
        y[14]=siluf(fmaf((v3.z-mu)*inv,G3.z,B3.z)); y[15]=siluf(fmaf((v3.w-mu)*inv,G3.w,B3.w));
    }
    __syncthreads();
    {
        U8 ha, hb2;
        #pragma unroll
        for (int j = 0; j < 8; ++j) {
            ha.a[j]  = bf16_rn(y[j]);
            hb2.a[j] = bf16_rn(y[8+j]);
        }
        const int cA = (2*(tid & 7))     ^ (eLN & 15);
        const int cB = (2*(tid & 7) + 1) ^ (eLN & 15);
        *(bfx8*)&sY[eLN*128 + (cA << 3)] = ha.v;
        *(bfx8*)&sY[eLN*128 + (cB << 3)] = hb2.v;
    }
    __syncthreads();

    f32x4 d00={0,0,0,0}, d01={0,0,0,0}, d10={0,0,0,0}, d11={0,0,0,0};
    {
        const u16* c2H0 = B2H + (size_t)colB0*HID + lh*8;
        const u16* c2H1 = B2H + (size_t)colB1*HID + lh*8;
        const u16* c2L0 = B2L + (size_t)colB0*HID + lh*8;
        const u16* c2L1 = B2L + (size_t)colB1*HID + lh*8;
        bfx8 wh0 = *(const bfx8*)c2H0, wh1 = *(const bfx8*)c2H1;
        bfx8 wl0 = *(const bfx8*)c2L0, wl1 = *(const bfx8*)c2L1;
        #pragma unroll
        for (int s = 0; s < 4; ++s) {
            bfx8 nh0 = wh0, nh1 = wh1, nl0 = wl0, nl1 = wl1;
            if (s < 3) {
                nh0 = *(const bfx8*)(c2H0 + 32*(s+1)); nh1 = *(const bfx8*)(c2H1 + 32*(s+1));
                nl0 = *(const bfx8*)(c2L0 + 32*(s+1)); nl1 = *(const bfx8*)(c2L1 + 32*(s+1));
            }
            const int c4 = s*4 + lh;
            const int i0 = lr*128 + ((c4 ^ lr) << 3);
            const int i1 = (16+lr)*128 + ((c4 ^ lr) << 3);
            bfx8 ah0 = *(const bfx8*)&sY[i0], ah1 = *(const bfx8*)&sY[i1];
            d00 = mfma2(ah0, wh0, wl0, d00);
            d01 = mfma2(ah0, wh1, wl1, d01);
            d10 = mfma2(ah1, wh0, wl0, d10);
            d11 = mfma2(ah1, wh1, wl1, d11);
            wh0 = nh0; wh1 = nh1; wl0 = nl0; wl1 = nl1;
        }
    }

    {
        const float b20 = bn2[colB0], b21 = bn2[colB1];
        #pragma unroll
        for (int j = 0; j < 4; ++j) {
            const int r0 = 4*lh + j, r1 = 16 + 4*lh + j;
            const size_t i00 = (size_t)(node0+r0)*HID + colB0;
            const size_t i01 = (size_t)(node0+r0)*HID + colB1;
            const size_t i10 = (size_t)(node0+r1)*HID + colB0;
            const size_t i11 = (size_t)(node0+r1)*HID + colB1;
            float v00 = hh[i00] + d00[j] + b20;
            float v01 = hh[i01] + d01[j] + b21;
            float v10 = hh[i10] + d10[j] + b20;
            float v11 = hh[i11] + d11[j] + b21;
            hh[i00] = v00; hh[i01] = v01; hh[i10] = v10; hh[i11] = v11;
            u16 h00 = bf16_rn(v00); hhH[i00] = h00; hhL[i00] = bf16_rn(v00 - bf16_tof(h00));
            u16 h01 = bf16_rn(v01); hhH[i01] = h01; hhL[i01] = bf16_rn(v01 - bf16_tof(h01));
            u16 h10 = bf16_rn(v10); hhH[i10] = h10; hhL[i10] = bf16_rn(v10 - bf16_tof(h10));
            u16 h11 = bf16_rn(v11); hhH[i11] = h11; hhL[i11] = bf16_rn(v11 - bf16_tof(h11));
        }
    }
}

// ---------------------------------------------------------------- output head
__global__ __launch_bounds__(HID) void out_k(
    const float* __restrict__ hh, const float* __restrict__ Woe,
    const float* __restrict__ boe, const float* __restrict__ Wf,
    const float* __restrict__ bf, float* __restrict__ out)
{
    __shared__ float sH[HID];
    const int lig = blockIdx.x, tid = threadIdx.x;
    float s = 0.0f;
    const float* base = hh + (size_t)lig*KAT*HID + tid;
    #pragma unroll 8
    for (int a = 0; a < KAT; ++a) s += base[a*HID];
    sH[tid] = s * (1.0f/KAT);
    __syncthreads();

    float contrib = 0.0f;
    if (tid < OUTF) {
        float p = boe[tid];
        #pragma unroll 4
        for (int i = 0; i < HID; ++i)
            p = fmaf(sH[i], Woe[i*OUTF + tid], p);
        contrib = p * Wf[tid];
    }
    #pragma unroll
    for (int m = 1; m < 64; m <<= 1) contrib += __shfl_xor(contrib, m);
    if (tid == 0) out[lig] = contrib + bf[0];
}

// ---------------------------------------------------------------- launch
extern "C" void kernel_launch(void* const* d_in, const int* in_sizes, int n_in,
                              void* d_out, int out_size, void* d_ws, size_t ws_size,
                              hipStream_t stream)
{
    (void)in_sizes; (void)n_in; (void)out_size; (void)ws_size;
    const float* x    = (const float*)d_in[0];
    const float* h    = (const float*)d_in[1];
    const int*   t    = (const int*)d_in[2];
    const int*   edges= (const int*)d_in[3];
    const int*   tb   = (const int*)d_in[4];
    const float* temb = (const float*)d_in[8];
    const float* Win  = (const float*)d_in[9];
    const float* bin  = (const float*)d_in[10];
    const float* We1  = (const float*)d_in[11];
    const float* be1  = (const float*)d_in[12];
    const float* g1   = (const float*)d_in[13];
    const float* bt1  = (const float*)d_in[14];
    const float* We2  = (const float*)d_in[15];
    const float* be2  = (const float*)d_in[16];
    const float* Watt = (const float*)d_in[17];
    const float* batt = (const float*)d_in[18];
    const float* Wn1  = (const float*)d_in[19];
    const float* bn1  = (const float*)d_in[20];
    const float* g2   = (const float*)d_in[21];
    const float* bt2  = (const float*)d_in[22];
    const float* Wn2  = (const float*)d_in[23];
    const float* bn2  = (const float*)d_in[24];
    const float* Woe  = (const float*)d_in[25];
    const float* boe  = (const float*)d_in[26];
    const float* Wf   = (const float*)d_in[27];
    const float* bf   = (const float*)d_in[28];
    float* out = (float*)d_out;

    char* wsb = (char*)d_ws;
    float* hh  = (float*)(wsb);                        // 16 MB
    u16* hhH   = (u16*)(wsb + ((size_t)16<<20));       // 8 MB
    u16* hhL   = (u16*)(wsb + ((size_t)24<<20));       // 8 MB
    u16* aggH  = (u16*)(wsb + ((size_t)32<<20));       // 8 MB
    u16* aggL  = (u16*)(wsb + ((size_t)40<<20));       // 8 MB
    u16* tembH = (u16*)(wsb + ((size_t)48<<20));
    u16* tembL = tembH + PREP_TEMB;
    u16* W1TH  = tembL + PREP_TEMB;
    u16* W1TL  = W1TH + PREP_W1;
    u16* W2TH  = W1TL + PREP_W1;
    u16* W2TL  = W2TH + PREP_W2;
    u16* WN1TH = W2TL + PREP_W2;
    u16* WN1TL = WN1TH + PREP_WN1;
    u16* WN2TH = WN1TL + PREP_WN1;
    u16* WN2TL = WN2TH + PREP_WN2;

    prep_k<<<(PREP_TOT + 255)/256, 256, 0, stream>>>(
        temb, We1, We2, Wn1, Wn2,
        tembH, tembL, W1TH, W1TL, W2TH, W2TL, WN1TH, WN1TL, WN2TH, WN2TL);

    embed_k<<<NNODES/8, 256, 0, stream>>>(h, t, temb, Win, bin, hh, hhH, hhL);

    for (int l = 0; l < 4; ++l) {
        edge_k<<<NNODES/NPB, 256, 0, stream>>>(
            hhH, hhL, x, edges + NEDGES, tb, tembH, tembL,
            W1TH + (size_t)l*128*K1, W1TL + (size_t)l*128*K1,
            W2TH + (size_t)l*128*128, W2TL + (size_t)l*128*128,
            be1 + l*HID, g1 + l*HID, bt1 + l*HID, be2 + l*HID,
            Watt + l*HID, batt + l, aggH, aggL);
        node_k<<<NNODES/32, 256, 0, stream>>>(
            hh, hhH, hhL, aggH, aggL,
            WN1TH + (size_t)l*128*256, WN1TL + (size_t)l*128*256,
            WN2TH + (size_t)l*128*128, WN2TL + (size_t)l*128*128,
            bn1 + l*HID, g2 + l*HID, bt2 + l*HID, bn2 + l*HID);
    }
    out_k<<<NLIG, HID, 0, stream>>>(hh, Woe, boe, Wf, bf, out);
}

// Round 10
// 702.424 us; speedup vs baseline: 1.3425x; 1.0534x over previous
//
#include <hip/hip_runtime.h>
#include <math.h>

#define NNODES 32768
#define NLIG   1024
#define KAT    32
#define KNN    8
#define NEDGES (NNODES*KNN)
#define HID    128
#define TF     16
#define NG     20
#define OUTF   64

#define NPB    16           // nodes per edge-block
#define EPB    128          // edges per edge-block
#define K1     320          // padded GEMM1 K (292 -> 320)
#define MIDSTR 132          // node_k sMid row stride (floats)

typedef unsigned short u16;
typedef __attribute__((__ext_vector_type__(8))) short bfx8;
typedef __attribute__((__ext_vector_type__(4))) float f32x4;

union U8 { u16 a[8]; bfx8 v; };

// Gaussian smearing constants: og[g] = 5^(g/19)-1, coeff = -0.5/diff^2
__device__ const float GS_OG[20] = {
    0.0f, 0.0883984f, 0.1845966f, 0.2893285f, 0.4033028f,
    0.5273539f, 0.6623701f, 0.8093209f, 0.9692606f, 1.1433389f,
    1.3328075f, 1.5390240f, 1.7634662f, 2.0077560f, 2.2736369f,
    2.5630207f, 2.8779861f, 3.2207938f, 3.5939058f, 4.0f };
__device__ const float GS_CF[20] = {
    -63.9853f, -63.9853f, -54.0303f, -45.5840f, -38.4908f,
    -32.4913f, -27.4283f, -23.1540f, -19.5460f, -16.4999f,
    -13.9282f, -11.7577f, -9.92569f, -8.37837f, -7.07287f,
    -5.97065f, -5.04016f, -4.25470f, -3.59163f, -3.03191f };

__device__ __forceinline__ float siluf(float v) {
    return __fdividef(v, 1.0f + __expf(-v));
}
__device__ __forceinline__ float sigf(float v) {
    return __fdividef(1.0f, 1.0f + __expf(-v));
}
__device__ __forceinline__ u16 bf16_rn(float f) {
    union { float f; unsigned u; } v; v.f = f;
    unsigned r = v.u + 0x7FFFu + ((v.u >> 16) & 1u);
    return (u16)(r >> 16);
}
__device__ __forceinline__ float bf16_tof(u16 u) {
    union { unsigned u; float f; } v; v.u = ((unsigned)u) << 16;
    return v.f;
}
__device__ __forceinline__ f32x4 mfma3(bfx8 ah, bfx8 al, bfx8 wh, bfx8 wl, f32x4 c) {
    c = __builtin_amdgcn_mfma_f32_16x16x32_bf16(ah, wh, c, 0, 0, 0);
    c = __builtin_amdgcn_mfma_f32_16x16x32_bf16(ah, wl, c, 0, 0, 0);
    c = __builtin_amdgcn_mfma_f32_16x16x32_bf16(al, wh, c, 0, 0, 0);
    return c;
}
__device__ __forceinline__ f32x4 mfma2(bfx8 ah, bfx8 wh, bfx8 wl, f32x4 c) {
    c = __builtin_amdgcn_mfma_f32_16x16x32_bf16(ah, wh, c, 0, 0, 0);
    c = __builtin_amdgcn_mfma_f32_16x16x32_bf16(ah, wl, c, 0, 0, 0);
    return c;
}
__device__ __forceinline__ void wragg(u16* __restrict__ H, u16* __restrict__ L,
                                      size_t i, float v) {
    u16 hb = bf16_rn(v);
    H[i] = hb; L[i] = bf16_rn(v - bf16_tof(hb));
}

// ---------------------------------------------------------------- prep
#define PREP_TEMB 16000
#define PREP_W1   (4*128*K1)       // 163840
#define PREP_W2   (4*128*128)      // 65536
#define PREP_WN1  (4*128*256)      // 131072
#define PREP_WN2  (4*128*128)      // 65536
#define PREP_TOT  (PREP_TEMB+PREP_W1+PREP_W2+PREP_WN1+PREP_WN2)

__global__ __launch_bounds__(256) void prep_k(
    const float* __restrict__ temb, const float* __restrict__ We1,
    const float* __restrict__ We2,  const float* __restrict__ Wn1,
    const float* __restrict__ Wn2,
    u16* __restrict__ tembH, u16* __restrict__ tembL,
    u16* __restrict__ W1TH, u16* __restrict__ W1TL,
    u16* __restrict__ W2TH, u16* __restrict__ W2TL,
    u16* __restrict__ WN1TH, u16* __restrict__ WN1TL,
    u16* __restrict__ WN2TH, u16* __restrict__ WN2TL)
{
    int i = blockIdx.x*256 + threadIdx.x;
    if (i >= PREP_TOT) return;
    float v; u16 *dh, *dl; int di;
    if (i < PREP_TEMB) {
        v = temb[i]; dh = tembH; dl = tembL; di = i;
    } else if (i < PREP_TEMB + PREP_W1) {
        int j = i - PREP_TEMB; di = j; dh = W1TH; dl = W1TL;
        int l = j / (128*K1); int r = j - l*(128*K1);
        int col = r / K1, k = r - col*K1;
        v = (k < 292) ? We1[(size_t)l*292*128 + (size_t)k*128 + col] : 0.0f;
    } else if (i < PREP_TEMB + PREP_W1 + PREP_W2) {
        int j = i - PREP_TEMB - PREP_W1; di = j; dh = W2TH; dl = W2TL;
        int l = j >> 14; int r = j & 16383;
        int col = r >> 7, k = r & 127;
        v = We2[(size_t)l*16384 + (size_t)k*128 + col];
    } else if (i < PREP_TEMB + PREP_W1 + PREP_W2 + PREP_WN1) {
        int j = i - PREP_TEMB - PREP_W1 - PREP_W2; di = j; dh = WN1TH; dl = WN1TL;
        int l = j >> 15; int r = j & 32767;
        int col = r >> 8, k = r & 255;
        v = Wn1[(size_t)l*32768 + (size_t)k*128 + col];
    } else {
        int j = i - PREP_TEMB - PREP_W1 - PREP_W2 - PREP_WN1; di = j; dh = WN2TH; dl = WN2TL;
        int l = j >> 14; int r = j & 16383;
        int col = r >> 7, k = r & 127;
        v = Wn2[(size_t)l*16384 + (size_t)k*128 + col];
    }
    u16 hb = bf16_rn(v);
    dh[di] = hb;
    dl[di] = bf16_rn(v - bf16_tof(hb));
}

// ---------------------------------------------------------------- embed (8 nodes/block)
__global__ __launch_bounds__(256) void embed_k(
    const float* __restrict__ h, const int* __restrict__ t,
    const float* __restrict__ temb, const float* __restrict__ Win,
    const float* __restrict__ bin, float* __restrict__ hh,
    u16* __restrict__ hhH, u16* __restrict__ hhL)
{
    __shared__ float sIn[8][32];
    const int tid = threadIdx.x;
    {
        const int n = tid >> 5, i = tid & 31;
        const int node = blockIdx.x*8 + n;
        sIn[n][i] = (i < TF) ? h[node*TF + i] : temb[t[node]*TF + (i-TF)];
    }
    __syncthreads();
    const int sub = tid >> 7, col = tid & 127;
    float acc[4];
    const float b = bin[col];
    acc[0]=acc[1]=acc[2]=acc[3]=b;
    #pragma unroll 8
    for (int i = 0; i < 32; ++i) {
        const float wv = Win[i*HID + col];
        acc[0] = fmaf(sIn[sub][i],   wv, acc[0]);
        acc[1] = fmaf(sIn[2+sub][i], wv, acc[1]);
        acc[2] = fmaf(sIn[4+sub][i], wv, acc[2]);
        acc[3] = fmaf(sIn[6+sub][i], wv, acc[3]);
    }
    #pragma unroll
    for (int nn = 0; nn < 4; ++nn) {
        const size_t idx = (size_t)(blockIdx.x*8 + nn*2 + sub)*HID + col;
        hh[idx] = acc[nn];
        u16 hb = bf16_rn(acc[nn]);
        hhH[idx] = hb; hhL[idx] = bf16_rn(acc[nn] - bf16_tof(hb));
    }
}

// ---------------------------------------------------------------- edge
// M=128 (16 nodes, 128 edges / block). In-reg LN, single-bf16 post-LN acts,
// single-pass 2-product GEMM2. LDS 38.4 KB, 6 barriers.
__global__ __launch_bounds__(256, 4) void edge_k(
    const u16* __restrict__ hhH, const u16* __restrict__ hhL,
    const float* __restrict__ x,
    const int* __restrict__ ecol, const int* __restrict__ tbond,
    const u16* __restrict__ tembH, const u16* __restrict__ tembL,
    const u16* __restrict__ W1TH, const u16* __restrict__ W1TL,
    const u16* __restrict__ W2TH, const u16* __restrict__ W2TL,
    const float* __restrict__ be1, const float* __restrict__ g1,
    const float* __restrict__ bt1, const float* __restrict__ be2,
    const float* __restrict__ Watt, const float* __restrict__ batt,
    u16* __restrict__ aggH, u16* __restrict__ aggL)
{
    // LDS (38400 B):
    //  [0,16384)      tblH(8K)+tblL(8K)      | after LN: sB2 (128x128 u16 = 32K)
    //  [16384,32768)  tailB (128 x 64 u16)   | (sB2 tail half)
    //  [32768,36864)  sStats (128 x 4 x f32x2) | after GEMM2: sAP (512 f32)
    //  [36864,37888)  sMuInv (128 x f32x2)
    //  [37888,38400)  sAttv (128 f32)
    __shared__ __align__(16) char smem[38400];
    u16*   tblH  = (u16*)(smem);
    u16*   tblL  = (u16*)(smem + 8192);
    u16*   tailB = (u16*)(smem + 16384);
    float* sStats= (float*)(smem + 32768);
    float* sMuInv= (float*)(smem + 36864);
    u16*   sB2   = (u16*)(smem);
    float* sAP   = (float*)(smem + 32768);
    float* sAttv = (float*)(smem + 37888);

    const int tid = threadIdx.x;
    const int node0 = blockIdx.x * NPB;
    const int ligBase = node0 & ~31;
    const int aBase   = node0 & 31;      // 0 or 16
    const int w = tid >> 6, lane = tid & 63, lr = lane & 15, lh = lane >> 4;
    const int colB0 = w*32 + lr, colB1 = colB0 + 16;

    // ---- per-lane col atom ids, packed 8x8b into 2 u32 -----------------
    unsigned aColPk0 = 0, aColPk1 = 0;
    #pragma unroll
    for (int rt = 0; rt < 4; ++rt)
        aColPk0 |= (unsigned)(ecol[node0*KNN + rt*16 + lr] & 31) << (rt*8);
    #pragma unroll
    for (int rt = 0; rt < 4; ++rt)
        aColPk1 |= (unsigned)(ecol[node0*KNN + (4+rt)*16 + lr] & 31) << (rt*8);

    // ---- GEMM1 weight pointers + first fragments -----------------------
    const u16* bH0 = W1TH + (size_t)colB0*K1 + lh*8;
    const u16* bH1 = W1TH + (size_t)colB1*K1 + lh*8;
    const u16* bL0 = W1TL + (size_t)colB0*K1 + lh*8;
    const u16* bL1 = W1TL + (size_t)colB1*K1 + lh*8;
    bfx8 wh0 = *(const bfx8*)bH0, wh1 = *(const bfx8*)bH1;
    bfx8 wl0 = *(const bfx8*)bL0, wl1 = *(const bfx8*)bL1;

    // ---- stage ligand hh table (32 atoms x 16 chunks, hi/lo) -----------
    for (int idx = tid; idx < 1024; idx += 256) {
        const int hl = idx >> 9, rem = idx & 511;
        const int a = rem >> 4, c4 = rem & 15;
        const bfx8 v = *(const bfx8*)((hl ? hhL : hhH) + (size_t)(ligBase + a)*HID + c4*8);
        u16* dst = hl ? tblL : tblH;
        *(bfx8*)&dst[a*128 + ((c4 ^ (a & 15)) << 3)] = v;
    }

    // ---- tail (single bf16) [128 rows][8 chunks]: temb(2)|smear(3)|0(3)
    for (int pe = tid; pe < 1024; pe += 256) {
        const int row = pe & 127, part = pe >> 7;
        U8 vh;
        if (part < 2) {
            const int r = node0 + (row >> 3);
            const int c = ecol[node0*KNN + row];
            int sbi = r*(KAT-1) + c - (r/KAT)*KAT - (r < c ? 1 : 0);
            const int tb = tbond[sbi];
            #pragma unroll
            for (int j = 0; j < 8; ++j)
                vh.a[j] = tembH[tb*TF + part*8 + j];
        } else if (part < 5) {
            const int r = node0 + (row >> 3);
            const int c = ecol[node0*KNN + row];
            float dx = x[3*r]-x[3*c], dy = x[3*r+1]-x[3*c+1], dz = x[3*r+2]-x[3*c+2];
            float dist = fminf(sqrtf(dx*dx+dy*dy+dz*dz), 4.0f);
            #pragma unroll
            for (int j = 0; j < 8; ++j) {
                int g = (part-2)*8 + j;
                float v = 0.0f;
                if (g < NG) {
                    float dd = dist - GS_OG[g];
                    v = __expf(GS_CF[g]*dd*dd);
                }
                vh.a[j] = bf16_rn(v);
            }
        } else {
            #pragma unroll
            for (int j = 0; j < 8; ++j) vh.a[j] = 0;
        }
        *(bfx8*)&tailB[row*64 + ((part ^ (row & 7)) << 3)] = vh.v;
    }
    __syncthreads();                                    // bar1

    // ---- GEMM1: [128 x 320] @ [320 x 128], 1-deep W prefetch -----------
    f32x4 acc[8][2];
    #pragma unroll
    for (int rt = 0; rt < 8; ++rt) { acc[rt][0] = (f32x4){0,0,0,0}; acc[rt][1] = (f32x4){0,0,0,0}; }
    {
        #pragma unroll
        for (int s = 0; s < 10; ++s) {
            bfx8 nh0 = wh0, nh1 = wh1, nl0 = wl0, nl1 = wl1;
            if (s < 9) {
                nh0 = *(const bfx8*)(bH0 + 32*(s+1)); nh1 = *(const bfx8*)(bH1 + 32*(s+1));
                nl0 = *(const bfx8*)(bL0 + 32*(s+1)); nl1 = *(const bfx8*)(bL1 + 32*(s+1));
            }
            if (s < 4) {
                #pragma unroll
                for (int rt = 0; rt < 8; ++rt) {
                    const int aR = aBase + 2*rt + (lr >> 3);
                    const int c4 = s*4 + lh;
                    const int ad = aR*128 + ((c4 ^ (aR & 15)) << 3);
                    const bfx8 ah = *(const bfx8*)&tblH[ad];
                    const bfx8 al = *(const bfx8*)&tblL[ad];
                    acc[rt][0] = mfma3(ah, al, wh0, wl0, acc[rt][0]);
                    acc[rt][1] = mfma3(ah, al, wh1, wl1, acc[rt][1]);
                }
            } else if (s < 8) {
                #pragma unroll
                for (int rt = 0; rt < 8; ++rt) {
                    const int aC = (int)((rt < 4 ? (aColPk0 >> (rt*8))
                                                 : (aColPk1 >> ((rt-4)*8))) & 31u);
                    const int c4 = (s-4)*4 + lh;
                    const int ad = aC*128 + ((c4 ^ (aC & 15)) << 3);
                    const bfx8 ah = *(const bfx8*)&tblH[ad];
                    const bfx8 al = *(const bfx8*)&tblL[ad];
                    acc[rt][0] = mfma3(ah, al, wh0, wl0, acc[rt][0]);
                    acc[rt][1] = mfma3(ah, al, wh1, wl1, acc[rt][1]);
                }
            } else {
                #pragma unroll
                for (int rt = 0; rt < 8; ++rt) {
                    const int r = rt*16 + lr;
                    const int c = (s-8)*4 + lh;
                    const int ad = r*64 + ((c ^ (r & 7)) << 3);
                    const bfx8 ah = *(const bfx8*)&tailB[ad];
                    acc[rt][0] = mfma2(ah, wh0, wl0, acc[rt][0]);
                    acc[rt][1] = mfma2(ah, wh1, wl1, acc[rt][1]);
                }
            }
            wh0 = nh0; wh1 = nh1; wl0 = nl0; wl1 = nl1;
        }
    }

    // ---- bias + in-register LN partials --------------------------------
    {
        const float b10 = be1[colB0], b11 = be1[colB1];
        #pragma unroll
        for (int rt = 0; rt < 8; ++rt)
            #pragma unroll
            for (int j = 0; j < 4; ++j) { acc[rt][0][j] += b10; acc[rt][1][j] += b11; }
    }
    {
        #pragma unroll
        for (int rt = 0; rt < 8; ++rt) {
            float sv[4], qv[4];
            #pragma unroll
            for (int j = 0; j < 4; ++j) {
                const float a0 = acc[rt][0][j], a1 = acc[rt][1][j];
                sv[j] = a0 + a1; qv[j] = a0*a0 + a1*a1;
            }
            #pragma unroll
            for (int msk = 1; msk < 16; msk <<= 1) {
                #pragma unroll
                for (int j = 0; j < 4; ++j) {
                    sv[j] += __shfl_xor(sv[j], msk);
                    qv[j] += __shfl_xor(qv[j], msk);
                }
            }
            if (lr == 0) {
                #pragma unroll
                for (int j = 0; j < 4; ++j) {
                    const int row = rt*16 + 4*lh + j;
                    sStats[(row*4 + w)*2 + 0] = sv[j];
                    sStats[(row*4 + w)*2 + 1] = qv[j];
                }
            }
        }
    }
    __syncthreads();                                    // bar2

    if (tid < EPB) {
        const float4 a = *(const float4*)&sStats[tid*8];
        const float4 b = *(const float4*)&sStats[tid*8 + 4];
        const float st = a.x + a.z + b.x + b.z;
        const float qt = a.y + a.w + b.y + b.w;
        const float mu  = st * (1.0f/HID);
        const float var = qt * (1.0f/HID) - mu*mu;
        sMuInv[tid*2 + 0] = mu;
        sMuInv[tid*2 + 1] = rsqrtf(var + 1e-5f);
    }
    __syncthreads();                                    // bar3

    // ---- GEMM2 weight pointers + first fragments -----------------------
    const u16* c2H0 = W2TH + (size_t)colB0*HID + lh*8;
    const u16* c2H1 = W2TH + (size_t)colB1*HID + lh*8;
    const u16* c2L0 = W2TL + (size_t)colB0*HID + lh*8;
    const u16* c2L1 = W2TL + (size_t)colB1*HID + lh*8;
    bfx8 g2h0 = *(const bfx8*)c2H0, g2h1 = *(const bfx8*)c2H1;
    bfx8 g2l0 = *(const bfx8*)c2L0, g2l1 = *(const bfx8*)c2L1;

    // ---- normalize + SiLU in regs, write single-bf16 acts to sB2 -------
    {
        const float G0 = g1[colB0], G1s = g1[colB1];
        const float B0 = bt1[colB0], B1s = bt1[colB1];
        #pragma unroll
        for (int rt = 0; rt < 8; ++rt) {
            const int r0 = rt*16 + 4*lh;
            const float4 mi0 = *(const float4*)&sMuInv[r0*2];      // mu0,inv0,mu1,inv1
            const float4 mi1 = *(const float4*)&sMuInv[r0*2 + 4];  // mu2,inv2,mu3,inv3
            acc[rt][0][0] = siluf(fmaf((acc[rt][0][0]-mi0.x)*mi0.y, G0, B0));
            acc[rt][1][0] = siluf(fmaf((acc[rt][1][0]-mi0.x)*mi0.y, G1s, B1s));
            acc[rt][0][1] = siluf(fmaf((acc[rt][0][1]-mi0.z)*mi0.w, G0, B0));
            acc[rt][1][1] = siluf(fmaf((acc[rt][1][1]-mi0.z)*mi0.w, G1s, B1s));
            acc[rt][0][2] = siluf(fmaf((acc[rt][0][2]-mi1.x)*mi1.y, G0, B0));
            acc[rt][1][2] = siluf(fmaf((acc[rt][1][2]-mi1.x)*mi1.y, G1s, B1s));
            acc[rt][0][3] = siluf(fmaf((acc[rt][0][3]-mi1.z)*mi1.w, G0, B0));
            acc[rt][1][3] = siluf(fmaf((acc[rt][1][3]-mi1.z)*mi1.w, G1s, B1s));
        }
    }
    __syncthreads();                                    // bar4 (tbl/tail reads done; sB2 aliases them)
    {
        #pragma unroll
        for (int rt = 0; rt < 8; ++rt) {
            #pragma unroll
            for (int hcol = 0; hcol < 2; ++hcol) {
                const int col = hcol ? colB1 : colB0;
                const int gch = col >> 3, cw = col & 7;
                #pragma unroll
                for (int j = 0; j < 4; ++j) {
                    const int row = rt*16 + 4*lh + j;
                    sB2[row*128 + ((gch ^ (row & 15)) << 3) + cw] =
                        bf16_rn(acc[rt][hcol][j]);
                }
            }
        }
    }
    __syncthreads();                                    // bar5

    // ---- GEMM2: [128 x 128] @ [128 x 128], single-bf16 A, 2-product ----
    f32x4 d[8][2];
    #pragma unroll
    for (int rt = 0; rt < 8; ++rt) { d[rt][0] = (f32x4){0,0,0,0}; d[rt][1] = (f32x4){0,0,0,0}; }
    {
        #pragma unroll
        for (int s = 0; s < 4; ++s) {
            bfx8 nh0 = g2h0, nh1 = g2h1, nl0 = g2l0, nl1 = g2l1;
            if (s < 3) {
                nh0 = *(const bfx8*)(c2H0 + 32*(s+1)); nh1 = *(const bfx8*)(c2H1 + 32*(s+1));
                nl0 = *(const bfx8*)(c2L0 + 32*(s+1)); nl1 = *(const bfx8*)(c2L1 + 32*(s+1));
            }
            #pragma unroll
            for (int rt = 0; rt < 8; ++rt) {
                const int rowL = rt*16 + lr;
                const int c4 = s*4 + lh;
                const bfx8 ah = *(const bfx8*)&sB2[rowL*128 + ((c4 ^ (rowL & 15)) << 3)];
                d[rt][0] = mfma2(ah, g2h0, g2l0, d[rt][0]);
                d[rt][1] = mfma2(ah, g2h1, g2l1, d[rt][1]);
            }
            g2h0 = nh0; g2h1 = nh1; g2l0 = nl0; g2l1 = nl1;
        }
    }

    // ---- SiLU in place (d becomes m) + attention gate ------------------
    {
        const float b20 = be2[colB0], b21 = be2[colB1];
        #pragma unroll
        for (int rt = 0; rt < 8; ++rt) {
            #pragma unroll
            for (int j = 0; j < 4; ++j) {
                d[rt][0][j] = siluf(d[rt][0][j] + b20);
                d[rt][1][j] = siluf(d[rt][1][j] + b21);
            }
        }
    }
    {
        const float wa0 = Watt[colB0], wa1 = Watt[colB1];
        float pa[8][4];
        #pragma unroll
        for (int rt = 0; rt < 8; ++rt)
            #pragma unroll
            for (int j = 0; j < 4; ++j)
                pa[rt][j] = d[rt][0][j]*wa0 + d[rt][1][j]*wa1;
        #pragma unroll
        for (int msk = 1; msk < 16; msk <<= 1) {
            #pragma unroll
            for (int rt = 0; rt < 8; ++rt)
                #pragma unroll
                for (int j = 0; j < 4; ++j)
                    pa[rt][j] += __shfl_xor(pa[rt][j], msk);
        }
        if (lr == 0) {
            #pragma unroll
            for (int rt = 0; rt < 8; ++rt)
                #pragma unroll
                for (int j = 0; j < 4; ++j)
                    sAP[w*128 + rt*16 + 4*lh + j] = pa[rt][j];
        }
    }
    __syncthreads();                                    // bar6 (sB2 reads also done)
    if (tid < EPB)
        sAttv[tid] = sigf(sAP[tid] + sAP[128+tid] + sAP[256+tid] + sAP[384+tid] + batt[0]);
    __syncthreads();                                    // bar7

    // ---- gated aggregate -> aggH/aggL ----------------------------------
    #pragma unroll
    for (int rt = 0; rt < 8; ++rt) {
        float s0 = 0.0f, s1 = 0.0f;
        #pragma unroll
        for (int j = 0; j < 4; ++j) {
            const float av = sAttv[rt*16 + 4*lh + j];
            s0 += d[rt][0][j]*av;
            s1 += d[rt][1][j]*av;
        }
        s0 += __shfl_xor(s0, 16);
        s1 += __shfl_xor(s1, 16);
        if ((lh & 1) == 0) {
            const int node = node0 + 2*rt + (lh >> 1);
            wragg(aggH, aggL, (size_t)node*HID + colB0, s0*0.2f);
            wragg(aggH, aggL, (size_t)node*HID + colB1, s1*0.2f);
        }
    }
}

// ---------------------------------------------------------------- node (MFMA, 32 nodes/block)
__global__ __launch_bounds__(256, 6) void node_k(
    float* __restrict__ hh, u16* __restrict__ hhH, u16* __restrict__ hhL,
    const u16* __restrict__ aggH, const u16* __restrict__ aggL,
    const u16* __restrict__ B1H, const u16* __restrict__ B1L,
    const u16* __restrict__ B2H, const u16* __restrict__ B2L,
    const float* __restrict__ bn1, const float* __restrict__ g2,
    const float* __restrict__ bt2, const float* __restrict__ bn2)
{
    __shared__ __align__(16) char smem[16896];
    float* sMid = (float*)smem;
    u16* sY = (u16*)smem;                // single-bf16 post-LN acts (8 KB)

    const int tid = threadIdx.x;
    const int node0 = blockIdx.x * 32;
    const int w = tid >> 6, lane = tid & 63, lr = lane & 15, lh = lane >> 4;
    const int colB0 = w*32 + lr, colB1 = colB0 + 16;

    const u16* a1h0 = hhH  + (size_t)(node0+lr)*HID + lh*8;
    const u16* a1l0 = hhL  + (size_t)(node0+lr)*HID + lh*8;
    const u16* a2h0 = aggH + (size_t)(node0+lr)*HID + lh*8;
    const u16* a2l0 = aggL + (size_t)(node0+lr)*HID + lh*8;
    const u16* c1H0 = B1H + (size_t)colB0*256 + lh*8;
    const u16* c1H1 = B1H + (size_t)colB1*256 + lh*8;
    const u16* c1L0 = B1L + (size_t)colB0*256 + lh*8;
    const u16* c1L1 = B1L + (size_t)colB1*256 + lh*8;

    f32x4 acc00={0,0,0,0}, acc01={0,0,0,0}, acc10={0,0,0,0}, acc11={0,0,0,0};
    {
        bfx8 wh0 = *(const bfx8*)c1H0, wh1 = *(const bfx8*)c1H1;
        bfx8 wl0 = *(const bfx8*)c1L0, wl1 = *(const bfx8*)c1L1;
        #pragma unroll
        for (int s = 0; s < 8; ++s) {
            bfx8 nh0 = wh0, nh1 = wh1, nl0 = wl0, nl1 = wl1;
            if (s < 7) {
                nh0 = *(const bfx8*)(c1H0 + 32*(s+1)); nh1 = *(const bfx8*)(c1H1 + 32*(s+1));
                nl0 = *(const bfx8*)(c1L0 + 32*(s+1)); nl1 = *(const bfx8*)(c1L1 + 32*(s+1));
            }
            bfx8 ah0, ah1, al0, al1;
            if (s < 4) {
                ah0 = *(const bfx8*)(a1h0 + 32*s);            ah1 = *(const bfx8*)(a1h0 + 16*HID + 32*s);
                al0 = *(const bfx8*)(a1l0 + 32*s);            al1 = *(const bfx8*)(a1l0 + 16*HID + 32*s);
            } else {
                ah0 = *(const bfx8*)(a2h0 + 32*(s-4));        ah1 = *(const bfx8*)(a2h0 + 16*HID + 32*(s-4));
                al0 = *(const bfx8*)(a2l0 + 32*(s-4));        al1 = *(const bfx8*)(a2l0 + 16*HID + 32*(s-4));
            }
            acc00 = mfma3(ah0, al0, wh0, wl0, acc00);
            acc01 = mfma3(ah0, al0, wh1, wl1, acc01);
            acc10 = mfma3(ah1, al1, wh0, wl0, acc10);
            acc11 = mfma3(ah1, al1, wh1, wl1, acc11);
            wh0 = nh0; wh1 = nh1; wl0 = nl0; wl1 = nl1;
        }
    }
    {
        const float b10 = bn1[colB0], b11 = bn1[colB1];
        #pragma unroll
        for (int j = 0; j < 4; ++j) {
            const int r0 = 4*lh + j;
            sMid[r0*MIDSTR + colB0]      = acc00[j] + b10;
            sMid[r0*MIDSTR + colB1]      = acc01[j] + b11;
            sMid[(16+r0)*MIDSTR + colB0] = acc10[j] + b10;
            sMid[(16+r0)*MIDSTR + colB1] = acc11[j] + b11;
        }
    }
    __syncthreads();

    float y[16];
    const int eLN = tid >> 3, c0 = (tid & 7)*16;
    {
        const float* mrow = &sMid[eLN*MIDSTR + c0];
        float4 v0 = *(const float4*)&mrow[0];
        float4 v1 = *(const float4*)&mrow[4];
        float4 v2 = *(const float4*)&mrow[8];
        float4 v3 = *(const float4*)&mrow[12];
        float s = v0.x+v0.y+v0.z+v0.w + v1.x+v1.y+v1.z+v1.w
                + v2.x+v2.y+v2.z+v2.w + v3.x+v3.y+v3.z+v3.w;
        float q = v0.x*v0.x+v0.y*v0.y+v0.z*v0.z+v0.w*v0.w
                + v1.x*v1.x+v1.y*v1.y+v1.z*v1.z+v1.w*v1.w
                + v2.x*v2.x+v2.y*v2.y+v2.z*v2.z+v2.w*v2.w
                + v3.x*v3.x+v3.y*v3.y+v3.z*v3.z+v3.w*v3.w;
        #pragma unroll
        for (int m = 4; m >= 1; m >>= 1) { s += __shfl_xor(s, m); q += __shfl_xor(q, m); }
        float mu  = s * (1.0f/HID);
        float var = q * (1.0f/HID) - mu*mu;
        float inv = rsqrtf(var + 1e-5f);
        const float4 G0 = *(const float4*)&g2[c0+0],  G1v = *(const float4*)&g2[c0+4];
        const float4 G2 = *(const float4*)&g2[c0+8],  G3 = *(const float4*)&g2[c0+12];
        const float4 B0 = *(const float4*)&bt2[c0+0], B1 = *(const float4*)&bt2[c0+4];
        const float4 B2 = *(const float4*)&bt2[c0+8], B3 = *(const float4*)&bt2[c0+12];
        y[0]=siluf(fmaf((v0.x-mu)*inv,G0.x,B0.x));  y[1]=siluf(fmaf((v0.y-mu)*inv,G0.y,B0.y));
        y[2]=siluf(fmaf((v0.z-mu)*inv,G0.z,B0.z));  y[3]=siluf(fmaf((v0.w-mu)*inv,G0.w,B0.w));
        y[4]=siluf(fmaf((v1.x-mu)*inv,G1v.x,B1.x)); y[5]=siluf(fmaf((v1.y-mu)*inv,G1v.y,B1.y));
        y[6]=siluf(fmaf((v1.z-mu)*inv,G1v.z,B1.z)); y[7]=siluf(fmaf((v1.w-mu)*inv,G1v.w,B1.w));
        y[8]=siluf(fmaf((v2.x-mu)*inv,G2.x,B2.x));  y[9]=siluf(fmaf((v2.y-mu)*inv,G2.y,B2.y));
        y[10]=siluf(fmaf((v2.z-mu)*inv,G2.z,B2.z)); y[11]=siluf(fmaf((v2.w-mu)*inv,G2.w,B2.w));
        y[12]=siluf(fmaf((v3.x-mu)*inv,G3.x,B3.x)); y[13]=siluf(fmaf((v3.y-mu)*inv,G3.y,B3.y));
        y[14]=siluf(fmaf((v3.z-mu)*inv,G3.z,B3.z)); y[15]=siluf(fmaf((v3.w-mu)*inv,G3.w,B3.w));
    }
    __syncthreads();
    {
        U8 ha, hb2;
        #pragma unroll
        for (int j = 0; j < 8; ++j) {
            ha.a[j]  = bf16_rn(y[j]);
            hb2.a[j] = bf16_rn(y[8+j]);
        }
        const int cA = (2*(tid & 7))     ^ (eLN & 15);
        const int cB = (2*(tid & 7) + 1) ^ (eLN & 15);
        *(bfx8*)&sY[eLN*128 + (cA << 3)] = ha.v;
        *(bfx8*)&sY[eLN*128 + (cB << 3)] = hb2.v;
    }
    __syncthreads();

    f32x4 d00={0,0,0,0}, d01={0,0,0,0}, d10={0,0,0,0}, d11={0,0,0,0};
    {
        const u16* c2H0 = B2H + (size_t)colB0*HID + lh*8;
        const u16* c2H1 = B2H + (size_t)colB1*HID + lh*8;
        const u16* c2L0 = B2L + (size_t)colB0*HID + lh*8;
        const u16* c2L1 = B2L + (size_t)colB1*HID + lh*8;
        bfx8 wh0 = *(const bfx8*)c2H0, wh1 = *(const bfx8*)c2H1;
        bfx8 wl0 = *(const bfx8*)c2L0, wl1 = *(const bfx8*)c2L1;
        #pragma unroll
        for (int s = 0; s < 4; ++s) {
            bfx8 nh0 = wh0, nh1 = wh1, nl0 = wl0, nl1 = wl1;
            if (s < 3) {
                nh0 = *(const bfx8*)(c2H0 + 32*(s+1)); nh1 = *(const bfx8*)(c2H1 + 32*(s+1));
                nl0 = *(const bfx8*)(c2L0 + 32*(s+1)); nl1 = *(const bfx8*)(c2L1 + 32*(s+1));
            }
            const int c4 = s*4 + lh;
            const int i0 = lr*128 + ((c4 ^ lr) << 3);
            const int i1 = (16+lr)*128 + ((c4 ^ lr) << 3);
            bfx8 ah0 = *(const bfx8*)&sY[i0], ah1 = *(const bfx8*)&sY[i1];
            d00 = mfma2(ah0, wh0, wl0, d00);
            d01 = mfma2(ah0, wh1, wl1, d01);
            d10 = mfma2(ah1, wh0, wl0, d10);
            d11 = mfma2(ah1, wh1, wl1, d11);
            wh0 = nh0; wh1 = nh1; wl0 = nl0; wl1 = nl1;
        }
    }

    {
        const float b20 = bn2[colB0], b21 = bn2[colB1];
        #pragma unroll
        for (int j = 0; j < 4; ++j) {
            const int r0 = 4*lh + j, r1 = 16 + 4*lh + j;
            const size_t i00 = (size_t)(node0+r0)*HID + colB0;
            const size_t i01 = (size_t)(node0+r0)*HID + colB1;
            const size_t i10 = (size_t)(node0+r1)*HID + colB0;
            const size_t i11 = (size_t)(node0+r1)*HID + colB1;
            float v00 = hh[i00] + d00[j] + b20;
            float v01 = hh[i01] + d01[j] + b21;
            float v10 = hh[i10] + d10[j] + b20;
            float v11 = hh[i11] + d11[j] + b21;
            hh[i00] = v00; hh[i01] = v01; hh[i10] = v10; hh[i11] = v11;
            u16 h00 = bf16_rn(v00); hhH[i00] = h00; hhL[i00] = bf16_rn(v00 - bf16_tof(h00));
            u16 h01 = bf16_rn(v01); hhH[i01] = h01; hhL[i01] = bf16_rn(v01 - bf16_tof(h01));
            u16 h10 = bf16_rn(v10); hhH[i10] = h10; hhL[i10] = bf16_rn(v10 - bf16_tof(h10));
            u16 h11 = bf16_rn(v11); hhH[i11] = h11; hhL[i11] = bf16_rn(v11 - bf16_tof(h11));
        }
    }
}

// ---------------------------------------------------------------- output head
__global__ __launch_bounds__(HID) void out_k(
    const float* __restrict__ hh, const float* __restrict__ Woe,
    const float* __restrict__ boe, const float* __restrict__ Wf,
    const float* __restrict__ bf, float* __restrict__ out)
{
    __shared__ float sH[HID];
    const int lig = blockIdx.x, tid = threadIdx.x;
    float s = 0.0f;
    const float* base = hh + (size_t)lig*KAT*HID + tid;
    #pragma unroll 8
    for (int a = 0; a < KAT; ++a) s += base[a*HID];
    sH[tid] = s * (1.0f/KAT);
    __syncthreads();

    float contrib = 0.0f;
    if (tid < OUTF) {
        float p = boe[tid];
        #pragma unroll 4
        for (int i = 0; i < HID; ++i)
            p = fmaf(sH[i], Woe[i*OUTF + tid], p);
        contrib = p * Wf[tid];
    }
    #pragma unroll
    for (int m = 1; m < 64; m <<= 1) contrib += __shfl_xor(contrib, m);
    if (tid == 0) out[lig] = contrib + bf[0];
}

// ---------------------------------------------------------------- launch
extern "C" void kernel_launch(void* const* d_in, const int* in_sizes, int n_in,
                              void* d_out, int out_size, void* d_ws, size_t ws_size,
                              hipStream_t stream)
{
    (void)in_sizes; (void)n_in; (void)out_size; (void)ws_size;
    const float* x    = (const float*)d_in[0];
    const float* h    = (const float*)d_in[1];
    const int*   t    = (const int*)d_in[2];
    const int*   edges= (const int*)d_in[3];
    const int*   tb   = (const int*)d_in[4];
    const float* temb = (const float*)d_in[8];
    const float* Win  = (const float*)d_in[9];
    const float* bin  = (const float*)d_in[10];
    const float* We1  = (const float*)d_in[11];
    const float* be1  = (const float*)d_in[12];
    const float* g1   = (const float*)d_in[13];
    const float* bt1  = (const float*)d_in[14];
    const float* We2  = (const float*)d_in[15];
    const float* be2  = (const float*)d_in[16];
    const float* Watt = (const float*)d_in[17];
    const float* batt = (const float*)d_in[18];
    const float* Wn1  = (const float*)d_in[19];
    const float* bn1  = (const float*)d_in[20];
    const float* g2   = (const float*)d_in[21];
    const float* bt2  = (const float*)d_in[22];
    const float* Wn2  = (const float*)d_in[23];
    const float* bn2  = (const float*)d_in[24];
    const float* Woe  = (const float*)d_in[25];
    const float* boe  = (const float*)d_in[26];
    const float* Wf   = (const float*)d_in[27];
    const float* bf   = (const float*)d_in[28];
    float* out = (float*)d_out;

    char* wsb = (char*)d_ws;
    float* hh  = (float*)(wsb);                        // 16 MB
    u16* hhH   = (u16*)(wsb + ((size_t)16<<20));       // 8 MB
    u16* hhL   = (u16*)(wsb + ((size_t)24<<20));       // 8 MB
    u16* aggH  = (u16*)(wsb + ((size_t)32<<20));       // 8 MB
    u16* aggL  = (u16*)(wsb + ((size_t)40<<20));       // 8 MB
    u16* tembH = (u16*)(wsb + ((size_t)48<<20));
    u16* tembL = tembH + PREP_TEMB;
    u16* W1TH  = tembL + PREP_TEMB;
    u16* W1TL  = W1TH + PREP_W1;
    u16* W2TH  = W1TL + PREP_W1;
    u16* W2TL  = W2TH + PREP_W2;
    u16* WN1TH = W2TL + PREP_W2;
    u16* WN1TL = WN1TH + PREP_WN1;
    u16* WN2TH = WN1TL + PREP_WN1;
    u16* WN2TL = WN2TH + PREP_WN2;

    prep_k<<<(PREP_TOT + 255)/256, 256, 0, stream>>>(
        temb, We1, We2, Wn1, Wn2,
        tembH, tembL, W1TH, W1TL, W2TH, W2TL, WN1TH, WN1TL, WN2TH, WN2TL);

    embed_k<<<NNODES/8, 256, 0, stream>>>(h, t, temb, Win, bin, hh, hhH, hhL);

    for (int l = 0; l < 4; ++l) {
        edge_k<<<NNODES/NPB, 256, 0, stream>>>(
            hhH, hhL, x, edges + NEDGES, tb, tembH, tembL,
            W1TH + (size_t)l*128*K1, W1TL + (size_t)l*128*K1,
            W2TH + (size_t)l*128*128, W2TL + (size_t)l*128*128,
            be1 + l*HID, g1 + l*HID, bt1 + l*HID, be2 + l*HID,
            Watt + l*HID, batt + l, aggH, aggL);
        node_k<<<NNODES/32, 256, 0, stream>>>(
            hh, hhH, hhL, aggH, aggL,
            WN1TH + (size_t)l*128*256, WN1TL + (size_t)l*128*256,
            WN2TH + (size_t)l*128*128, WN2TL + (size_t)l*128*128,
            bn1 + l*HID, g2 + l*HID, bt2 + l*HID, bn2 + l*HID);
    }
    out_k<<<NLIG, HID, 0, stream>>>(hh, Woe, boe, Wf, bf, out);
}

// Round 11
// 665.077 us; speedup vs baseline: 1.4179x; 1.0562x over previous
//
#include <hip/hip_runtime.h>
#include <math.h>

#define NNODES 32768
#define NLIG   1024
#define KAT    32
#define KNN    8
#define NEDGES (NNODES*KNN)
#define HID    128
#define TF     16
#define NG     20
#define OUTF   64

#define NPB    16           // nodes per edge-block
#define EPB    128          // edges per edge-block
#define K1     320          // padded GEMM1 K (292 -> 320)
#define MIDSTR 132          // node_k sMid row stride (floats)

typedef unsigned short u16;
typedef __attribute__((__ext_vector_type__(8))) short bfx8;
typedef __attribute__((__ext_vector_type__(4))) float f32x4;

union U8 { u16 a[8]; bfx8 v; };

// Gaussian smearing constants: og[g] = 5^(g/19)-1, coeff = -0.5/diff^2
__device__ const float GS_OG[20] = {
    0.0f, 0.0883984f, 0.1845966f, 0.2893285f, 0.4033028f,
    0.5273539f, 0.6623701f, 0.8093209f, 0.9692606f, 1.1433389f,
    1.3328075f, 1.5390240f, 1.7634662f, 2.0077560f, 2.2736369f,
    2.5630207f, 2.8779861f, 3.2207938f, 3.5939058f, 4.0f };
__device__ const float GS_CF[20] = {
    -63.9853f, -63.9853f, -54.0303f, -45.5840f, -38.4908f,
    -32.4913f, -27.4283f, -23.1540f, -19.5460f, -16.4999f,
    -13.9282f, -11.7577f, -9.92569f, -8.37837f, -7.07287f,
    -5.97065f, -5.04016f, -4.25470f, -3.59163f, -3.03191f };

__device__ __forceinline__ float siluf(float v) {
    return __fdividef(v, 1.0f + __expf(-v));
}
__device__ __forceinline__ float sigf(float v) {
    return __fdividef(1.0f, 1.0f + __expf(-v));
}
__device__ __forceinline__ u16 bf16_rn(float f) {
    union { float f; unsigned u; } v; v.f = f;
    unsigned r = v.u + 0x7FFFu + ((v.u >> 16) & 1u);
    return (u16)(r >> 16);
}
__device__ __forceinline__ float bf16_tof(u16 u) {
    union { unsigned u; float f; } v; v.u = ((unsigned)u) << 16;
    return v.f;
}
__device__ __forceinline__ f32x4 mfma3(bfx8 ah, bfx8 al, bfx8 wh, bfx8 wl, f32x4 c) {
    c = __builtin_amdgcn_mfma_f32_16x16x32_bf16(ah, wh, c, 0, 0, 0);
    c = __builtin_amdgcn_mfma_f32_16x16x32_bf16(ah, wl, c, 0, 0, 0);
    c = __builtin_amdgcn_mfma_f32_16x16x32_bf16(al, wh, c, 0, 0, 0);
    return c;
}
__device__ __forceinline__ f32x4 mfma2(bfx8 ah, bfx8 wh, bfx8 wl, f32x4 c) {
    c = __builtin_amdgcn_mfma_f32_16x16x32_bf16(ah, wh, c, 0, 0, 0);
    c = __builtin_amdgcn_mfma_f32_16x16x32_bf16(ah, wl, c, 0, 0, 0);
    return c;
}
__device__ __forceinline__ void wragg(u16* __restrict__ H, u16* __restrict__ L,
                                      size_t i, float v) {
    u16 hb = bf16_rn(v);
    H[i] = hb; L[i] = bf16_rn(v - bf16_tof(hb));
}

// ---------------------------------------------------------------- prep
#define PREP_TEMB 16000
#define PREP_W1   (4*128*K1)       // 163840
#define PREP_W2   (4*128*128)      // 65536
#define PREP_WN1  (4*128*256)      // 131072
#define PREP_WN2  (4*128*128)      // 65536
#define PREP_TOT  (PREP_TEMB+PREP_W1+PREP_W2+PREP_WN1+PREP_WN2)

__global__ __launch_bounds__(256) void prep_k(
    const float* __restrict__ temb, const float* __restrict__ We1,
    const float* __restrict__ We2,  const float* __restrict__ Wn1,
    const float* __restrict__ Wn2,
    u16* __restrict__ tembH, u16* __restrict__ tembL,
    u16* __restrict__ W1TH, u16* __restrict__ W1TL,
    u16* __restrict__ W2TH, u16* __restrict__ W2TL,
    u16* __restrict__ WN1TH, u16* __restrict__ WN1TL,
    u16* __restrict__ WN2TH, u16* __restrict__ WN2TL)
{
    int i = blockIdx.x*256 + threadIdx.x;
    if (i >= PREP_TOT) return;
    float v; u16 *dh, *dl; int di;
    if (i < PREP_TEMB) {
        v = temb[i]; dh = tembH; dl = tembL; di = i;
    } else if (i < PREP_TEMB + PREP_W1) {
        int j = i - PREP_TEMB; di = j; dh = W1TH; dl = W1TL;
        int l = j / (128*K1); int r = j - l*(128*K1);
        int col = r / K1, k = r - col*K1;
        v = (k < 292) ? We1[(size_t)l*292*128 + (size_t)k*128 + col] : 0.0f;
    } else if (i < PREP_TEMB + PREP_W1 + PREP_W2) {
        int j = i - PREP_TEMB - PREP_W1; di = j; dh = W2TH; dl = W2TL;
        int l = j >> 14; int r = j & 16383;
        int col = r >> 7, k = r & 127;
        v = We2[(size_t)l*16384 + (size_t)k*128 + col];
    } else if (i < PREP_TEMB + PREP_W1 + PREP_W2 + PREP_WN1) {
        int j = i - PREP_TEMB - PREP_W1 - PREP_W2; di = j; dh = WN1TH; dl = WN1TL;
        int l = j >> 15; int r = j & 32767;
        int col = r >> 8, k = r & 255;
        v = Wn1[(size_t)l*32768 + (size_t)k*128 + col];
    } else {
        int j = i - PREP_TEMB - PREP_W1 - PREP_W2 - PREP_WN1; di = j; dh = WN2TH; dl = WN2TL;
        int l = j >> 14; int r = j & 16383;
        int col = r >> 7, k = r & 127;
        v = Wn2[(size_t)l*16384 + (size_t)k*128 + col];
    }
    u16 hb = bf16_rn(v);
    dh[di] = hb;
    dl[di] = bf16_rn(v - bf16_tof(hb));
}

// ---------------------------------------------------------------- embed (8 nodes/block)
__global__ __launch_bounds__(256) void embed_k(
    const float* __restrict__ h, const int* __restrict__ t,
    const float* __restrict__ temb, const float* __restrict__ Win,
    const float* __restrict__ bin, float* __restrict__ hh,
    u16* __restrict__ hhH, u16* __restrict__ hhL)
{
    __shared__ float sIn[8][32];
    const int tid = threadIdx.x;
    {
        const int n = tid >> 5, i = tid & 31;
        const int node = blockIdx.x*8 + n;
        sIn[n][i] = (i < TF) ? h[node*TF + i] : temb[t[node]*TF + (i-TF)];
    }
    __syncthreads();
    const int sub = tid >> 7, col = tid & 127;
    float acc[4];
    const float b = bin[col];
    acc[0]=acc[1]=acc[2]=acc[3]=b;
    #pragma unroll 8
    for (int i = 0; i < 32; ++i) {
        const float wv = Win[i*HID + col];
        acc[0] = fmaf(sIn[sub][i],   wv, acc[0]);
        acc[1] = fmaf(sIn[2+sub][i], wv, acc[1]);
        acc[2] = fmaf(sIn[4+sub][i], wv, acc[2]);
        acc[3] = fmaf(sIn[6+sub][i], wv, acc[3]);
    }
    #pragma unroll
    for (int nn = 0; nn < 4; ++nn) {
        const size_t idx = (size_t)(blockIdx.x*8 + nn*2 + sub)*HID + col;
        hh[idx] = acc[nn];
        u16 hb = bf16_rn(acc[nn]);
        hhH[idx] = hb; hhL[idx] = bf16_rn(acc[nn] - bf16_tof(hb));
    }
}

// ---------------------------------------------------------------- edge
// M=128 (16 nodes, 128 edges / block). In-reg LN, single-bf16 post-LN acts,
// single-pass 2-product GEMM2. LDS 38.4 KB.
// __launch_bounds__(256,3): combined VGPR+AGPR cap ~170 — the NPB=16 working
// set (64 acc AGPRs + ~70 VGPRs) needs >128, so (256,4) spilled (round 10:
// WRITE_SIZE 16->118 MB scratch). 3 blocks/CU spill-free > 4 blocks spilling.
__global__ __launch_bounds__(256, 3) void edge_k(
    const u16* __restrict__ hhH, const u16* __restrict__ hhL,
    const float* __restrict__ x,
    const int* __restrict__ ecol, const int* __restrict__ tbond,
    const u16* __restrict__ tembH, const u16* __restrict__ tembL,
    const u16* __restrict__ W1TH, const u16* __restrict__ W1TL,
    const u16* __restrict__ W2TH, const u16* __restrict__ W2TL,
    const float* __restrict__ be1, const float* __restrict__ g1,
    const float* __restrict__ bt1, const float* __restrict__ be2,
    const float* __restrict__ Watt, const float* __restrict__ batt,
    u16* __restrict__ aggH, u16* __restrict__ aggL)
{
    // LDS (38400 B):
    //  [0,16384)      tblH(8K)+tblL(8K)      | after LN: sB2 (128x128 u16 = 32K)
    //  [16384,32768)  tailB (128 x 64 u16)   | (sB2 tail half)
    //  [32768,36864)  sStats (128 x 4 x f32x2) | after GEMM2: sAP (512 f32)
    //  [36864,37888)  sMuInv (128 x f32x2)
    //  [37888,38400)  sAttv (128 f32)
    __shared__ __align__(16) char smem[38400];
    u16*   tblH  = (u16*)(smem);
    u16*   tblL  = (u16*)(smem + 8192);
    u16*   tailB = (u16*)(smem + 16384);
    float* sStats= (float*)(smem + 32768);
    float* sMuInv= (float*)(smem + 36864);
    u16*   sB2   = (u16*)(smem);
    float* sAP   = (float*)(smem + 32768);
    float* sAttv = (float*)(smem + 37888);

    const int tid = threadIdx.x;
    const int node0 = blockIdx.x * NPB;
    const int ligBase = node0 & ~31;
    const int aBase   = node0 & 31;      // 0 or 16
    const int w = tid >> 6, lane = tid & 63, lr = lane & 15, lh = lane >> 4;
    const int colB0 = w*32 + lr, colB1 = colB0 + 16;

    // ---- per-lane col atom ids, packed 8x8b into 2 u32 -----------------
    unsigned aColPk0 = 0, aColPk1 = 0;
    #pragma unroll
    for (int rt = 0; rt < 4; ++rt)
        aColPk0 |= (unsigned)(ecol[node0*KNN + rt*16 + lr] & 31) << (rt*8);
    #pragma unroll
    for (int rt = 0; rt < 4; ++rt)
        aColPk1 |= (unsigned)(ecol[node0*KNN + (4+rt)*16 + lr] & 31) << (rt*8);

    // ---- GEMM1 weight pointers + first fragments -----------------------
    const u16* bH0 = W1TH + (size_t)colB0*K1 + lh*8;
    const u16* bH1 = W1TH + (size_t)colB1*K1 + lh*8;
    const u16* bL0 = W1TL + (size_t)colB0*K1 + lh*8;
    const u16* bL1 = W1TL + (size_t)colB1*K1 + lh*8;
    bfx8 wh0 = *(const bfx8*)bH0, wh1 = *(const bfx8*)bH1;
    bfx8 wl0 = *(const bfx8*)bL0, wl1 = *(const bfx8*)bL1;

    // ---- stage ligand hh table (32 atoms x 16 chunks, hi/lo) -----------
    for (int idx = tid; idx < 1024; idx += 256) {
        const int hl = idx >> 9, rem = idx & 511;
        const int a = rem >> 4, c4 = rem & 15;
        const bfx8 v = *(const bfx8*)((hl ? hhL : hhH) + (size_t)(ligBase + a)*HID + c4*8);
        u16* dst = hl ? tblL : tblH;
        *(bfx8*)&dst[a*128 + ((c4 ^ (a & 15)) << 3)] = v;
    }

    // ---- tail (single bf16) [128 rows][8 chunks]: temb(2)|smear(3)|0(3)
    for (int pe = tid; pe < 1024; pe += 256) {
        const int row = pe & 127, part = pe >> 7;
        U8 vh;
        if (part < 2) {
            const int r = node0 + (row >> 3);
            const int c = ecol[node0*KNN + row];
            int sbi = r*(KAT-1) + c - (r/KAT)*KAT - (r < c ? 1 : 0);
            const int tb = tbond[sbi];
            #pragma unroll
            for (int j = 0; j < 8; ++j)
                vh.a[j] = tembH[tb*TF + part*8 + j];
        } else if (part < 5) {
            const int r = node0 + (row >> 3);
            const int c = ecol[node0*KNN + row];
            float dx = x[3*r]-x[3*c], dy = x[3*r+1]-x[3*c+1], dz = x[3*r+2]-x[3*c+2];
            float dist = fminf(sqrtf(dx*dx+dy*dy+dz*dz), 4.0f);
            #pragma unroll
            for (int j = 0; j < 8; ++j) {
                int g = (part-2)*8 + j;
                float v = 0.0f;
                if (g < NG) {
                    float dd = dist - GS_OG[g];
                    v = __expf(GS_CF[g]*dd*dd);
                }
                vh.a[j] = bf16_rn(v);
            }
        } else {
            #pragma unroll
            for (int j = 0; j < 8; ++j) vh.a[j] = 0;
        }
        *(bfx8*)&tailB[row*64 + ((part ^ (row & 7)) << 3)] = vh.v;
    }
    __syncthreads();                                    // bar1

    // ---- GEMM1: [128 x 320] @ [320 x 128], 1-deep W prefetch -----------
    f32x4 acc[8][2];
    #pragma unroll
    for (int rt = 0; rt < 8; ++rt) { acc[rt][0] = (f32x4){0,0,0,0}; acc[rt][1] = (f32x4){0,0,0,0}; }
    {
        #pragma unroll
        for (int s = 0; s < 10; ++s) {
            bfx8 nh0 = wh0, nh1 = wh1, nl0 = wl0, nl1 = wl1;
            if (s < 9) {
                nh0 = *(const bfx8*)(bH0 + 32*(s+1)); nh1 = *(const bfx8*)(bH1 + 32*(s+1));
                nl0 = *(const bfx8*)(bL0 + 32*(s+1)); nl1 = *(const bfx8*)(bL1 + 32*(s+1));
            }
            if (s < 4) {
                #pragma unroll
                for (int rt = 0; rt < 8; ++rt) {
                    const int aR = aBase + 2*rt + (lr >> 3);
                    const int c4 = s*4 + lh;
                    const int ad = aR*128 + ((c4 ^ (aR & 15)) << 3);
                    const bfx8 ah = *(const bfx8*)&tblH[ad];
                    const bfx8 al = *(const bfx8*)&tblL[ad];
                    acc[rt][0] = mfma3(ah, al, wh0, wl0, acc[rt][0]);
                    acc[rt][1] = mfma3(ah, al, wh1, wl1, acc[rt][1]);
                }
            } else if (s < 8) {
                #pragma unroll
                for (int rt = 0; rt < 8; ++rt) {
                    const int aC = (int)((rt < 4 ? (aColPk0 >> (rt*8))
                                                 : (aColPk1 >> ((rt-4)*8))) & 31u);
                    const int c4 = (s-4)*4 + lh;
                    const int ad = aC*128 + ((c4 ^ (aC & 15)) << 3);
                    const bfx8 ah = *(const bfx8*)&tblH[ad];
                    const bfx8 al = *(const bfx8*)&tblL[ad];
                    acc[rt][0] = mfma3(ah, al, wh0, wl0, acc[rt][0]);
                    acc[rt][1] = mfma3(ah, al, wh1, wl1, acc[rt][1]);
                }
            } else {
                #pragma unroll
                for (int rt = 0; rt < 8; ++rt) {
                    const int r = rt*16 + lr;
                    const int c = (s-8)*4 + lh;
                    const int ad = r*64 + ((c ^ (r & 7)) << 3);
                    const bfx8 ah = *(const bfx8*)&tailB[ad];
                    acc[rt][0] = mfma2(ah, wh0, wl0, acc[rt][0]);
                    acc[rt][1] = mfma2(ah, wh1, wl1, acc[rt][1]);
                }
            }
            wh0 = nh0; wh1 = nh1; wl0 = nl0; wl1 = nl1;
        }
    }

    // ---- bias + in-register LN partials --------------------------------
    {
        const float b10 = be1[colB0], b11 = be1[colB1];
        #pragma unroll
        for (int rt = 0; rt < 8; ++rt)
            #pragma unroll
            for (int j = 0; j < 4; ++j) { acc[rt][0][j] += b10; acc[rt][1][j] += b11; }
    }
    {
        #pragma unroll
        for (int rt = 0; rt < 8; ++rt) {
            float sv[4], qv[4];
            #pragma unroll
            for (int j = 0; j < 4; ++j) {
                const float a0 = acc[rt][0][j], a1 = acc[rt][1][j];
                sv[j] = a0 + a1; qv[j] = a0*a0 + a1*a1;
            }
            #pragma unroll
            for (int msk = 1; msk < 16; msk <<= 1) {
                #pragma unroll
                for (int j = 0; j < 4; ++j) {
                    sv[j] += __shfl_xor(sv[j], msk);
                    qv[j] += __shfl_xor(qv[j], msk);
                }
            }
            if (lr == 0) {
                #pragma unroll
                for (int j = 0; j < 4; ++j) {
                    const int row = rt*16 + 4*lh + j;
                    sStats[(row*4 + w)*2 + 0] = sv[j];
                    sStats[(row*4 + w)*2 + 1] = qv[j];
                }
            }
        }
    }
    __syncthreads();                                    // bar2

    if (tid < EPB) {
        const float4 a = *(const float4*)&sStats[tid*8];
        const float4 b = *(const float4*)&sStats[tid*8 + 4];
        const float st = a.x + a.z + b.x + b.z;
        const float qt = a.y + a.w + b.y + b.w;
        const float mu  = st * (1.0f/HID);
        const float var = qt * (1.0f/HID) - mu*mu;
        sMuInv[tid*2 + 0] = mu;
        sMuInv[tid*2 + 1] = rsqrtf(var + 1e-5f);
    }
    __syncthreads();                                    // bar3

    // ---- GEMM2 weight pointers + first fragments -----------------------
    const u16* c2H0 = W2TH + (size_t)colB0*HID + lh*8;
    const u16* c2H1 = W2TH + (size_t)colB1*HID + lh*8;
    const u16* c2L0 = W2TL + (size_t)colB0*HID + lh*8;
    const u16* c2L1 = W2TL + (size_t)colB1*HID + lh*8;
    bfx8 g2h0 = *(const bfx8*)c2H0, g2h1 = *(const bfx8*)c2H1;
    bfx8 g2l0 = *(const bfx8*)c2L0, g2l1 = *(const bfx8*)c2L1;

    // ---- normalize + SiLU in regs, write single-bf16 acts to sB2 -------
    {
        const float G0 = g1[colB0], G1s = g1[colB1];
        const float B0 = bt1[colB0], B1s = bt1[colB1];
        #pragma unroll
        for (int rt = 0; rt < 8; ++rt) {
            const int r0 = rt*16 + 4*lh;
            const float4 mi0 = *(const float4*)&sMuInv[r0*2];      // mu0,inv0,mu1,inv1
            const float4 mi1 = *(const float4*)&sMuInv[r0*2 + 4];  // mu2,inv2,mu3,inv3
            acc[rt][0][0] = siluf(fmaf((acc[rt][0][0]-mi0.x)*mi0.y, G0, B0));
            acc[rt][1][0] = siluf(fmaf((acc[rt][1][0]-mi0.x)*mi0.y, G1s, B1s));
            acc[rt][0][1] = siluf(fmaf((acc[rt][0][1]-mi0.z)*mi0.w, G0, B0));
            acc[rt][1][1] = siluf(fmaf((acc[rt][1][1]-mi0.z)*mi0.w, G1s, B1s));
            acc[rt][0][2] = siluf(fmaf((acc[rt][0][2]-mi1.x)*mi1.y, G0, B0));
            acc[rt][1][2] = siluf(fmaf((acc[rt][1][2]-mi1.x)*mi1.y, G1s, B1s));
            acc[rt][0][3] = siluf(fmaf((acc[rt][0][3]-mi1.z)*mi1.w, G0, B0));
            acc[rt][1][3] = siluf(fmaf((acc[rt][1][3]-mi1.z)*mi1.w, G1s, B1s));
        }
    }
    __syncthreads();                                    // bar4 (tbl/tail reads done; sB2 aliases them)
    {
        #pragma unroll
        for (int rt = 0; rt < 8; ++rt) {
            #pragma unroll
            for (int hcol = 0; hcol < 2; ++hcol) {
                const int col = hcol ? colB1 : colB0;
                const int gch = col >> 3, cw = col & 7;
                #pragma unroll
                for (int j = 0; j < 4; ++j) {
                    const int row = rt*16 + 4*lh + j;
                    sB2[row*128 + ((gch ^ (row & 15)) << 3) + cw] =
                        bf16_rn(acc[rt][hcol][j]);
                }
            }
        }
    }
    __syncthreads();                                    // bar5

    // ---- GEMM2: [128 x 128] @ [128 x 128], single-bf16 A, 2-product ----
    f32x4 d[8][2];
    #pragma unroll
    for (int rt = 0; rt < 8; ++rt) { d[rt][0] = (f32x4){0,0,0,0}; d[rt][1] = (f32x4){0,0,0,0}; }
    {
        #pragma unroll
        for (int s = 0; s < 4; ++s) {
            bfx8 nh0 = g2h0, nh1 = g2h1, nl0 = g2l0, nl1 = g2l1;
            if (s < 3) {
                nh0 = *(const bfx8*)(c2H0 + 32*(s+1)); nh1 = *(const bfx8*)(c2H1 + 32*(s+1));
                nl0 = *(const bfx8*)(c2L0 + 32*(s+1)); nl1 = *(const bfx8*)(c2L1 + 32*(s+1));
            }
            #pragma unroll
            for (int rt = 0; rt < 8; ++rt) {
                const int rowL = rt*16 + lr;
                const int c4 = s*4 + lh;
                const bfx8 ah = *(const bfx8*)&sB2[rowL*128 + ((c4 ^ (rowL & 15)) << 3)];
                d[rt][0] = mfma2(ah, g2h0, g2l0, d[rt][0]);
                d[rt][1] = mfma2(ah, g2h1, g2l1, d[rt][1]);
            }
            g2h0 = nh0; g2h1 = nh1; g2l0 = nl0; g2l1 = nl1;
        }
    }

    // ---- SiLU in place (d becomes m) + attention gate ------------------
    {
        const float b20 = be2[colB0], b21 = be2[colB1];
        #pragma unroll
        for (int rt = 0; rt < 8; ++rt) {
            #pragma unroll
            for (int j = 0; j < 4; ++j) {
                d[rt][0][j] = siluf(d[rt][0][j] + b20);
                d[rt][1][j] = siluf(d[rt][1][j] + b21);
            }
        }
    }
    {
        const float wa0 = Watt[colB0], wa1 = Watt[colB1];
        float pa[8][4];
        #pragma unroll
        for (int rt = 0; rt < 8; ++rt)
            #pragma unroll
            for (int j = 0; j < 4; ++j)
                pa[rt][j] = d[rt][0][j]*wa0 + d[rt][1][j]*wa1;
        #pragma unroll
        for (int msk = 1; msk < 16; msk <<= 1) {
            #pragma unroll
            for (int rt = 0; rt < 8; ++rt)
                #pragma unroll
                for (int j = 0; j < 4; ++j)
                    pa[rt][j] += __shfl_xor(pa[rt][j], msk);
        }
        if (lr == 0) {
            #pragma unroll
            for (int rt = 0; rt < 8; ++rt)
                #pragma unroll
                for (int j = 0; j < 4; ++j)
                    sAP[w*128 + rt*16 + 4*lh + j] = pa[rt][j];
        }
    }
    __syncthreads();                                    // bar6 (sB2 reads also done)
    if (tid < EPB)
        sAttv[tid] = sigf(sAP[tid] + sAP[128+tid] + sAP[256+tid] + sAP[384+tid] + batt[0]);
    __syncthreads();                                    // bar7

    // ---- gated aggregate -> aggH/aggL ----------------------------------
    #pragma unroll
    for (int rt = 0; rt < 8; ++rt) {
        float s0 = 0.0f, s1 = 0.0f;
        #pragma unroll
        for (int j = 0; j < 4; ++j) {
            const float av = sAttv[rt*16 + 4*lh + j];
            s0 += d[rt][0][j]*av;
            s1 += d[rt][1][j]*av;
        }
        s0 += __shfl_xor(s0, 16);
        s1 += __shfl_xor(s1, 16);
        if ((lh & 1) == 0) {
            const int node = node0 + 2*rt + (lh >> 1);
            wragg(aggH, aggL, (size_t)node*HID + colB0, s0*0.2f);
            wragg(aggH, aggL, (size_t)node*HID + colB1, s1*0.2f);
        }
    }
}

// ---------------------------------------------------------------- node (MFMA, 32 nodes/block)
__global__ __launch_bounds__(256, 6) void node_k(
    float* __restrict__ hh, u16* __restrict__ hhH, u16* __restrict__ hhL,
    const u16* __restrict__ aggH, const u16* __restrict__ aggL,
    const u16* __restrict__ B1H, const u16* __restrict__ B1L,
    const u16* __restrict__ B2H, const u16* __restrict__ B2L,
    const float* __restrict__ bn1, const float* __restrict__ g2,
    const float* __restrict__ bt2, const float* __restrict__ bn2)
{
    __shared__ __align__(16) char smem[16896];
    float* sMid = (float*)smem;
    u16* sY = (u16*)smem;                // single-bf16 post-LN acts (8 KB)

    const int tid = threadIdx.x;
    const int node0 = blockIdx.x * 32;
    const int w = tid >> 6, lane = tid & 63, lr = lane & 15, lh = lane >> 4;
    const int colB0 = w*32 + lr, colB1 = colB0 + 16;

    const u16* a1h0 = hhH  + (size_t)(node0+lr)*HID + lh*8;
    const u16* a1l0 = hhL  + (size_t)(node0+lr)*HID + lh*8;
    const u16* a2h0 = aggH + (size_t)(node0+lr)*HID + lh*8;
    const u16* a2l0 = aggL + (size_t)(node0+lr)*HID + lh*8;
    const u16* c1H0 = B1H + (size_t)colB0*256 + lh*8;
    const u16* c1H1 = B1H + (size_t)colB1*256 + lh*8;
    const u16* c1L0 = B1L + (size_t)colB0*256 + lh*8;
    const u16* c1L1 = B1L + (size_t)colB1*256 + lh*8;

    f32x4 acc00={0,0,0,0}, acc01={0,0,0,0}, acc10={0,0,0,0}, acc11={0,0,0,0};
    {
        bfx8 wh0 = *(const bfx8*)c1H0, wh1 = *(const bfx8*)c1H1;
        bfx8 wl0 = *(const bfx8*)c1L0, wl1 = *(const bfx8*)c1L1;
        #pragma unroll
        for (int s = 0; s < 8; ++s) {
            bfx8 nh0 = wh0, nh1 = wh1, nl0 = wl0, nl1 = wl1;
            if (s < 7) {
                nh0 = *(const bfx8*)(c1H0 + 32*(s+1)); nh1 = *(const bfx8*)(c1H1 + 32*(s+1));
                nl0 = *(const bfx8*)(c1L0 + 32*(s+1)); nl1 = *(const bfx8*)(c1L1 + 32*(s+1));
            }
            bfx8 ah0, ah1, al0, al1;
            if (s < 4) {
                ah0 = *(const bfx8*)(a1h0 + 32*s);            ah1 = *(const bfx8*)(a1h0 + 16*HID + 32*s);
                al0 = *(const bfx8*)(a1l0 + 32*s);            al1 = *(const bfx8*)(a1l0 + 16*HID + 32*s);
            } else {
                ah0 = *(const bfx8*)(a2h0 + 32*(s-4));        ah1 = *(const bfx8*)(a2h0 + 16*HID + 32*(s-4));
                al0 = *(const bfx8*)(a2l0 + 32*(s-4));        al1 = *(const bfx8*)(a2l0 + 16*HID + 32*(s-4));
            }
            acc00 = mfma3(ah0, al0, wh0, wl0, acc00);
            acc01 = mfma3(ah0, al0, wh1, wl1, acc01);
            acc10 = mfma3(ah1, al1, wh0, wl0, acc10);
            acc11 = mfma3(ah1, al1, wh1, wl1, acc11);
            wh0 = nh0; wh1 = nh1; wl0 = nl0; wl1 = nl1;
        }
    }
    {
        const float b10 = bn1[colB0], b11 = bn1[colB1];
        #pragma unroll
        for (int j = 0; j < 4; ++j) {
            const int r0 = 4*lh + j;
            sMid[r0*MIDSTR + colB0]      = acc00[j] + b10;
            sMid[r0*MIDSTR + colB1]      = acc01[j] + b11;
            sMid[(16+r0)*MIDSTR + colB0] = acc10[j] + b10;
            sMid[(16+r0)*MIDSTR + colB1] = acc11[j] + b11;
        }
    }
    __syncthreads();

    float y[16];
    const int eLN = tid >> 3, c0 = (tid & 7)*16;
    {
        const float* mrow = &sMid[eLN*MIDSTR + c0];
        float4 v0 = *(const float4*)&mrow[0];
        float4 v1 = *(const float4*)&mrow[4];
        float4 v2 = *(const float4*)&mrow[8];
        float4 v3 = *(const float4*)&mrow[12];
        float s = v0.x+v0.y+v0.z+v0.w + v1.x+v1.y+v1.z+v1.w
                + v2.x+v2.y+v2.z+v2.w + v3.x+v3.y+v3.z+v3.w;
        float q = v0.x*v0.x+v0.y*v0.y+v0.z*v0.z+v0.w*v0.w
                + v1.x*v1.x+v1.y*v1.y+v1.z*v1.z+v1.w*v1.w
                + v2.x*v2.x+v2.y*v2.y+v2.z*v2.z+v2.w*v2.w
                + v3.x*v3.x+v3.y*v3.y+v3.z*v3.z+v3.w*v3.w;
        #pragma unroll
        for (int m = 4; m >= 1; m >>= 1) { s += __shfl_xor(s, m); q += __shfl_xor(q, m); }
        float mu  = s * (1.0f/HID);
        float var = q * (1.0f/HID) - mu*mu;
        float inv = rsqrtf(var + 1e-5f);
        const float4 G0 = *(const float4*)&g2[c0+0],  G1v = *(const float4*)&g2[c0+4];
        const float4 G2 = *(const float4*)&g2[c0+8],  G3 = *(const float4*)&g2[c0+12];
        const float4 B0 = *(const float4*)&bt2[c0+0], B1 = *(const float4*)&bt2[c0+4];
        const float4 B2 = *(const float4*)&bt2[c0+8], B3 = *(const float4*)&bt2[c0+12];
        y[0]=siluf(fmaf((v0.x-mu)*inv,G0.x,B0.x));  y[1]=siluf(fmaf((v0.y-mu)*inv,G0.y,B0.y));
        y[2]=siluf(fmaf((v0.z-mu)*inv,G0.z,B0.z));  y[3]=siluf(fmaf((v0.w-mu)*inv,G0.w,B0.w));
        y[4]=siluf(fmaf((v1.x-mu)*inv,G1v.x,B1.x)); y[5]=siluf(fmaf((v1.y-mu)*inv,G1v.y,B1.y));
        y[6]=siluf(fmaf((v1.z-mu)*inv,G1v.z,B1.z)); y[7]=siluf(fmaf((v1.w-mu)*inv,G1v.w,B1.w));
        y[8]=siluf(fmaf((v2.x-mu)*inv,G2.x,B2.x));  y[9]=siluf(fmaf((v2.y-mu)*inv,G2.y,B2.y));
        y[10]=siluf(fmaf((v2.z-mu)*inv,G2.z,B2.z)); y[11]=siluf(fmaf((v2.w-mu)*inv,G2.w,B2.w));
        y[12]=siluf(fmaf((v3.x-mu)*inv,G3.x,B3.x)); y[13]=siluf(fmaf((v3.y-mu)*inv,G3.y,B3.y));
        y[14]=siluf(fmaf((v3.z-mu)*inv,G3.z,B3.z)); y[15]=siluf(fmaf((v3.w-mu)*inv,G3.w,B3.w));
    }
    __syncthreads();
    {
        U8 ha, hb2;
        #pragma unroll
        for (int j = 0; j < 8; ++j) {
            ha.a[j]  = bf16_rn(y[j]);
            hb2.a[j] = bf16_rn(y[8+j]);
        }
        const int cA = (2*(tid & 7))     ^ (eLN & 15);
        const int cB = (2*(tid & 7) + 1) ^ (eLN & 15);
        *(bfx8*)&sY[eLN*128 + (cA << 3)] = ha.v;
        *(bfx8*)&sY[eLN*128 + (cB << 3)] = hb2.v;
    }
    __syncthreads();

    f32x4 d00={0,0,0,0}, d01={0,0,0,0}, d10={0,0,0,0}, d11={0,0,0,0};
    {
        const u16* c2H0 = B2H + (size_t)colB0*HID + lh*8;
        const u16* c2H1 = B2H + (size_t)colB1*HID + lh*8;
        const u16* c2L0 = B2L + (size_t)colB0*HID + lh*8;
        const u16* c2L1 = B2L + (size_t)colB1*HID + lh*8;
        bfx8 wh0 = *(const bfx8*)c2H0, wh1 = *(const bfx8*)c2H1;
        bfx8 wl0 = *(const bfx8*)c2L0, wl1 = *(const bfx8*)c2L1;
        #pragma unroll
        for (int s = 0; s < 4; ++s) {
            bfx8 nh0 = wh0, nh1 = wh1, nl0 = wl0, nl1 = wl1;
            if (s < 3) {
                nh0 = *(const bfx8*)(c2H0 + 32*(s+1)); nh1 = *(const bfx8*)(c2H1 + 32*(s+1));
                nl0 = *(const bfx8*)(c2L0 + 32*(s+1)); nl1 = *(const bfx8*)(c2L1 + 32*(s+1));
            }
            const int c4 = s*4 + lh;
            const int i0 = lr*128 + ((c4 ^ lr) << 3);
            const int i1 = (16+lr)*128 + ((c4 ^ lr) << 3);
            bfx8 ah0 = *(const bfx8*)&sY[i0], ah1 = *(const bfx8*)&sY[i1];
            d00 = mfma2(ah0, wh0, wl0, d00);
            d01 = mfma2(ah0, wh1, wl1, d01);
            d10 = mfma2(ah1, wh0, wl0, d10);
            d11 = mfma2(ah1, wh1, wl1, d11);
            wh0 = nh0; wh1 = nh1; wl0 = nl0; wl1 = nl1;
        }
    }

    {
        const float b20 = bn2[colB0], b21 = bn2[colB1];
        #pragma unroll
        for (int j = 0; j < 4; ++j) {
            const int r0 = 4*lh + j, r1 = 16 + 4*lh + j;
            const size_t i00 = (size_t)(node0+r0)*HID + colB0;
            const size_t i01 = (size_t)(node0+r0)*HID + colB1;
            const size_t i10 = (size_t)(node0+r1)*HID + colB0;
            const size_t i11 = (size_t)(node0+r1)*HID + colB1;
            float v00 = hh[i00] + d00[j] + b20;
            float v01 = hh[i01] + d01[j] + b21;
            float v10 = hh[i10] + d10[j] + b20;
            float v11 = hh[i11] + d11[j] + b21;
            hh[i00] = v00; hh[i01] = v01; hh[i10] = v10; hh[i11] = v11;
            u16 h00 = bf16_rn(v00); hhH[i00] = h00; hhL[i00] = bf16_rn(v00 - bf16_tof(h00));
            u16 h01 = bf16_rn(v01); hhH[i01] = h01; hhL[i01] = bf16_rn(v01 - bf16_tof(h01));
            u16 h10 = bf16_rn(v10); hhH[i10] = h10; hhL[i10] = bf16_rn(v10 - bf16_tof(h10));
            u16 h11 = bf16_rn(v11); hhH[i11] = h11; hhL[i11] = bf16_rn(v11 - bf16_tof(h11));
        }
    }
}

// ---------------------------------------------------------------- output head
__global__ __launch_bounds__(HID) void out_k(
    const float* __restrict__ hh, const float* __restrict__ Woe,
    const float* __restrict__ boe, const float* __restrict__ Wf,
    const float* __restrict__ bf, float* __restrict__ out)
{
    __shared__ float sH[HID];
    const int lig = blockIdx.x, tid = threadIdx.x;
    float s = 0.0f;
    const float* base = hh + (size_t)lig*KAT*HID + tid;
    #pragma unroll 8
    for (int a = 0; a < KAT; ++a) s += base[a*HID];
    sH[tid] = s * (1.0f/KAT);
    __syncthreads();

    float contrib = 0.0f;
    if (tid < OUTF) {
        float p = boe[tid];
        #pragma unroll 4
        for (int i = 0; i < HID; ++i)
            p = fmaf(sH[i], Woe[i*OUTF + tid], p);
        contrib = p * Wf[tid];
    }
    #pragma unroll
    for (int m = 1; m < 64; m <<= 1) contrib += __shfl_xor(contrib, m);
    if (tid == 0) out[lig] = contrib + bf[0];
}

// ---------------------------------------------------------------- launch
extern "C" void kernel_launch(void* const* d_in, const int* in_sizes, int n_in,
                              void* d_out, int out_size, void* d_ws, size_t ws_size,
                              hipStream_t stream)
{
    (void)in_sizes; (void)n_in; (void)out_size; (void)ws_size;
    const float* x    = (const float*)d_in[0];
    const float* h    = (const float*)d_in[1];
    const int*   t    = (const int*)d_in[2];
    const int*   edges= (const int*)d_in[3];
    const int*   tb   = (const int*)d_in[4];
    const float* temb = (const float*)d_in[8];
    const float* Win  = (const float*)d_in[9];
    const float* bin  = (const float*)d_in[10];
    const float* We1  = (const float*)d_in[11];
    const float* be1  = (const float*)d_in[12];
    const float* g1   = (const float*)d_in[13];
    const float* bt1  = (const float*)d_in[14];
    const float* We2  = (const float*)d_in[15];
    const float* be2  = (const float*)d_in[16];
    const float* Watt = (const float*)d_in[17];
    const float* batt = (const float*)d_in[18];
    const float* Wn1  = (const float*)d_in[19];
    const float* bn1  = (const float*)d_in[20];
    const float* g2   = (const float*)d_in[21];
    const float* bt2  = (const float*)d_in[22];
    const float* Wn2  = (const float*)d_in[23];
    const float* bn2  = (const float*)d_in[24];
    const float* Woe  = (const float*)d_in[25];
    const float* boe  = (const float*)d_in[26];
    const float* Wf   = (const float*)d_in[27];
    const float* bf   = (const float*)d_in[28];
    float* out = (float*)d_out;

    char* wsb = (char*)d_ws;
    float* hh  = (float*)(wsb);                        // 16 MB
    u16* hhH   = (u16*)(wsb + ((size_t)16<<20));       // 8 MB
    u16* hhL   = (u16*)(wsb + ((size_t)24<<20));       // 8 MB
    u16* aggH  = (u16*)(wsb + ((size_t)32<<20));       // 8 MB
    u16* aggL  = (u16*)(wsb + ((size_t)40<<20));       // 8 MB
    u16* tembH = (u16*)(wsb + ((size_t)48<<20));
    u16* tembL = tembH + PREP_TEMB;
    u16* W1TH  = tembL + PREP_TEMB;
    u16* W1TL  = W1TH + PREP_W1;
    u16* W2TH  = W1TL + PREP_W1;
    u16* W2TL  = W2TH + PREP_W2;
    u16* WN1TH = W2TL + PREP_W2;
    u16* WN1TL = WN1TH + PREP_WN1;
    u16* WN2TH = WN1TL + PREP_WN1;
    u16* WN2TL = WN2TH + PREP_WN2;

    prep_k<<<(PREP_TOT + 255)/256, 256, 0, stream>>>(
        temb, We1, We2, Wn1, Wn2,
        tembH, tembL, W1TH, W1TL, W2TH, W2TL, WN1TH, WN1TL, WN2TH, WN2TL);

    embed_k<<<NNODES/8, 256, 0, stream>>>(h, t, temb, Win, bin, hh, hhH, hhL);

    for (int l = 0; l < 4; ++l) {
        edge_k<<<NNODES/NPB, 256, 0, stream>>>(
            hhH, hhL, x, edges + NEDGES, tb, tembH, tembL,
            W1TH + (size_t)l*128*K1, W1TL + (size_t)l*128*K1,
            W2TH + (size_t)l*128*128, W2TL + (size_t)l*128*128,
            be1 + l*HID, g1 + l*HID, bt1 + l*HID, be2 + l*HID,
            Watt + l*HID, batt + l, aggH, aggL);
        node_k<<<NNODES/32, 256, 0, stream>>>(
            hh, hhH, hhL, aggH, aggL,
            WN1TH + (size_t)l*128*256, WN1TL + (size_t)l*128*256,
            WN2TH + (size_t)l*128*128, WN2TL + (size_t)l*128*128,
            bn1 + l*HID, g2 + l*HID, bt2 + l*HID, bn2 + l*HID);
    }
    out_k<<<NLIG, HID, 0, stream>>>(hh, Woe, boe, Wf, bf, out);
}

// Round 12
// 517.708 us; speedup vs baseline: 1.8216x; 1.2847x over previous
//
#include <hip/hip_runtime.h>
#include <math.h>

#define NNODES 32768
#define NLIG   1024
#define KAT    32
#define KNN    8
#define NEDGES (NNODES*KNN)
#define HID    128
#define TF     16
#define NG     20
#define OUTF   64

#define NPB    16           // nodes per edge-block
#define EPB    128          // edges per edge-block
#define K1     320          // padded GEMM1 K (292 -> 320)
#define MIDSTR 132          // node_k sMid row stride (floats)

typedef unsigned short u16;
typedef _Float16 f16;
typedef __attribute__((__ext_vector_type__(8))) _Float16 f16x8;
typedef __attribute__((__ext_vector_type__(4))) float f32x4;

union U8h { f16 a[8]; f16x8 v; };

// Gaussian smearing constants: og[g] = 5^(g/19)-1, coeff = -0.5/diff^2
__device__ const float GS_OG[20] = {
    0.0f, 0.0883984f, 0.1845966f, 0.2893285f, 0.4033028f,
    0.5273539f, 0.6623701f, 0.8093209f, 0.9692606f, 1.1433389f,
    1.3328075f, 1.5390240f, 1.7634662f, 2.0077560f, 2.2736369f,
    2.5630207f, 2.8779861f, 3.2207938f, 3.5939058f, 4.0f };
__device__ const float GS_CF[20] = {
    -63.9853f, -63.9853f, -54.0303f, -45.5840f, -38.4908f,
    -32.4913f, -27.4283f, -23.1540f, -19.5460f, -16.4999f,
    -13.9282f, -11.7577f, -9.92569f, -8.37837f, -7.07287f,
    -5.97065f, -5.04016f, -4.25470f, -3.59163f, -3.03191f };

__device__ __forceinline__ float siluf(float v) {
    return __fdividef(v, 1.0f + __expf(-v));
}
__device__ __forceinline__ float sigf(float v) {
    return __fdividef(1.0f, 1.0f + __expf(-v));
}
__device__ __forceinline__ f32x4 mfma16(f16x8 a, f16x8 b, f32x4 c) {
    return __builtin_amdgcn_mfma_f32_16x16x32_f16(a, b, c, 0, 0, 0);
}

// ---------------------------------------------------------------- prep (fp16 single)
#define PREP_TEMB 16000
#define PREP_W1   (4*128*K1)       // 163840
#define PREP_W2   (4*128*128)      // 65536
#define PREP_WN1  (4*128*256)      // 131072
#define PREP_WN2  (4*128*128)      // 65536
#define PREP_TOT  (PREP_TEMB+PREP_W1+PREP_W2+PREP_WN1+PREP_WN2)

__global__ __launch_bounds__(256) void prep_k(
    const float* __restrict__ temb, const float* __restrict__ We1,
    const float* __restrict__ We2,  const float* __restrict__ Wn1,
    const float* __restrict__ Wn2,
    f16* __restrict__ tembF,
    f16* __restrict__ W1T, f16* __restrict__ W2T,
    f16* __restrict__ WN1T, f16* __restrict__ WN2T)
{
    int i = blockIdx.x*256 + threadIdx.x;
    if (i >= PREP_TOT) return;
    float v; f16* dst; int di;
    if (i < PREP_TEMB) {
        v = temb[i]; dst = tembF; di = i;
    } else if (i < PREP_TEMB + PREP_W1) {
        int j = i - PREP_TEMB; di = j; dst = W1T;
        int l = j / (128*K1); int r = j - l*(128*K1);
        int col = r / K1, k = r - col*K1;
        v = (k < 292) ? We1[(size_t)l*292*128 + (size_t)k*128 + col] : 0.0f;
    } else if (i < PREP_TEMB + PREP_W1 + PREP_W2) {
        int j = i - PREP_TEMB - PREP_W1; di = j; dst = W2T;
        int l = j >> 14; int r = j & 16383;
        int col = r >> 7, k = r & 127;
        v = We2[(size_t)l*16384 + (size_t)k*128 + col];
    } else if (i < PREP_TEMB + PREP_W1 + PREP_W2 + PREP_WN1) {
        int j = i - PREP_TEMB - PREP_W1 - PREP_W2; di = j; dst = WN1T;
        int l = j >> 15; int r = j & 32767;
        int col = r >> 8, k = r & 255;
        v = Wn1[(size_t)l*32768 + (size_t)k*128 + col];
    } else {
        int j = i - PREP_TEMB - PREP_W1 - PREP_W2 - PREP_WN1; di = j; dst = WN2T;
        int l = j >> 14; int r = j & 16383;
        int col = r >> 7, k = r & 127;
        v = Wn2[(size_t)l*16384 + (size_t)k*128 + col];
    }
    dst[di] = (f16)v;
}

// ---------------------------------------------------------------- embed (8 nodes/block)
__global__ __launch_bounds__(256) void embed_k(
    const float* __restrict__ h, const int* __restrict__ t,
    const float* __restrict__ temb, const float* __restrict__ Win,
    const float* __restrict__ bin, float* __restrict__ hh,
    f16* __restrict__ hhF)
{
    __shared__ float sIn[8][32];
    const int tid = threadIdx.x;
    {
        const int n = tid >> 5, i = tid & 31;
        const int node = blockIdx.x*8 + n;
        sIn[n][i] = (i < TF) ? h[node*TF + i] : temb[t[node]*TF + (i-TF)];
    }
    __syncthreads();
    const int sub = tid >> 7, col = tid & 127;
    float acc[4];
    const float b = bin[col];
    acc[0]=acc[1]=acc[2]=acc[3]=b;
    #pragma unroll 8
    for (int i = 0; i < 32; ++i) {
        const float wv = Win[i*HID + col];
        acc[0] = fmaf(sIn[sub][i],   wv, acc[0]);
        acc[1] = fmaf(sIn[2+sub][i], wv, acc[1]);
        acc[2] = fmaf(sIn[4+sub][i], wv, acc[2]);
        acc[3] = fmaf(sIn[6+sub][i], wv, acc[3]);
    }
    #pragma unroll
    for (int nn = 0; nn < 4; ++nn) {
        const size_t idx = (size_t)(blockIdx.x*8 + nn*2 + sub)*HID + col;
        hh[idx] = acc[nn];
        hhF[idx] = (f16)acc[nn];
    }
}

// ---------------------------------------------------------------- edge
// M=128 (16 nodes, 128 edges/block), fp16 single-product MFMA throughout.
__global__ __launch_bounds__(256, 4) void edge_k(
    const f16* __restrict__ hhF, const float* __restrict__ x,
    const int* __restrict__ ecol, const int* __restrict__ tbond,
    const f16* __restrict__ tembF,
    const f16* __restrict__ W1T, const f16* __restrict__ W2T,
    const float* __restrict__ be1, const float* __restrict__ g1,
    const float* __restrict__ bt1, const float* __restrict__ be2,
    const float* __restrict__ Watt, const float* __restrict__ batt,
    f16* __restrict__ aggF)
{
    // LDS (38400 B):
    //  [0,8192)       tbl (32 atoms x 128 f16)   | after LN: sB2 (128x128 f16 = 32K) [0,32768)
    //  [8192,24576)   tailB (128 x 64 f16)
    //  [32768,36864)  sStats (128 x 4 x f32x2)   | after GEMM2: sAP (512 f32)
    //  [36864,37888)  sMuInv (128 x f32x2)
    //  [37888,38400)  sAttv (128 f32)
    __shared__ __align__(16) char smem[38400];
    f16*   tbl   = (f16*)(smem);
    f16*   tailB = (f16*)(smem + 8192);
    float* sStats= (float*)(smem + 32768);
    float* sMuInv= (float*)(smem + 36864);
    f16*   sB2   = (f16*)(smem);
    float* sAP   = (float*)(smem + 32768);
    float* sAttv = (float*)(smem + 37888);

    const int tid = threadIdx.x;
    const int node0 = blockIdx.x * NPB;
    const int ligBase = node0 & ~31;
    const int aBase   = node0 & 31;      // 0 or 16
    const int w = tid >> 6, lane = tid & 63, lr = lane & 15, lh = lane >> 4;
    const int colB0 = w*32 + lr, colB1 = colB0 + 16;

    // ---- per-lane col atom ids, packed 8x8b into 2 u32 -----------------
    unsigned aColPk0 = 0, aColPk1 = 0;
    #pragma unroll
    for (int rt = 0; rt < 4; ++rt)
        aColPk0 |= (unsigned)(ecol[node0*KNN + rt*16 + lr] & 31) << (rt*8);
    #pragma unroll
    for (int rt = 0; rt < 4; ++rt)
        aColPk1 |= (unsigned)(ecol[node0*KNN + (4+rt)*16 + lr] & 31) << (rt*8);

    // ---- GEMM1 weight pointers + first fragments -----------------------
    const f16* bF0 = W1T + (size_t)colB0*K1 + lh*8;
    const f16* bF1 = W1T + (size_t)colB1*K1 + lh*8;
    f16x8 wf0 = *(const f16x8*)bF0, wf1 = *(const f16x8*)bF1;

    // ---- stage ligand hh table (32 atoms x 16 chunks) ------------------
    for (int idx = tid; idx < 512; idx += 256) {
        const int a = idx >> 4, c4 = idx & 15;
        const f16x8 v = *(const f16x8*)(hhF + (size_t)(ligBase + a)*HID + c4*8);
        *(f16x8*)&tbl[a*128 + ((c4 ^ (a & 15)) << 3)] = v;
    }

    // ---- tail (fp16) [128 rows][8 chunks]: temb(2)|smear(3)|0(3) -------
    for (int pe = tid; pe < 1024; pe += 256) {
        const int row = pe & 127, part = pe >> 7;
        U8h vh;
        if (part < 2) {
            const int r = node0 + (row >> 3);
            const int c = ecol[node0*KNN + row];
            int sbi = r*(KAT-1) + c - (r/KAT)*KAT - (r < c ? 1 : 0);
            const int tb = tbond[sbi];
            #pragma unroll
            for (int j = 0; j < 8; ++j)
                vh.a[j] = tembF[tb*TF + part*8 + j];
        } else if (part < 5) {
            const int r = node0 + (row >> 3);
            const int c = ecol[node0*KNN + row];
            float dx = x[3*r]-x[3*c], dy = x[3*r+1]-x[3*c+1], dz = x[3*r+2]-x[3*c+2];
            float dist = fminf(sqrtf(dx*dx+dy*dy+dz*dz), 4.0f);
            #pragma unroll
            for (int j = 0; j < 8; ++j) {
                int g = (part-2)*8 + j;
                float v = 0.0f;
                if (g < NG) {
                    float dd = dist - GS_OG[g];
                    v = __expf(GS_CF[g]*dd*dd);
                }
                vh.a[j] = (f16)v;
            }
        } else {
            #pragma unroll
            for (int j = 0; j < 8; ++j) vh.a[j] = (f16)0.0f;
        }
        *(f16x8*)&tailB[row*64 + ((part ^ (row & 7)) << 3)] = vh.v;
    }
    __syncthreads();                                    // bar1

    // ---- GEMM1: [128 x 320] @ [320 x 128], 1-deep W prefetch -----------
    f32x4 acc[8][2];
    #pragma unroll
    for (int rt = 0; rt < 8; ++rt) { acc[rt][0] = (f32x4){0,0,0,0}; acc[rt][1] = (f32x4){0,0,0,0}; }
    {
        #pragma unroll
        for (int s = 0; s < 10; ++s) {
            f16x8 nf0 = wf0, nf1 = wf1;
            if (s < 9) {
                nf0 = *(const f16x8*)(bF0 + 32*(s+1));
                nf1 = *(const f16x8*)(bF1 + 32*(s+1));
            }
            if (s < 4) {
                #pragma unroll
                for (int rt = 0; rt < 8; ++rt) {
                    const int aR = aBase + 2*rt + (lr >> 3);
                    const int c4 = s*4 + lh;
                    const int ad = aR*128 + ((c4 ^ (aR & 15)) << 3);
                    const f16x8 ah = *(const f16x8*)&tbl[ad];
                    acc[rt][0] = mfma16(ah, wf0, acc[rt][0]);
                    acc[rt][1] = mfma16(ah, wf1, acc[rt][1]);
                }
            } else if (s < 8) {
                #pragma unroll
                for (int rt = 0; rt < 8; ++rt) {
                    const int aC = (int)((rt < 4 ? (aColPk0 >> (rt*8))
                                                 : (aColPk1 >> ((rt-4)*8))) & 31u);
                    const int c4 = (s-4)*4 + lh;
                    const int ad = aC*128 + ((c4 ^ (aC & 15)) << 3);
                    const f16x8 ah = *(const f16x8*)&tbl[ad];
                    acc[rt][0] = mfma16(ah, wf0, acc[rt][0]);
                    acc[rt][1] = mfma16(ah, wf1, acc[rt][1]);
                }
            } else {
                #pragma unroll
                for (int rt = 0; rt < 8; ++rt) {
                    const int r = rt*16 + lr;
                    const int c = (s-8)*4 + lh;
                    const int ad = r*64 + ((c ^ (r & 7)) << 3);
                    const f16x8 ah = *(const f16x8*)&tailB[ad];
                    acc[rt][0] = mfma16(ah, wf0, acc[rt][0]);
                    acc[rt][1] = mfma16(ah, wf1, acc[rt][1]);
                }
            }
            wf0 = nf0; wf1 = nf1;
        }
    }

    // ---- bias + in-register LN partials --------------------------------
    {
        const float b10 = be1[colB0], b11 = be1[colB1];
        #pragma unroll
        for (int rt = 0; rt < 8; ++rt)
            #pragma unroll
            for (int j = 0; j < 4; ++j) { acc[rt][0][j] += b10; acc[rt][1][j] += b11; }
    }
    {
        #pragma unroll
        for (int rt = 0; rt < 8; ++rt) {
            float sv[4], qv[4];
            #pragma unroll
            for (int j = 0; j < 4; ++j) {
                const float a0 = acc[rt][0][j], a1 = acc[rt][1][j];
                sv[j] = a0 + a1; qv[j] = a0*a0 + a1*a1;
            }
            #pragma unroll
            for (int msk = 1; msk < 16; msk <<= 1) {
                #pragma unroll
                for (int j = 0; j < 4; ++j) {
                    sv[j] += __shfl_xor(sv[j], msk);
                    qv[j] += __shfl_xor(qv[j], msk);
                }
            }
            if (lr == 0) {
                #pragma unroll
                for (int j = 0; j < 4; ++j) {
                    const int row = rt*16 + 4*lh + j;
                    sStats[(row*4 + w)*2 + 0] = sv[j];
                    sStats[(row*4 + w)*2 + 1] = qv[j];
                }
            }
        }
    }
    __syncthreads();                                    // bar2

    if (tid < EPB) {
        const float4 a = *(const float4*)&sStats[tid*8];
        const float4 b = *(const float4*)&sStats[tid*8 + 4];
        const float st = a.x + a.z + b.x + b.z;
        const float qt = a.y + a.w + b.y + b.w;
        const float mu  = st * (1.0f/HID);
        const float var = qt * (1.0f/HID) - mu*mu;
        sMuInv[tid*2 + 0] = mu;
        sMuInv[tid*2 + 1] = rsqrtf(var + 1e-5f);
    }
    __syncthreads();                                    // bar3

    // ---- GEMM2 weight pointers + first fragments -----------------------
    const f16* c2F0 = W2T + (size_t)colB0*HID + lh*8;
    const f16* c2F1 = W2T + (size_t)colB1*HID + lh*8;
    f16x8 g2f0 = *(const f16x8*)c2F0, g2f1 = *(const f16x8*)c2F1;

    // ---- normalize + SiLU in regs, write fp16 acts to sB2 --------------
    {
        const float G0 = g1[colB0], G1s = g1[colB1];
        const float B0 = bt1[colB0], B1s = bt1[colB1];
        #pragma unroll
        for (int rt = 0; rt < 8; ++rt) {
            const int r0 = rt*16 + 4*lh;
            const float4 mi0 = *(const float4*)&sMuInv[r0*2];      // mu0,inv0,mu1,inv1
            const float4 mi1 = *(const float4*)&sMuInv[r0*2 + 4];  // mu2,inv2,mu3,inv3
            acc[rt][0][0] = siluf(fmaf((acc[rt][0][0]-mi0.x)*mi0.y, G0, B0));
            acc[rt][1][0] = siluf(fmaf((acc[rt][1][0]-mi0.x)*mi0.y, G1s, B1s));
            acc[rt][0][1] = siluf(fmaf((acc[rt][0][1]-mi0.z)*mi0.w, G0, B0));
            acc[rt][1][1] = siluf(fmaf((acc[rt][1][1]-mi0.z)*mi0.w, G1s, B1s));
            acc[rt][0][2] = siluf(fmaf((acc[rt][0][2]-mi1.x)*mi1.y, G0, B0));
            acc[rt][1][2] = siluf(fmaf((acc[rt][1][2]-mi1.x)*mi1.y, G1s, B1s));
            acc[rt][0][3] = siluf(fmaf((acc[rt][0][3]-mi1.z)*mi1.w, G0, B0));
            acc[rt][1][3] = siluf(fmaf((acc[rt][1][3]-mi1.z)*mi1.w, G1s, B1s));
        }
    }
    {
        #pragma unroll
        for (int rt = 0; rt < 8; ++rt) {
            #pragma unroll
            for (int hcol = 0; hcol < 2; ++hcol) {
                const int col = hcol ? colB1 : colB0;
                const int gch = col >> 3, cw = col & 7;
                #pragma unroll
                for (int j = 0; j < 4; ++j) {
                    const int row = rt*16 + 4*lh + j;
                    sB2[row*128 + ((gch ^ (row & 15)) << 3) + cw] =
                        (f16)acc[rt][hcol][j];
                }
            }
        }
    }
    __syncthreads();                                    // bar4

    // ---- GEMM2: [128 x 128] @ [128 x 128] ------------------------------
    f32x4 d[8][2];
    #pragma unroll
    for (int rt = 0; rt < 8; ++rt) { d[rt][0] = (f32x4){0,0,0,0}; d[rt][1] = (f32x4){0,0,0,0}; }
    {
        #pragma unroll
        for (int s = 0; s < 4; ++s) {
            f16x8 nf0 = g2f0, nf1 = g2f1;
            if (s < 3) {
                nf0 = *(const f16x8*)(c2F0 + 32*(s+1));
                nf1 = *(const f16x8*)(c2F1 + 32*(s+1));
            }
            #pragma unroll
            for (int rt = 0; rt < 8; ++rt) {
                const int rowL = rt*16 + lr;
                const int c4 = s*4 + lh;
                const f16x8 ah = *(const f16x8*)&sB2[rowL*128 + ((c4 ^ (rowL & 15)) << 3)];
                d[rt][0] = mfma16(ah, g2f0, d[rt][0]);
                d[rt][1] = mfma16(ah, g2f1, d[rt][1]);
            }
            g2f0 = nf0; g2f1 = nf1;
        }
    }

    // ---- SiLU in place (d becomes m) + attention gate ------------------
    {
        const float b20 = be2[colB0], b21 = be2[colB1];
        #pragma unroll
        for (int rt = 0; rt < 8; ++rt) {
            #pragma unroll
            for (int j = 0; j < 4; ++j) {
                d[rt][0][j] = siluf(d[rt][0][j] + b20);
                d[rt][1][j] = siluf(d[rt][1][j] + b21);
            }
        }
    }
    {
        const float wa0 = Watt[colB0], wa1 = Watt[colB1];
        float pa[8][4];
        #pragma unroll
        for (int rt = 0; rt < 8; ++rt)
            #pragma unroll
            for (int j = 0; j < 4; ++j)
                pa[rt][j] = d[rt][0][j]*wa0 + d[rt][1][j]*wa1;
        #pragma unroll
        for (int msk = 1; msk < 16; msk <<= 1) {
            #pragma unroll
            for (int rt = 0; rt < 8; ++rt)
                #pragma unroll
                for (int j = 0; j < 4; ++j)
                    pa[rt][j] += __shfl_xor(pa[rt][j], msk);
        }
        if (lr == 0) {
            #pragma unroll
            for (int rt = 0; rt < 8; ++rt)
                #pragma unroll
                for (int j = 0; j < 4; ++j)
                    sAP[w*128 + rt*16 + 4*lh + j] = pa[rt][j];
        }
    }
    __syncthreads();                                    // bar5
    if (tid < EPB)
        sAttv[tid] = sigf(sAP[tid] + sAP[128+tid] + sAP[256+tid] + sAP[384+tid] + batt[0]);
    __syncthreads();                                    // bar6

    // ---- gated aggregate -> aggF ---------------------------------------
    #pragma unroll
    for (int rt = 0; rt < 8; ++rt) {
        float s0 = 0.0f, s1 = 0.0f;
        #pragma unroll
        for (int j = 0; j < 4; ++j) {
            const float av = sAttv[rt*16 + 4*lh + j];
            s0 += d[rt][0][j]*av;
            s1 += d[rt][1][j]*av;
        }
        s0 += __shfl_xor(s0, 16);
        s1 += __shfl_xor(s1, 16);
        if ((lh & 1) == 0) {
            const int node = node0 + 2*rt + (lh >> 1);
            aggF[(size_t)node*HID + colB0] = (f16)(s0*0.2f);
            aggF[(size_t)node*HID + colB1] = (f16)(s1*0.2f);
        }
    }
}

// ---------------------------------------------------------------- node (fp16 MFMA, 32 nodes/block)
__global__ __launch_bounds__(256, 6) void node_k(
    float* __restrict__ hh, f16* __restrict__ hhF,
    const f16* __restrict__ aggF,
    const f16* __restrict__ B1T, const f16* __restrict__ B2T,
    const float* __restrict__ bn1, const float* __restrict__ g2,
    const float* __restrict__ bt2, const float* __restrict__ bn2)
{
    __shared__ __align__(16) char smem[16896];
    float* sMid = (float*)smem;
    f16* sY = (f16*)smem;                // fp16 post-LN acts (8 KB)

    const int tid = threadIdx.x;
    const int node0 = blockIdx.x * 32;
    const int w = tid >> 6, lane = tid & 63, lr = lane & 15, lh = lane >> 4;
    const int colB0 = w*32 + lr, colB1 = colB0 + 16;

    const f16* a1f = hhF  + (size_t)(node0+lr)*HID + lh*8;
    const f16* a2f = aggF + (size_t)(node0+lr)*HID + lh*8;
    const f16* c1F0 = B1T + (size_t)colB0*256 + lh*8;
    const f16* c1F1 = B1T + (size_t)colB1*256 + lh*8;

    f32x4 acc00={0,0,0,0}, acc01={0,0,0,0}, acc10={0,0,0,0}, acc11={0,0,0,0};
    {
        f16x8 wf0 = *(const f16x8*)c1F0, wf1 = *(const f16x8*)c1F1;
        #pragma unroll
        for (int s = 0; s < 8; ++s) {
            f16x8 nf0 = wf0, nf1 = wf1;
            if (s < 7) {
                nf0 = *(const f16x8*)(c1F0 + 32*(s+1));
                nf1 = *(const f16x8*)(c1F1 + 32*(s+1));
            }
            f16x8 ah0, ah1;
            if (s < 4) {
                ah0 = *(const f16x8*)(a1f + 32*s);
                ah1 = *(const f16x8*)(a1f + 16*HID + 32*s);
            } else {
                ah0 = *(const f16x8*)(a2f + 32*(s-4));
                ah1 = *(const f16x8*)(a2f + 16*HID + 32*(s-4));
            }
            acc00 = mfma16(ah0, wf0, acc00);
            acc01 = mfma16(ah0, wf1, acc01);
            acc10 = mfma16(ah1, wf0, acc10);
            acc11 = mfma16(ah1, wf1, acc11);
            wf0 = nf0; wf1 = nf1;
        }
    }
    {
        const float b10 = bn1[colB0], b11 = bn1[colB1];
        #pragma unroll
        for (int j = 0; j < 4; ++j) {
            const int r0 = 4*lh + j;
            sMid[r0*MIDSTR + colB0]      = acc00[j] + b10;
            sMid[r0*MIDSTR + colB1]      = acc01[j] + b11;
            sMid[(16+r0)*MIDSTR + colB0] = acc10[j] + b10;
            sMid[(16+r0)*MIDSTR + colB1] = acc11[j] + b11;
        }
    }
    __syncthreads();

    float y[16];
    const int eLN = tid >> 3, c0 = (tid & 7)*16;
    {
        const float* mrow = &sMid[eLN*MIDSTR + c0];
        float4 v0 = *(const float4*)&mrow[0];
        float4 v1 = *(const float4*)&mrow[4];
        float4 v2 = *(const float4*)&mrow[8];
        float4 v3 = *(const float4*)&mrow[12];
        float s = v0.x+v0.y+v0.z+v0.w + v1.x+v1.y+v1.z+v1.w
                + v2.x+v2.y+v2.z+v2.w + v3.x+v3.y+v3.z+v3.w;
        float q = v0.x*v0.x+v0.y*v0.y+v0.z*v0.z+v0.w*v0.w
                + v1.x*v1.x+v1.y*v1.y+v1.z*v1.z+v1.w*v1.w
                + v2.x*v2.x+v2.y*v2.y+v2.z*v2.z+v2.w*v2.w
                + v3.x*v3.x+v3.y*v3.y+v3.z*v3.z+v3.w*v3.w;
        #pragma unroll
        for (int m = 4; m >= 1; m >>= 1) { s += __shfl_xor(s, m); q += __shfl_xor(q, m); }
        float mu  = s * (1.0f/HID);
        float var = q * (1.0f/HID) - mu*mu;
        float inv = rsqrtf(var + 1e-5f);
        const float4 G0 = *(const float4*)&g2[c0+0],  G1v = *(const float4*)&g2[c0+4];
        const float4 G2 = *(const float4*)&g2[c0+8],  G3 = *(const float4*)&g2[c0+12];
        const float4 B0 = *(const float4*)&bt2[c0+0], B1 = *(const float4*)&bt2[c0+4];
        const float4 B2 = *(const float4*)&bt2[c0+8], B3 = *(const float4*)&bt2[c0+12];
        y[0]=siluf(fmaf((v0.x-mu)*inv,G0.x,B0.x));  y[1]=siluf(fmaf((v0.y-mu)*inv,G0.y,B0.y));
        y[2]=siluf(fmaf((v0.z-mu)*inv,G0.z,B0.z));  y[3]=siluf(fmaf((v0.w-mu)*inv,G0.w,B0.w));
        y[4]=siluf(fmaf((v1.x-mu)*inv,G1v.x,B1.x)); y[5]=siluf(fmaf((v1.y-mu)*inv,G1v.y,B1.y));
        y[6]=siluf(fmaf((v1.z-mu)*inv,G1v.z,B1.z)); y[7]=siluf(fmaf((v1.w-mu)*inv,G1v.w,B1.w));
        y[8]=siluf(fmaf((v2.x-mu)*inv,G2.x,B2.x));  y[9]=siluf(fmaf((v2.y-mu)*inv,G2.y,B2.y));
        y[10]=siluf(fmaf((v2.z-mu)*inv,G2.z,B2.z)); y[11]=siluf(fmaf((v2.w-mu)*inv,G2.w,B2.w));
        y[12]=siluf(fmaf((v3.x-mu)*inv,G3.x,B3.x)); y[13]=siluf(fmaf((v3.y-mu)*inv,G3.y,B3.y));
        y[14]=siluf(fmaf((v3.z-mu)*inv,G3.z,B3.z)); y[15]=siluf(fmaf((v3.w-mu)*inv,G3.w,B3.w));
    }
    __syncthreads();
    {
        U8h ha, hb2;
        #pragma unroll
        for (int j = 0; j < 8; ++j) {
            ha.a[j]  = (f16)y[j];
            hb2.a[j] = (f16)y[8+j];
        }
        const int cA = (2*(tid & 7))     ^ (eLN & 15);
        const int cB = (2*(tid & 7) + 1) ^ (eLN & 15);
        *(f16x8*)&sY[eLN*128 + (cA << 3)] = ha.v;
        *(f16x8*)&sY[eLN*128 + (cB << 3)] = hb2.v;
    }
    __syncthreads();

    f32x4 d00={0,0,0,0}, d01={0,0,0,0}, d10={0,0,0,0}, d11={0,0,0,0};
    {
        const f16* c2F0 = B2T + (size_t)colB0*HID + lh*8;
        const f16* c2F1 = B2T + (size_t)colB1*HID + lh*8;
        f16x8 wf0 = *(const f16x8*)c2F0, wf1 = *(const f16x8*)c2F1;
        #pragma unroll
        for (int s = 0; s < 4; ++s) {
            f16x8 nf0 = wf0, nf1 = wf1;
            if (s < 3) {
                nf0 = *(const f16x8*)(c2F0 + 32*(s+1));
                nf1 = *(const f16x8*)(c2F1 + 32*(s+1));
            }
            const int c4 = s*4 + lh;
            const int i0 = lr*128 + ((c4 ^ lr) << 3);
            const int i1 = (16+lr)*128 + ((c4 ^ lr) << 3);
            f16x8 ah0 = *(const f16x8*)&sY[i0], ah1 = *(const f16x8*)&sY[i1];
            d00 = mfma16(ah0, wf0, d00);
            d01 = mfma16(ah0, wf1, d01);
            d10 = mfma16(ah1, wf0, d10);
            d11 = mfma16(ah1, wf1, d11);
            wf0 = nf0; wf1 = nf1;
        }
    }

    {
        const float b20 = bn2[colB0], b21 = bn2[colB1];
        #pragma unroll
        for (int j = 0; j < 4; ++j) {
            const int r0 = 4*lh + j, r1 = 16 + 4*lh + j;
            const size_t i00 = (size_t)(node0+r0)*HID + colB0;
            const size_t i01 = (size_t)(node0+r0)*HID + colB1;
            const size_t i10 = (size_t)(node0+r1)*HID + colB0;
            const size_t i11 = (size_t)(node0+r1)*HID + colB1;
            float v00 = hh[i00] + d00[j] + b20;
            float v01 = hh[i01] + d01[j] + b21;
            float v10 = hh[i10] + d10[j] + b20;
            float v11 = hh[i11] + d11[j] + b21;
            hh[i00] = v00; hh[i01] = v01; hh[i10] = v10; hh[i11] = v11;
            hhF[i00] = (f16)v00; hhF[i01] = (f16)v01;
            hhF[i10] = (f16)v10; hhF[i11] = (f16)v11;
        }
    }
}

// ---------------------------------------------------------------- output head
__global__ __launch_bounds__(HID) void out_k(
    const float* __restrict__ hh, const float* __restrict__ Woe,
    const float* __restrict__ boe, const float* __restrict__ Wf,
    const float* __restrict__ bf, float* __restrict__ out)
{
    __shared__ float sH[HID];
    const int lig = blockIdx.x, tid = threadIdx.x;
    float s = 0.0f;
    const float* base = hh + (size_t)lig*KAT*HID + tid;
    #pragma unroll 8
    for (int a = 0; a < KAT; ++a) s += base[a*HID];
    sH[tid] = s * (1.0f/KAT);
    __syncthreads();

    float contrib = 0.0f;
    if (tid < OUTF) {
        float p = boe[tid];
        #pragma unroll 4
        for (int i = 0; i < HID; ++i)
            p = fmaf(sH[i], Woe[i*OUTF + tid], p);
        contrib = p * Wf[tid];
    }
    #pragma unroll
    for (int m = 1; m < 64; m <<= 1) contrib += __shfl_xor(contrib, m);
    if (tid == 0) out[lig] = contrib + bf[0];
}

// ---------------------------------------------------------------- launch
extern "C" void kernel_launch(void* const* d_in, const int* in_sizes, int n_in,
                              void* d_out, int out_size, void* d_ws, size_t ws_size,
                              hipStream_t stream)
{
    (void)in_sizes; (void)n_in; (void)out_size; (void)ws_size;
    const float* x    = (const float*)d_in[0];
    const float* h    = (const float*)d_in[1];
    const int*   t    = (const int*)d_in[2];
    const int*   edges= (const int*)d_in[3];
    const int*   tb   = (const int*)d_in[4];
    const float* temb = (const float*)d_in[8];
    const float* Win  = (const float*)d_in[9];
    const float* bin  = (const float*)d_in[10];
    const float* We1  = (const float*)d_in[11];
    const float* be1  = (const float*)d_in[12];
    const float* g1   = (const float*)d_in[13];
    const float* bt1  = (const float*)d_in[14];
    const float* We2  = (const float*)d_in[15];
    const float* be2  = (const float*)d_in[16];
    const float* Watt = (const float*)d_in[17];
    const float* batt = (const float*)d_in[18];
    const float* Wn1  = (const float*)d_in[19];
    const float* bn1  = (const float*)d_in[20];
    const float* g2   = (const float*)d_in[21];
    const float* bt2  = (const float*)d_in[22];
    const float* Wn2  = (const float*)d_in[23];
    const float* bn2  = (const float*)d_in[24];
    const float* Woe  = (const float*)d_in[25];
    const float* boe  = (const float*)d_in[26];
    const float* Wf   = (const float*)d_in[27];
    const float* bf   = (const float*)d_in[28];
    float* out = (float*)d_out;

    char* wsb = (char*)d_ws;
    float* hh  = (float*)(wsb);                        // 16 MB
    f16* hhF   = (f16*)(wsb + ((size_t)16<<20));       // 8 MB
    f16* aggF  = (f16*)(wsb + ((size_t)24<<20));       // 8 MB
    f16* tembF = (f16*)(wsb + ((size_t)32<<20));
    f16* W1T   = tembF + PREP_TEMB;
    f16* W2T   = W1T + PREP_W1;
    f16* WN1T  = W2T + PREP_W2;
    f16* WN2T  = WN1T + PREP_WN1;

    prep_k<<<(PREP_TOT + 255)/256, 256, 0, stream>>>(
        temb, We1, We2, Wn1, Wn2, tembF, W1T, W2T, WN1T, WN2T);

    embed_k<<<NNODES/8, 256, 0, stream>>>(h, t, temb, Win, bin, hh, hhF);

    for (int l = 0; l < 4; ++l) {
        edge_k<<<NNODES/NPB, 256, 0, stream>>>(
            hhF, x, edges + NEDGES, tb, tembF,
            W1T + (size_t)l*128*K1, W2T + (size_t)l*128*128,
            be1 + l*HID, g1 + l*HID, bt1 + l*HID, be2 + l*HID,
            Watt + l*HID, batt + l, aggF);
        node_k<<<NNODES/32, 256, 0, stream>>>(
            hh, hhF, aggF,
            WN1T + (size_t)l*128*256, WN2T + (size_t)l*128*128,
            bn1 + l*HID, g2 + l*HID, bt2 + l*HID, bn2 + l*HID);
    }
    out_k<<<NLIG, HID, 0, stream>>>(hh, Woe, boe, Wf, bf, out);
}

// Round 13
// 479.522 us; speedup vs baseline: 1.9666x; 1.0796x over previous
//
#include <hip/hip_runtime.h>
#include <math.h>

#define NNODES 32768
#define NLIG   1024
#define KAT    32
#define KNN    8
#define NEDGES (NNODES*KNN)
#define HID    128
#define TF     16
#define NG     20
#define OUTF   64

#define NPB    16           // nodes per edge-block
#define EPB    128          // edges per edge-block
#define K1     320          // padded GEMM1 K (292 -> 320)
#define MIDSTR 132          // node_k sMid row stride (floats)

typedef unsigned short u16;
typedef _Float16 f16;
typedef __attribute__((__ext_vector_type__(8))) _Float16 f16x8;
typedef __attribute__((__ext_vector_type__(4))) float f32x4;

union U8h { f16 a[8]; f16x8 v; };

// Gaussian smearing constants: og[g] = 5^(g/19)-1, coeff = -0.5/diff^2
__device__ const float GS_OG[20] = {
    0.0f, 0.0883984f, 0.1845966f, 0.2893285f, 0.4033028f,
    0.5273539f, 0.6623701f, 0.8093209f, 0.9692606f, 1.1433389f,
    1.3328075f, 1.5390240f, 1.7634662f, 2.0077560f, 2.2736369f,
    2.5630207f, 2.8779861f, 3.2207938f, 3.5939058f, 4.0f };
__device__ const float GS_CF[20] = {
    -63.9853f, -63.9853f, -54.0303f, -45.5840f, -38.4908f,
    -32.4913f, -27.4283f, -23.1540f, -19.5460f, -16.4999f,
    -13.9282f, -11.7577f, -9.92569f, -8.37837f, -7.07287f,
    -5.97065f, -5.04016f, -4.25470f, -3.59163f, -3.03191f };

__device__ __forceinline__ float siluf(float v) {
    return __fdividef(v, 1.0f + __expf(-v));
}
__device__ __forceinline__ float sigf(float v) {
    return __fdividef(1.0f, 1.0f + __expf(-v));
}
__device__ __forceinline__ f32x4 mfma16(f16x8 a, f16x8 b, f32x4 c) {
    return __builtin_amdgcn_mfma_f32_16x16x32_f16(a, b, c, 0, 0, 0);
}

// ---------------------------------------------------------------- prep (fp16 single)
#define PREP_TEMB 16000
#define PREP_W1   (4*128*K1)       // 163840
#define PREP_W2   (4*128*128)      // 65536
#define PREP_WN1  (4*128*256)      // 131072
#define PREP_WN2  (4*128*128)      // 65536
#define PREP_TOT  (PREP_TEMB+PREP_W1+PREP_W2+PREP_WN1+PREP_WN2)

__global__ __launch_bounds__(256) void prep_k(
    const float* __restrict__ temb, const float* __restrict__ We1,
    const float* __restrict__ We2,  const float* __restrict__ Wn1,
    const float* __restrict__ Wn2,
    f16* __restrict__ tembF,
    f16* __restrict__ W1T, f16* __restrict__ W2T,
    f16* __restrict__ WN1T, f16* __restrict__ WN2T)
{
    int i = blockIdx.x*256 + threadIdx.x;
    if (i >= PREP_TOT) return;
    float v; f16* dst; int di;
    if (i < PREP_TEMB) {
        v = temb[i]; dst = tembF; di = i;
    } else if (i < PREP_TEMB + PREP_W1) {
        int j = i - PREP_TEMB; di = j; dst = W1T;
        int l = j / (128*K1); int r = j - l*(128*K1);
        int col = r / K1, k = r - col*K1;
        v = (k < 292) ? We1[(size_t)l*292*128 + (size_t)k*128 + col] : 0.0f;
    } else if (i < PREP_TEMB + PREP_W1 + PREP_W2) {
        int j = i - PREP_TEMB - PREP_W1; di = j; dst = W2T;
        int l = j >> 14; int r = j & 16383;
        int col = r >> 7, k = r & 127;
        v = We2[(size_t)l*16384 + (size_t)k*128 + col];
    } else if (i < PREP_TEMB + PREP_W1 + PREP_W2 + PREP_WN1) {
        int j = i - PREP_TEMB - PREP_W1 - PREP_W2; di = j; dst = WN1T;
        int l = j >> 15; int r = j & 32767;
        int col = r >> 8, k = r & 255;
        v = Wn1[(size_t)l*32768 + (size_t)k*128 + col];
    } else {
        int j = i - PREP_TEMB - PREP_W1 - PREP_W2 - PREP_WN1; di = j; dst = WN2T;
        int l = j >> 14; int r = j & 16383;
        int col = r >> 7, k = r & 127;
        v = Wn2[(size_t)l*16384 + (size_t)k*128 + col];
    }
    dst[di] = (f16)v;
}

// ---------------------------------------------------------------- embed (8 nodes/block)
__global__ __launch_bounds__(256) void embed_k(
    const float* __restrict__ h, const int* __restrict__ t,
    const float* __restrict__ temb, const float* __restrict__ Win,
    const float* __restrict__ bin, float* __restrict__ hh,
    f16* __restrict__ hhF)
{
    __shared__ float sIn[8][32];
    const int tid = threadIdx.x;
    {
        const int n = tid >> 5, i = tid & 31;
        const int node = blockIdx.x*8 + n;
        sIn[n][i] = (i < TF) ? h[node*TF + i] : temb[t[node]*TF + (i-TF)];
    }
    __syncthreads();
    const int sub = tid >> 7, col = tid & 127;
    float acc[4];
    const float b = bin[col];
    acc[0]=acc[1]=acc[2]=acc[3]=b;
    #pragma unroll 8
    for (int i = 0; i < 32; ++i) {
        const float wv = Win[i*HID + col];
        acc[0] = fmaf(sIn[sub][i],   wv, acc[0]);
        acc[1] = fmaf(sIn[2+sub][i], wv, acc[1]);
        acc[2] = fmaf(sIn[4+sub][i], wv, acc[2]);
        acc[3] = fmaf(sIn[6+sub][i], wv, acc[3]);
    }
    #pragma unroll
    for (int nn = 0; nn < 4; ++nn) {
        const size_t idx = (size_t)(blockIdx.x*8 + nn*2 + sub)*HID + col;
        hh[idx] = acc[nn];
        hhF[idx] = (f16)acc[nn];
    }
}

// ---------------------------------------------------------------- edge
// M=128 (16 nodes, 128 edges/block), fp16 single-product MFMA throughout.
// __launch_bounds__(256,3): (256,4)'s 128-reg cap == exact working-set size
// (64 VGPR + 64 acc AGPR) -> spilled (round-12: FETCH 57 MB, dispatch-0 WRITE
// 98 MB of scratch). Cap ~170 fits with margin; LDS caps blocks at 4 anyway.
__global__ __launch_bounds__(256, 3) void edge_k(
    const f16* __restrict__ hhF, const float* __restrict__ x,
    const int* __restrict__ ecol, const int* __restrict__ tbond,
    const f16* __restrict__ tembF,
    const f16* __restrict__ W1T, const f16* __restrict__ W2T,
    const float* __restrict__ be1, const float* __restrict__ g1,
    const float* __restrict__ bt1, const float* __restrict__ be2,
    const float* __restrict__ Watt, const float* __restrict__ batt,
    f16* __restrict__ aggF)
{
    // LDS (38400 B):
    //  [0,8192)       tbl (32 atoms x 128 f16)   | after LN: sB2 (128x128 f16 = 32K) [0,32768)
    //  [8192,24576)   tailB (128 x 64 f16)
    //  [32768,36864)  sStats (128 x 4 x f32x2)   | after GEMM2: sAP (512 f32)
    //  [36864,37888)  sMuInv (128 x f32x2)
    //  [37888,38400)  sAttv (128 f32)
    __shared__ __align__(16) char smem[38400];
    f16*   tbl   = (f16*)(smem);
    f16*   tailB = (f16*)(smem + 8192);
    float* sStats= (float*)(smem + 32768);
    float* sMuInv= (float*)(smem + 36864);
    f16*   sB2   = (f16*)(smem);
    float* sAP   = (float*)(smem + 32768);
    float* sAttv = (float*)(smem + 37888);

    const int tid = threadIdx.x;
    const int node0 = blockIdx.x * NPB;
    const int ligBase = node0 & ~31;
    const int aBase   = node0 & 31;      // 0 or 16
    const int w = tid >> 6, lane = tid & 63, lr = lane & 15, lh = lane >> 4;
    const int colB0 = w*32 + lr, colB1 = colB0 + 16;

    // ---- per-lane col atom ids, packed 8x8b into 2 u32 -----------------
    unsigned aColPk0 = 0, aColPk1 = 0;
    #pragma unroll
    for (int rt = 0; rt < 4; ++rt)
        aColPk0 |= (unsigned)(ecol[node0*KNN + rt*16 + lr] & 31) << (rt*8);
    #pragma unroll
    for (int rt = 0; rt < 4; ++rt)
        aColPk1 |= (unsigned)(ecol[node0*KNN + (4+rt)*16 + lr] & 31) << (rt*8);

    // ---- GEMM1 weight pointers + first fragments -----------------------
    const f16* bF0 = W1T + (size_t)colB0*K1 + lh*8;
    const f16* bF1 = W1T + (size_t)colB1*K1 + lh*8;
    f16x8 wf0 = *(const f16x8*)bF0, wf1 = *(const f16x8*)bF1;

    // ---- stage ligand hh table (32 atoms x 16 chunks) ------------------
    for (int idx = tid; idx < 512; idx += 256) {
        const int a = idx >> 4, c4 = idx & 15;
        const f16x8 v = *(const f16x8*)(hhF + (size_t)(ligBase + a)*HID + c4*8);
        *(f16x8*)&tbl[a*128 + ((c4 ^ (a & 15)) << 3)] = v;
    }

    // ---- tail (fp16) [128 rows][8 chunks]: temb(2)|smear(3)|0(3) -------
    for (int pe = tid; pe < 1024; pe += 256) {
        const int row = pe & 127, part = pe >> 7;
        U8h vh;
        if (part < 2) {
            const int r = node0 + (row >> 3);
            const int c = ecol[node0*KNN + row];
            int sbi = r*(KAT-1) + c - (r/KAT)*KAT - (r < c ? 1 : 0);
            const int tb = tbond[sbi];
            #pragma unroll
            for (int j = 0; j < 8; ++j)
                vh.a[j] = tembF[tb*TF + part*8 + j];
        } else if (part < 5) {
            const int r = node0 + (row >> 3);
            const int c = ecol[node0*KNN + row];
            float dx = x[3*r]-x[3*c], dy = x[3*r+1]-x[3*c+1], dz = x[3*r+2]-x[3*c+2];
            float dist = fminf(sqrtf(dx*dx+dy*dy+dz*dz), 4.0f);
            #pragma unroll
            for (int j = 0; j < 8; ++j) {
                int g = (part-2)*8 + j;
                float v = 0.0f;
                if (g < NG) {
                    float dd = dist - GS_OG[g];
                    v = __expf(GS_CF[g]*dd*dd);
                }
                vh.a[j] = (f16)v;
            }
        } else {
            #pragma unroll
            for (int j = 0; j < 8; ++j) vh.a[j] = (f16)0.0f;
        }
        *(f16x8*)&tailB[row*64 + ((part ^ (row & 7)) << 3)] = vh.v;
    }
    __syncthreads();                                    // bar1

    // ---- GEMM1: [128 x 320] @ [320 x 128], 1-deep W prefetch -----------
    f32x4 acc[8][2];
    #pragma unroll
    for (int rt = 0; rt < 8; ++rt) { acc[rt][0] = (f32x4){0,0,0,0}; acc[rt][1] = (f32x4){0,0,0,0}; }
    {
        #pragma unroll
        for (int s = 0; s < 10; ++s) {
            f16x8 nf0 = wf0, nf1 = wf1;
            if (s < 9) {
                nf0 = *(const f16x8*)(bF0 + 32*(s+1));
                nf1 = *(const f16x8*)(bF1 + 32*(s+1));
            }
            if (s < 4) {
                #pragma unroll
                for (int rt = 0; rt < 8; ++rt) {
                    const int aR = aBase + 2*rt + (lr >> 3);
                    const int c4 = s*4 + lh;
                    const int ad = aR*128 + ((c4 ^ (aR & 15)) << 3);
                    const f16x8 ah = *(const f16x8*)&tbl[ad];
                    acc[rt][0] = mfma16(ah, wf0, acc[rt][0]);
                    acc[rt][1] = mfma16(ah, wf1, acc[rt][1]);
                }
            } else if (s < 8) {
                #pragma unroll
                for (int rt = 0; rt < 8; ++rt) {
                    const int aC = (int)((rt < 4 ? (aColPk0 >> (rt*8))
                                                 : (aColPk1 >> ((rt-4)*8))) & 31u);
                    const int c4 = (s-4)*4 + lh;
                    const int ad = aC*128 + ((c4 ^ (aC & 15)) << 3);
                    const f16x8 ah = *(const f16x8*)&tbl[ad];
                    acc[rt][0] = mfma16(ah, wf0, acc[rt][0]);
                    acc[rt][1] = mfma16(ah, wf1, acc[rt][1]);
                }
            } else {
                #pragma unroll
                for (int rt = 0; rt < 8; ++rt) {
                    const int r = rt*16 + lr;
                    const int c = (s-8)*4 + lh;
                    const int ad = r*64 + ((c ^ (r & 7)) << 3);
                    const f16x8 ah = *(const f16x8*)&tailB[ad];
                    acc[rt][0] = mfma16(ah, wf0, acc[rt][0]);
                    acc[rt][1] = mfma16(ah, wf1, acc[rt][1]);
                }
            }
            wf0 = nf0; wf1 = nf1;
        }
    }

    // ---- bias + in-register LN partials --------------------------------
    {
        const float b10 = be1[colB0], b11 = be1[colB1];
        #pragma unroll
        for (int rt = 0; rt < 8; ++rt)
            #pragma unroll
            for (int j = 0; j < 4; ++j) { acc[rt][0][j] += b10; acc[rt][1][j] += b11; }
    }
    {
        #pragma unroll
        for (int rt = 0; rt < 8; ++rt) {
            float sv[4], qv[4];
            #pragma unroll
            for (int j = 0; j < 4; ++j) {
                const float a0 = acc[rt][0][j], a1 = acc[rt][1][j];
                sv[j] = a0 + a1; qv[j] = a0*a0 + a1*a1;
            }
            #pragma unroll
            for (int msk = 1; msk < 16; msk <<= 1) {
                #pragma unroll
                for (int j = 0; j < 4; ++j) {
                    sv[j] += __shfl_xor(sv[j], msk);
                    qv[j] += __shfl_xor(qv[j], msk);
                }
            }
            if (lr == 0) {
                #pragma unroll
                for (int j = 0; j < 4; ++j) {
                    const int row = rt*16 + 4*lh + j;
                    sStats[(row*4 + w)*2 + 0] = sv[j];
                    sStats[(row*4 + w)*2 + 1] = qv[j];
                }
            }
        }
    }
    __syncthreads();                                    // bar2

    if (tid < EPB) {
        const float4 a = *(const float4*)&sStats[tid*8];
        const float4 b = *(const float4*)&sStats[tid*8 + 4];
        const float st = a.x + a.z + b.x + b.z;
        const float qt = a.y + a.w + b.y + b.w;
        const float mu  = st * (1.0f/HID);
        const float var = qt * (1.0f/HID) - mu*mu;
        sMuInv[tid*2 + 0] = mu;
        sMuInv[tid*2 + 1] = rsqrtf(var + 1e-5f);
    }
    __syncthreads();                                    // bar3

    // ---- GEMM2 weight pointers + first fragments -----------------------
    const f16* c2F0 = W2T + (size_t)colB0*HID + lh*8;
    const f16* c2F1 = W2T + (size_t)colB1*HID + lh*8;
    f16x8 g2f0 = *(const f16x8*)c2F0, g2f1 = *(const f16x8*)c2F1;

    // ---- normalize + SiLU in regs, write fp16 acts to sB2 --------------
    {
        const float G0 = g1[colB0], G1s = g1[colB1];
        const float B0 = bt1[colB0], B1s = bt1[colB1];
        #pragma unroll
        for (int rt = 0; rt < 8; ++rt) {
            const int r0 = rt*16 + 4*lh;
            const float4 mi0 = *(const float4*)&sMuInv[r0*2];      // mu0,inv0,mu1,inv1
            const float4 mi1 = *(const float4*)&sMuInv[r0*2 + 4];  // mu2,inv2,mu3,inv3
            acc[rt][0][0] = siluf(fmaf((acc[rt][0][0]-mi0.x)*mi0.y, G0, B0));
            acc[rt][1][0] = siluf(fmaf((acc[rt][1][0]-mi0.x)*mi0.y, G1s, B1s));
            acc[rt][0][1] = siluf(fmaf((acc[rt][0][1]-mi0.z)*mi0.w, G0, B0));
            acc[rt][1][1] = siluf(fmaf((acc[rt][1][1]-mi0.z)*mi0.w, G1s, B1s));
            acc[rt][0][2] = siluf(fmaf((acc[rt][0][2]-mi1.x)*mi1.y, G0, B0));
            acc[rt][1][2] = siluf(fmaf((acc[rt][1][2]-mi1.x)*mi1.y, G1s, B1s));
            acc[rt][0][3] = siluf(fmaf((acc[rt][0][3]-mi1.z)*mi1.w, G0, B0));
            acc[rt][1][3] = siluf(fmaf((acc[rt][1][3]-mi1.z)*mi1.w, G1s, B1s));
        }
    }
    {
        #pragma unroll
        for (int rt = 0; rt < 8; ++rt) {
            #pragma unroll
            for (int hcol = 0; hcol < 2; ++hcol) {
                const int col = hcol ? colB1 : colB0;
                const int gch = col >> 3, cw = col & 7;
                #pragma unroll
                for (int j = 0; j < 4; ++j) {
                    const int row = rt*16 + 4*lh + j;
                    sB2[row*128 + ((gch ^ (row & 15)) << 3) + cw] =
                        (f16)acc[rt][hcol][j];
                }
            }
        }
    }
    __syncthreads();                                    // bar4

    // ---- GEMM2: [128 x 128] @ [128 x 128] ------------------------------
    f32x4 d[8][2];
    #pragma unroll
    for (int rt = 0; rt < 8; ++rt) { d[rt][0] = (f32x4){0,0,0,0}; d[rt][1] = (f32x4){0,0,0,0}; }
    {
        #pragma unroll
        for (int s = 0; s < 4; ++s) {
            f16x8 nf0 = g2f0, nf1 = g2f1;
            if (s < 3) {
                nf0 = *(const f16x8*)(c2F0 + 32*(s+1));
                nf1 = *(const f16x8*)(c2F1 + 32*(s+1));
            }
            #pragma unroll
            for (int rt = 0; rt < 8; ++rt) {
                const int rowL = rt*16 + lr;
                const int c4 = s*4 + lh;
                const f16x8 ah = *(const f16x8*)&sB2[rowL*128 + ((c4 ^ (rowL & 15)) << 3)];
                d[rt][0] = mfma16(ah, g2f0, d[rt][0]);
                d[rt][1] = mfma16(ah, g2f1, d[rt][1]);
            }
            g2f0 = nf0; g2f1 = nf1;
        }
    }

    // ---- SiLU in place (d becomes m) + attention gate ------------------
    {
        const float b20 = be2[colB0], b21 = be2[colB1];
        #pragma unroll
        for (int rt = 0; rt < 8; ++rt) {
            #pragma unroll
            for (int j = 0; j < 4; ++j) {
                d[rt][0][j] = siluf(d[rt][0][j] + b20);
                d[rt][1][j] = siluf(d[rt][1][j] + b21);
            }
        }
    }
    {
        const float wa0 = Watt[colB0], wa1 = Watt[colB1];
        float pa[8][4];
        #pragma unroll
        for (int rt = 0; rt < 8; ++rt)
            #pragma unroll
            for (int j = 0; j < 4; ++j)
                pa[rt][j] = d[rt][0][j]*wa0 + d[rt][1][j]*wa1;
        #pragma unroll
        for (int msk = 1; msk < 16; msk <<= 1) {
            #pragma unroll
            for (int rt = 0; rt < 8; ++rt)
                #pragma unroll
                for (int j = 0; j < 4; ++j)
                    pa[rt][j] += __shfl_xor(pa[rt][j], msk);
        }
        if (lr == 0) {
            #pragma unroll
            for (int rt = 0; rt < 8; ++rt)
                #pragma unroll
                for (int j = 0; j < 4; ++j)
                    sAP[w*128 + rt*16 + 4*lh + j] = pa[rt][j];
        }
    }
    __syncthreads();                                    // bar5
    if (tid < EPB)
        sAttv[tid] = sigf(sAP[tid] + sAP[128+tid] + sAP[256+tid] + sAP[384+tid] + batt[0]);
    __syncthreads();                                    // bar6

    // ---- gated aggregate -> aggF ---------------------------------------
    #pragma unroll
    for (int rt = 0; rt < 8; ++rt) {
        float s0 = 0.0f, s1 = 0.0f;
        #pragma unroll
        for (int j = 0; j < 4; ++j) {
            const float av = sAttv[rt*16 + 4*lh + j];
            s0 += d[rt][0][j]*av;
            s1 += d[rt][1][j]*av;
        }
        s0 += __shfl_xor(s0, 16);
        s1 += __shfl_xor(s1, 16);
        if ((lh & 1) == 0) {
            const int node = node0 + 2*rt + (lh >> 1);
            aggF[(size_t)node*HID + colB0] = (f16)(s0*0.2f);
            aggF[(size_t)node*HID + colB1] = (f16)(s1*0.2f);
        }
    }
}

// ---------------------------------------------------------------- node (fp16 MFMA, 32 nodes/block)
__global__ __launch_bounds__(256, 6) void node_k(
    float* __restrict__ hh, f16* __restrict__ hhF,
    const f16* __restrict__ aggF,
    const f16* __restrict__ B1T, const f16* __restrict__ B2T,
    const float* __restrict__ bn1, const float* __restrict__ g2,
    const float* __restrict__ bt2, const float* __restrict__ bn2)
{
    __shared__ __align__(16) char smem[16896];
    float* sMid = (float*)smem;
    f16* sY = (f16*)smem;                // fp16 post-LN acts (8 KB)

    const int tid = threadIdx.x;
    const int node0 = blockIdx.x * 32;
    const int w = tid >> 6, lane = tid & 63, lr = lane & 15, lh = lane >> 4;
    const int colB0 = w*32 + lr, colB1 = colB0 + 16;

    const f16* a1f = hhF  + (size_t)(node0+lr)*HID + lh*8;
    const f16* a2f = aggF + (size_t)(node0+lr)*HID + lh*8;
    const f16* c1F0 = B1T + (size_t)colB0*256 + lh*8;
    const f16* c1F1 = B1T + (size_t)colB1*256 + lh*8;

    f32x4 acc00={0,0,0,0}, acc01={0,0,0,0}, acc10={0,0,0,0}, acc11={0,0,0,0};
    {
        f16x8 wf0 = *(const f16x8*)c1F0, wf1 = *(const f16x8*)c1F1;
        #pragma unroll
        for (int s = 0; s < 8; ++s) {
            f16x8 nf0 = wf0, nf1 = wf1;
            if (s < 7) {
                nf0 = *(const f16x8*)(c1F0 + 32*(s+1));
                nf1 = *(const f16x8*)(c1F1 + 32*(s+1));
            }
            f16x8 ah0, ah1;
            if (s < 4) {
                ah0 = *(const f16x8*)(a1f + 32*s);
                ah1 = *(const f16x8*)(a1f + 16*HID + 32*s);
            } else {
                ah0 = *(const f16x8*)(a2f + 32*(s-4));
                ah1 = *(const f16x8*)(a2f + 16*HID + 32*(s-4));
            }
            acc00 = mfma16(ah0, wf0, acc00);
            acc01 = mfma16(ah0, wf1, acc01);
            acc10 = mfma16(ah1, wf0, acc10);
            acc11 = mfma16(ah1, wf1, acc11);
            wf0 = nf0; wf1 = nf1;
        }
    }
    {
        const float b10 = bn1[colB0], b11 = bn1[colB1];
        #pragma unroll
        for (int j = 0; j < 4; ++j) {
            const int r0 = 4*lh + j;
            sMid[r0*MIDSTR + colB0]      = acc00[j] + b10;
            sMid[r0*MIDSTR + colB1]      = acc01[j] + b11;
            sMid[(16+r0)*MIDSTR + colB0] = acc10[j] + b10;
            sMid[(16+r0)*MIDSTR + colB1] = acc11[j] + b11;
        }
    }
    __syncthreads();

    float y[16];
    const int eLN = tid >> 3, c0 = (tid & 7)*16;
    {
        const float* mrow = &sMid[eLN*MIDSTR + c0];
        float4 v0 = *(const float4*)&mrow[0];
        float4 v1 = *(const float4*)&mrow[4];
        float4 v2 = *(const float4*)&mrow[8];
        float4 v3 = *(const float4*)&mrow[12];
        float s = v0.x+v0.y+v0.z+v0.w + v1.x+v1.y+v1.z+v1.w
                + v2.x+v2.y+v2.z+v2.w + v3.x+v3.y+v3.z+v3.w;
        float q = v0.x*v0.x+v0.y*v0.y+v0.z*v0.z+v0.w*v0.w
                + v1.x*v1.x+v1.y*v1.y+v1.z*v1.z+v1.w*v1.w
                + v2.x*v2.x+v2.y*v2.y+v2.z*v2.z+v2.w*v2.w
                + v3.x*v3.x+v3.y*v3.y+v3.z*v3.z+v3.w*v3.w;
        #pragma unroll
        for (int m = 4; m >= 1; m >>= 1) { s += __shfl_xor(s, m); q += __shfl_xor(q, m); }
        float mu  = s * (1.0f/HID);
        float var = q * (1.0f/HID) - mu*mu;
        float inv = rsqrtf(var + 1e-5f);
        const float4 G0 = *(const float4*)&g2[c0+0],  G1v = *(const float4*)&g2[c0+4];
        const float4 G2 = *(const float4*)&g2[c0+8],  G3 = *(const float4*)&g2[c0+12];
        const float4 B0 = *(const float4*)&bt2[c0+0], B1 = *(const float4*)&bt2[c0+4];
        const float4 B2 = *(const float4*)&bt2[c0+8], B3 = *(const float4*)&bt2[c0+12];
        y[0]=siluf(fmaf((v0.x-mu)*inv,G0.x,B0.x));  y[1]=siluf(fmaf((v0.y-mu)*inv,G0.y,B0.y));
        y[2]=siluf(fmaf((v0.z-mu)*inv,G0.z,B0.z));  y[3]=siluf(fmaf((v0.w-mu)*inv,G0.w,B0.w));
        y[4]=siluf(fmaf((v1.x-mu)*inv,G1v.x,B1.x)); y[5]=siluf(fmaf((v1.y-mu)*inv,G1v.y,B1.y));
        y[6]=siluf(fmaf((v1.z-mu)*inv,G1v.z,B1.z)); y[7]=siluf(fmaf((v1.w-mu)*inv,G1v.w,B1.w));
        y[8]=siluf(fmaf((v2.x-mu)*inv,G2.x,B2.x));  y[9]=siluf(fmaf((v2.y-mu)*inv,G2.y,B2.y));
        y[10]=siluf(fmaf((v2.z-mu)*inv,G2.z,B2.z)); y[11]=siluf(fmaf((v2.w-mu)*inv,G2.w,B2.w));
        y[12]=siluf(fmaf((v3.x-mu)*inv,G3.x,B3.x)); y[13]=siluf(fmaf((v3.y-mu)*inv,G3.y,B3.y));
        y[14]=siluf(fmaf((v3.z-mu)*inv,G3.z,B3.z)); y[15]=siluf(fmaf((v3.w-mu)*inv,G3.w,B3.w));
    }
    __syncthreads();
    {
        U8h ha, hb2;
        #pragma unroll
        for (int j = 0; j < 8; ++j) {
            ha.a[j]  = (f16)y[j];
            hb2.a[j] = (f16)y[8+j];
        }
        const int cA = (2*(tid & 7))     ^ (eLN & 15);
        const int cB = (2*(tid & 7) + 1) ^ (eLN & 15);
        *(f16x8*)&sY[eLN*128 + (cA << 3)] = ha.v;
        *(f16x8*)&sY[eLN*128 + (cB << 3)] = hb2.v;
    }
    __syncthreads();

    f32x4 d00={0,0,0,0}, d01={0,0,0,0}, d10={0,0,0,0}, d11={0,0,0,0};
    {
        const f16* c2F0 = B2T + (size_t)colB0*HID + lh*8;
        const f16* c2F1 = B2T + (size_t)colB1*HID + lh*8;
        f16x8 wf0 = *(const f16x8*)c2F0, wf1 = *(const f16x8*)c2F1;
        #pragma unroll
        for (int s = 0; s < 4; ++s) {
            f16x8 nf0 = wf0, nf1 = wf1;
            if (s < 3) {
                nf0 = *(const f16x8*)(c2F0 + 32*(s+1));
                nf1 = *(const f16x8*)(c2F1 + 32*(s+1));
            }
            const int c4 = s*4 + lh;
            const int i0 = lr*128 + ((c4 ^ lr) << 3);
            const int i1 = (16+lr)*128 + ((c4 ^ lr) << 3);
            f16x8 ah0 = *(const f16x8*)&sY[i0], ah1 = *(const f16x8*)&sY[i1];
            d00 = mfma16(ah0, wf0, d00);
            d01 = mfma16(ah0, wf1, d01);
            d10 = mfma16(ah1, wf0, d10);
            d11 = mfma16(ah1, wf1, d11);
            wf0 = nf0; wf1 = nf1;
        }
    }

    {
        const float b20 = bn2[colB0], b21 = bn2[colB1];
        #pragma unroll
        for (int j = 0; j < 4; ++j) {
            const int r0 = 4*lh + j, r1 = 16 + 4*lh + j;
            const size_t i00 = (size_t)(node0+r0)*HID + colB0;
            const size_t i01 = (size_t)(node0+r0)*HID + colB1;
            const size_t i10 = (size_t)(node0+r1)*HID + colB0;
            const size_t i11 = (size_t)(node0+r1)*HID + colB1;
            float v00 = hh[i00] + d00[j] + b20;
            float v01 = hh[i01] + d01[j] + b21;
            float v10 = hh[i10] + d10[j] + b20;
            float v11 = hh[i11] + d11[j] + b21;
            hh[i00] = v00; hh[i01] = v01; hh[i10] = v10; hh[i11] = v11;
            hhF[i00] = (f16)v00; hhF[i01] = (f16)v01;
            hhF[i10] = (f16)v10; hhF[i11] = (f16)v11;
        }
    }
}

// ---------------------------------------------------------------- output head
__global__ __launch_bounds__(HID) void out_k(
    const float* __restrict__ hh, const float* __restrict__ Woe,
    const float* __restrict__ boe, const float* __restrict__ Wf,
    const float* __restrict__ bf, float* __restrict__ out)
{
    __shared__ float sH[HID];
    const int lig = blockIdx.x, tid = threadIdx.x;
    float s = 0.0f;
    const float* base = hh + (size_t)lig*KAT*HID + tid;
    #pragma unroll 8
    for (int a = 0; a < KAT; ++a) s += base[a*HID];
    sH[tid] = s * (1.0f/KAT);
    __syncthreads();

    float contrib = 0.0f;
    if (tid < OUTF) {
        float p = boe[tid];
        #pragma unroll 4
        for (int i = 0; i < HID; ++i)
            p = fmaf(sH[i], Woe[i*OUTF + tid], p);
        contrib = p * Wf[tid];
    }
    #pragma unroll
    for (int m = 1; m < 64; m <<= 1) contrib += __shfl_xor(contrib, m);
    if (tid == 0) out[lig] = contrib + bf[0];
}

// ---------------------------------------------------------------- launch
extern "C" void kernel_launch(void* const* d_in, const int* in_sizes, int n_in,
                              void* d_out, int out_size, void* d_ws, size_t ws_size,
                              hipStream_t stream)
{
    (void)in_sizes; (void)n_in; (void)out_size; (void)ws_size;
    const float* x    = (const float*)d_in[0];
    const float* h    = (const float*)d_in[1];
    const int*   t    = (const int*)d_in[2];
    const int*   edges= (const int*)d_in[3];
    const int*   tb   = (const int*)d_in[4];
    const float* temb = (const float*)d_in[8];
    const float* Win  = (const float*)d_in[9];
    const float* bin  = (const float*)d_in[10];
    const float* We1  = (const float*)d_in[11];
    const float* be1  = (const float*)d_in[12];
    const float* g1   = (const float*)d_in[13];
    const float* bt1  = (const float*)d_in[14];
    const float* We2  = (const float*)d_in[15];
    const float* be2  = (const float*)d_in[16];
    const float* Watt = (const float*)d_in[17];
    const float* batt = (const float*)d_in[18];
    const float* Wn1  = (const float*)d_in[19];
    const float* bn1  = (const float*)d_in[20];
    const float* g2   = (const float*)d_in[21];
    const float* bt2  = (const float*)d_in[22];
    const float* Wn2  = (const float*)d_in[23];
    const float* bn2  = (const float*)d_in[24];
    const float* Woe  = (const float*)d_in[25];
    const float* boe  = (const float*)d_in[26];
    const float* Wf   = (const float*)d_in[27];
    const float* bf   = (const float*)d_in[28];
    float* out = (float*)d_out;

    char* wsb = (char*)d_ws;
    float* hh  = (float*)(wsb);                        // 16 MB
    f16* hhF   = (f16*)(wsb + ((size_t)16<<20));       // 8 MB
    f16* aggF  = (f16*)(wsb + ((size_t)24<<20));       // 8 MB
    f16* tembF = (f16*)(wsb + ((size_t)32<<20));
    f16* W1T   = tembF + PREP_TEMB;
    f16* W2T   = W1T + PREP_W1;
    f16* WN1T  = W2T + PREP_W2;
    f16* WN2T  = WN1T + PREP_WN1;

    prep_k<<<(PREP_TOT + 255)/256, 256, 0, stream>>>(
        temb, We1, We2, Wn1, Wn2, tembF, W1T, W2T, WN1T, WN2T);

    embed_k<<<NNODES/8, 256, 0, stream>>>(h, t, temb, Win, bin, hh, hhF);

    for (int l = 0; l < 4; ++l) {
        edge_k<<<NNODES/NPB, 256, 0, stream>>>(
            hhF, x, edges + NEDGES, tb, tembF,
            W1T + (size_t)l*128*K1, W2T + (size_t)l*128*128,
            be1 + l*HID, g1 + l*HID, bt1 + l*HID, be2 + l*HID,
            Watt + l*HID, batt + l, aggF);
        node_k<<<NNODES/32, 256, 0, stream>>>(
            hh, hhF, aggF,
            WN1T + (size_t)l*128*256, WN2T + (size_t)l*128*128,
            bn1 + l*HID, g2 + l*HID, bt2 + l*HID, bn2 + l*HID);
    }
    out_k<<<NLIG, HID, 0, stream>>>(hh, Woe, boe, Wf, bf, out);
}